// Round 13
// baseline (5324.840 us; speedup 1.0000x reference)
//
#include <hip/hip_runtime.h>

#define L_ 18
#define H_ 1024
#define NH_ 8
#define HD_ 256
#define FF_ 4096
#define HOR_ 50
#define PRE_ 968
#define B_ 8
#define AD_ 32
#define TPAD_ 1024
#define MROWS_ 400
#define MPAD_ 512
#define KSTEP_ 128
#define LST_ 132

typedef float f32x4 __attribute__((ext_vector_type(4)));
typedef short s16x4 __attribute__((ext_vector_type(4)));
typedef short s16x8 __attribute__((ext_vector_type(8)));
typedef unsigned short u16x8 __attribute__((ext_vector_type(8)));

__device__ __forceinline__ unsigned short f2bf(float f) {
  unsigned u = __float_as_uint(f);
  u += 0x7FFFu + ((u >> 16) & 1u);
  return (unsigned short)(u >> 16);
}
__device__ __forceinline__ float bf2f(unsigned short h) {
  return __uint_as_float(((unsigned)h) << 16);
}
__device__ __forceinline__ float wave_sum(float v) {
#pragma unroll
  for (int o = 32; o > 0; o >>= 1) v += __shfl_xor(v, o);
  return v;
}

// ---------------------------------------------------------------- time embedding
__global__ __launch_bounds__(256) void emb_k(const float* __restrict__ ts, float* __restrict__ emb) {
  int b = blockIdx.x, tid = threadIdx.x;
  float t = ts[b];
  for (int j = tid; j < 512; j += 256) {
    float ang = 1570.7963267948966f * expf((float)j * (-6.907755278982137f / 511.0f)) * t;
    emb[(size_t)b * H_ + j] = sinf(ang);
    emb[(size_t)b * H_ + 512 + j] = cosf(ang);
  }
}

// ---------------------------------------------------------------- [8,1024]@[1024,1024] (+bias,+silu)
__global__ __launch_bounds__(256) void gemm8_k(const float* __restrict__ A8, const float* __restrict__ W,
                                               const float* __restrict__ bias, float* __restrict__ out,
                                               int act) {
  __shared__ float a_s[8 * 1024];
  __shared__ float red[4][8][64];
  int tid = threadIdx.x;
  for (int i = tid; i < 8 * 1024; i += 256) a_s[i] = A8[i];
  __syncthreads();
  int nl = tid & 63, kg = tid >> 6;
  int n = blockIdx.x * 64 + nl;
  float acc[8];
#pragma unroll
  for (int m = 0; m < 8; m++) acc[m] = 0.f;
  for (int k = kg * 256; k < kg * 256 + 256; k++) {
    float wv = W[(size_t)k * 1024 + n];
#pragma unroll
    for (int m = 0; m < 8; m++) acc[m] += a_s[m * 1024 + k] * wv;
  }
#pragma unroll
  for (int m = 0; m < 8; m++) red[kg][m][nl] = acc[m];
  __syncthreads();
  if (kg == 0) {
#pragma unroll
    for (int m = 0; m < 8; m++) {
      float v = red[0][m][nl] + red[1][m][nl] + red[2][m][nl] + red[3][m][nl];
      if (bias) v += bias[n];
      if (act) v = v / (1.f + expf(-v));
      out[(size_t)m * 1024 + n] = v;
    }
  }
}

// ---------------------------------------------------------------- all 72 adaLN cond GEMMs in one grid
__global__ __launch_bounds__(256) void gates_k(const float* __restrict__ cond,
                                               const float* __restrict__ w0, const float* __restrict__ w1,
                                               const float* __restrict__ w2, const float* __restrict__ w3,
                                               float* __restrict__ gates) {
  __shared__ float a_s[8 * 1024];
  __shared__ float red[4][8][64];
  int tid = threadIdx.x;
  for (int i = tid; i < 8 * 1024; i += 256) a_s[i] = cond[i];
  __syncthreads();
  int z = blockIdx.z, layer = blockIdx.y;
  const float* W = (z == 0 ? w0 : z == 1 ? w1 : z == 2 ? w2 : w3) + (size_t)layer * H_ * H_;
  float* out = gates + ((size_t)(z * L_ + layer) * 8) * H_;
  int nl = tid & 63, kg = tid >> 6;
  int n = blockIdx.x * 64 + nl;
  float acc[8];
#pragma unroll
  for (int m = 0; m < 8; m++) acc[m] = 0.f;
  for (int k = kg * 256; k < kg * 256 + 256; k++) {
    float wv = W[(size_t)k * 1024 + n];
#pragma unroll
    for (int m = 0; m < 8; m++) acc[m] += a_s[m * 1024 + k] * wv;
  }
#pragma unroll
  for (int m = 0; m < 8; m++) red[kg][m][nl] = acc[m];
  __syncthreads();
  if (kg == 0) {
#pragma unroll
    for (int m = 0; m < 8; m++)
      out[(size_t)m * 1024 + n] = red[0][m][nl] + red[1][m][nl] + red[2][m][nl] + red[3][m][nl];
  }
}

// ---------------------------------------------------------------- pad-mask -> per-batch valid counts
__global__ void offs_k(const unsigned char* __restrict__ mask, int* __restrict__ offs) {
  __shared__ int cnt[8];
  __shared__ int mod4;
  int tid = threadIdx.x;
  if (tid < 8) cnt[tid] = 0;
  if (tid == 8) mod4 = 0;
  __syncthreads();
  for (int i = tid; i < B_ * PRE_; i += 256) {
    unsigned char v = mask[i];
    if (v) {
      atomicAdd(&cnt[i / PRE_], 1);
      if (i & 3) atomicAdd(&mod4, 1);
    }
  }
  __syncthreads();
  if (tid < 8) offs[tid] = (mod4 == 0) ? cnt[tid] * 4 : cnt[tid];
}

// ---------------------------------------------------------------- h = x_t @ action_in_w + b  (pad rows = 0)
__global__ __launch_bounds__(256) void action_in_k(const float* __restrict__ xt, const float* __restrict__ Wi,
                                                   const float* __restrict__ bi, float* __restrict__ h) {
  int idx = blockIdx.x * 256 + threadIdx.x;
  int m = idx >> 10, n = idx & 1023;
  float v = 0.f;
  if (m < MROWS_) {
    const float* xr = xt + (size_t)m * AD_;
#pragma unroll
    for (int k = 0; k < AD_; k++) v += xr[k] * Wi[(size_t)k * H_ + n];
    v += bi[n];
  }
  h[idx] = v;
}

// ---------------------------------------------------------------- w2[slot][b][n] = (1+nw[n])*(1+sc[b][n])
// slots: 0..17 = in (layer), 18..35 = post, 36 = final
__global__ __launch_bounds__(256) void w2p_k(const float* __restrict__ in_norm_w,
                                             const float* __restrict__ post_norm_w,
                                             const float* __restrict__ fnorm_w,
                                             const float* __restrict__ gates, const float* __restrict__ fscale,
                                             float* __restrict__ w2all) {
  int slot = blockIdx.x, b = blockIdx.y, tid = threadIdx.x;
  const float* nw;
  const float* sc;
  if (slot < 18) {
    nw = in_norm_w + (size_t)slot * 1024;
    sc = gates + ((size_t)(0 * L_ + slot) * 8 + b) * 1024;
  } else if (slot < 36) {
    nw = post_norm_w + (size_t)(slot - 18) * 1024;
    sc = gates + ((size_t)(2 * L_ + (slot - 18)) * 8 + b) * 1024;
  } else {
    nw = fnorm_w;
    sc = fscale + (size_t)b * 1024;
  }
  float* o = w2all + ((size_t)slot * 8 + b) * 1024;
  for (int i = tid; i < 1024; i += 256) o[i] = (1.f + nw[i]) * (1.f + sc[i]);
}

// ---------------------------------------------------------------- AdaRMSNorm -> bf16 (pad rows = 0), layer-0 only
__global__ __launch_bounds__(256) void ada_k(const float* __restrict__ X, const float* __restrict__ nw,
                                             const float* __restrict__ sc, unsigned short* __restrict__ Y) {
  int m = blockIdx.x, tid = threadIdx.x;
  size_t base = (size_t)m * H_;
  if (m >= MROWS_) {
#pragma unroll
    for (int j = 0; j < 4; j++) Y[base + tid * 4 + j] = 0;
    return;
  }
  f32x4 x = *(const f32x4*)(X + base + tid * 4);
  float ss = x[0] * x[0] + x[1] * x[1] + x[2] * x[2] + x[3] * x[3];
  __shared__ float r4[4];
  float wsv = wave_sum(ss);
  if ((tid & 63) == 0) r4[tid >> 6] = wsv;
  __syncthreads();
  float rs = rsqrtf((r4[0] + r4[1] + r4[2] + r4[3]) * (1.f / 1024.f) + 1e-6f);
  int b = m / HOR_;
#pragma unroll
  for (int j = 0; j < 4; j++) {
    int n = tid * 4 + j;
    Y[base + n] = f2bf(x[j] * rs * (1.f + nw[n]) * (1.f + sc[(size_t)b * H_ + n]));
  }
}

// ---------------------------------------------------------------- all-layer prefix convert: K row-major, V transposed
__global__ __launch_bounds__(256) void prefixAll_k(const float* __restrict__ pk, const float* __restrict__ pv,
                                                   unsigned short* __restrict__ Kf_all,
                                                   unsigned short* __restrict__ Vt_all) {
  int b = blockIdx.y, t0 = blockIdx.x * 64, layer = blockIdx.z, tid = threadIdx.x;
  unsigned short* Kf = Kf_all + (size_t)layer * B_ * TPAD_ * HD_;
  unsigned short* Vt = Vt_all + (size_t)layer * B_ * HD_ * TPAD_;
  __shared__ unsigned short vt[256][72];
  const float* kp = pk + ((size_t)(b * L_ + layer)) * PRE_ * HD_;
  const float* vp = pv + ((size_t)(b * L_ + layer)) * PRE_ * HD_;
  for (int i = 0; i < 64; i++) {
    int t = t0 + i;
    float kv = 0.f, vv = 0.f;
    if (t < PRE_) {
      kv = kp[(size_t)t * HD_ + tid];
      vv = vp[(size_t)t * HD_ + tid];
    }
    Kf[((size_t)b * TPAD_ + t) * HD_ + tid] = f2bf(kv);  // suffix rows rewritten per layer by qkvF
    vt[tid][i] = f2bf(vv);
  }
  __syncthreads();
#pragma unroll
  for (int p = 0; p < 4; p++) {
    int d = p * 64 + (tid >> 2);
    int c0 = (tid & 3) * 16;
    u16x8 v0, v1;
#pragma unroll
    for (int j = 0; j < 8; j++) { v0[j] = vt[d][c0 + j]; v1[j] = vt[d][c0 + 8 + j]; }
    size_t dst = ((size_t)(b * HD_ + d)) * TPAD_ + t0 + c0;
    *(u16x8*)(Vt + dst) = v0;
    *(u16x8*)(Vt + dst + 8) = v1;
  }
}

// ================================================================ QKV GEMM (raw A + deferred rs) + RoPE/scatter
// (validated round-11) grid (80 strips, 2 m-halves), 512 thr. rs=1 when ssA==nullptr.
__global__ __launch_bounds__(512) void qkvF_k(const unsigned short* __restrict__ A,
                                              const float* __restrict__ ssA,
                                              const float* __restrict__ Wq, const float* __restrict__ Wk,
                                              const float* __restrict__ Wv, const int* __restrict__ offs,
                                              unsigned short* __restrict__ q_r, unsigned short* __restrict__ Kf,
                                              unsigned short* __restrict__ Vt) {
  const int st = blockIdx.x, mh = blockIdx.y;
  const int tid = threadIdx.x, wv = tid >> 6, l = tid & 63;
  const int lr = l & 15, kg = l >> 4, lk = kg << 2;
  const int m0blk = mh * 256, m0 = m0blk + wv * 32;

  const float* W;
  int ldw, wbase;
  bool paired;
  if (st < 64)      { W = Wq; ldw = 2048; wbase = (st >> 3) * 256 + (st & 7) * 16; paired = true; }
  else if (st < 72) { W = Wk; ldw = 256;  wbase = (st - 64) * 16; paired = true; }
  else              { W = Wv; ldw = 256;  wbase = (st - 72) * 32; paired = false; }

  __shared__ unsigned short Wt[2][32][LST_];
  __shared__ int offsL[8];
  __shared__ float rsL[256];
  const int pr = tid >> 3, c0 = (tid & 7) * 4;
  const int wcol = wbase + c0 + ((paired && c0 >= 16) ? 112 : 0);

  if (tid < 8) offsL[tid] = offs[tid];
  if (tid < 256) {
    int row = m0blk + tid;
    float rs = 1.f;
    if (ssA && row < MROWS_) {
      float ss = 0.f;
#pragma unroll
      for (int p = 0; p < 32; p++) ss += ssA[(size_t)p * 512 + row];
      rs = rsqrtf(ss * (1.f / 1024.f) + 1e-6f);
    }
    rsL[tid] = rs;
  }

  f32x4 acc[2][2];
#pragma unroll
  for (int a = 0; a < 2; a++)
#pragma unroll
    for (int b = 0; b < 2; b++) acc[a][b] = (f32x4){0.f, 0.f, 0.f, 0.f};

  f32x4 pa0, pa1;
  auto LOADW = [&](int IT) {
    size_t kk = (size_t)IT * KSTEP_ + 2 * pr;
    pa0 = *(const f32x4*)(W + kk * ldw + wcol);
    pa1 = *(const f32x4*)(W + (kk + 1) * ldw + wcol);
  };
  auto STOREW = [&](int BUF) {
#pragma unroll
    for (int j = 0; j < 4; j++) {
      unsigned v = (unsigned)f2bf(pa0[j]) | ((unsigned)f2bf(pa1[j]) << 16);
      *(unsigned*)&Wt[BUF][c0 + j][2 * pr] = v;
    }
  };

  LOADW(0);
  STOREW(0);
  __syncthreads();

  for (int it = 0; it < 8; ++it) {
    if (it + 1 < 8) LOADW(it + 1);
    const int cur = it & 1, kb = it * KSTEP_;
#pragma unroll
    for (int s = 0; s < 4; s++) {
      s16x8 bfr[2];
#pragma unroll
      for (int nf = 0; nf < 2; nf++) {
        const unsigned short* wp = &Wt[cur][nf * 16 + lr][s * 32 + 2 * lk];
        s16x4 b0 = *(const s16x4*)wp;
        s16x4 b1 = *(const s16x4*)(wp + 4);
#pragma unroll
        for (int j = 0; j < 4; j++) { bfr[nf][j] = b0[j]; bfr[nf][4 + j] = b1[j]; }
      }
#pragma unroll
      for (int mf = 0; mf < 2; mf++) {
        s16x8 a = *(const s16x8*)(A + (size_t)(m0 + mf * 16 + lr) * H_ + kb + s * 32 + 8 * kg);
#pragma unroll
        for (int nf = 0; nf < 2; nf++)
          acc[mf][nf] = __builtin_amdgcn_mfma_f32_16x16x32_bf16(a, bfr[nf], acc[mf][nf], 0, 0, 0);
      }
    }
    if (it + 1 < 8) STOREW((it + 1) & 1);
    __syncthreads();
  }

  const float RK = -9.210340371976184f / 128.0f;
  if (st < 64) {  // Q: rope pair, write q_r
    const int h = st >> 3, x = (st & 7) * 16, dd = x + lr;
    const float inv = expf((float)dd * RK);
#pragma unroll
    for (int mf = 0; mf < 2; mf++)
#pragma unroll
      for (int r = 0; r < 4; r++) {
        int m = m0 + mf * 16 + lk + r;
        if (m >= MROWS_) continue;
        float rsv = rsL[m - m0blk];
        int b = m / HOR_, s = m - b * HOR_;
        float ang = (float)(offsL[b] + s) * inv;
        float cc = cosf(ang), sn = sinf(ang);
        float v1 = rsv * acc[mf][0][r], v2 = rsv * acc[mf][1][r];
        size_t base = ((size_t)(b * NH_ + h) * 64 + s) * HD_;
        q_r[base + dd] = f2bf(v1 * cc - v2 * sn);
        q_r[base + dd + 128] = f2bf(v2 * cc + v1 * sn);
      }
  } else if (st < 72) {  // K: rope pair, write Kf suffix rows
    const int x = (st - 64) * 16, dd = x + lr;
    const float inv = expf((float)dd * RK);
#pragma unroll
    for (int mf = 0; mf < 2; mf++)
#pragma unroll
      for (int r = 0; r < 4; r++) {
        int m = m0 + mf * 16 + lk + r;
        if (m >= MROWS_) continue;
        float rsv = rsL[m - m0blk];
        int b = m / HOR_, s = m - b * HOR_;
        float ang = (float)(offsL[b] + s) * inv;
        float cc = cosf(ang), sn = sinf(ang);
        float v1 = rsv * acc[mf][0][r], v2 = rsv * acc[mf][1][r];
        size_t base = ((size_t)b * TPAD_ + PRE_ + s) * HD_;
        Kf[base + dd] = f2bf(v1 * cc - v2 * sn);
        Kf[base + dd + 128] = f2bf(v2 * cc + v1 * sn);
      }
  } else {  // V: write Vt columns
    const int x = (st - 72) * 32;
#pragma unroll
    for (int mf = 0; mf < 2; mf++)
#pragma unroll
      for (int nf = 0; nf < 2; nf++)
#pragma unroll
        for (int r = 0; r < 4; r++) {
          int m = m0 + mf * 16 + lk + r;
          if (m >= MROWS_) continue;
          float rsv = rsL[m - m0blk];
          int b = m / HOR_, s = m - b * HOR_;
          int d = x + nf * 16 + lr;
          Vt[((size_t)(b * HD_ + d)) * TPAD_ + PRE_ + s] = f2bf(rsv * acc[mf][nf][r]);
        }
  }
}

// ================================================================ 8-wave flash attention (validated round-12)
// grid (B, 4 rg, NH) [b = bid%8 -> per-batch KV pinned to one XCD's L2]. 512 thr = 8 waves.
__global__ __launch_bounds__(512) void flash8_k(const unsigned short* __restrict__ qr,
                                                const unsigned short* __restrict__ Kf,
                                                const unsigned short* __restrict__ Vt,
                                                unsigned short* __restrict__ attb) {
  const int b = blockIdx.x, rg = blockIdx.y, h = blockIdx.z;
  const int bh = b * NH_ + h;
  const int tid = threadIdx.x, w = tid >> 6, l = tid & 63;
  const int lr = l & 15, kg = l >> 4;
  const int t0 = w * 128;

  __shared__ __align__(16) unsigned short Pl[8][16][136];
  __shared__ float mlS[8][16][2];

  const unsigned short* qbase = qr + ((size_t)bh * 64 + rg * 16 + lr) * HD_;
  s16x8 afr[8];
#pragma unroll
  for (int js = 0; js < 8; js++) afr[js] = *(const s16x8*)(qbase + js * 32 + 8 * kg);
  f32x4 sc[8];
#pragma unroll
  for (int nf = 0; nf < 8; nf++) sc[nf] = (f32x4){0.f, 0.f, 0.f, 0.f};
  const unsigned short* kb = Kf + ((size_t)b * TPAD_ + t0) * HD_;
#pragma unroll
  for (int js = 0; js < 8; js++)
#pragma unroll
    for (int nf = 0; nf < 8; nf++) {
      s16x8 bv = *(const s16x8*)(kb + (size_t)(nf * 16 + lr) * HD_ + js * 32 + 8 * kg);
      sc[nf] = __builtin_amdgcn_mfma_f32_16x16x32_bf16(afr[js], bv, sc[nf], 0, 0, 0);
    }
  float mx[4] = {-3.0e38f, -3.0e38f, -3.0e38f, -3.0e38f};
#pragma unroll
  for (int nf = 0; nf < 8; nf++) {
    int t = t0 + nf * 16 + lr;
#pragma unroll
    for (int r = 0; r < 4; r++) {
      int srw = rg * 16 + 4 * kg + r;
      float v = sc[nf][r] * 0.0625f;
      if (t >= PRE_ && (t - PRE_) > srw) v = -1e9f;
      sc[nf][r] = v;
      mx[r] = fmaxf(mx[r], v);
    }
  }
#pragma unroll
  for (int o = 8; o > 0; o >>= 1)
#pragma unroll
    for (int r = 0; r < 4; r++) mx[r] = fmaxf(mx[r], __shfl_xor(mx[r], o));
  float ls[4] = {0.f, 0.f, 0.f, 0.f};
#pragma unroll
  for (int nf = 0; nf < 8; nf++)
#pragma unroll
    for (int r = 0; r < 4; r++) {
      float p = expf(sc[nf][r] - mx[r]);
      sc[nf][r] = p;
      ls[r] += p;
    }
#pragma unroll
  for (int o = 8; o > 0; o >>= 1)
#pragma unroll
    for (int r = 0; r < 4; r++) ls[r] += __shfl_xor(ls[r], o);
#pragma unroll
  for (int nf = 0; nf < 8; nf++)
#pragma unroll
    for (int r = 0; r < 4; r++) Pl[w][4 * kg + r][nf * 16 + lr] = f2bf(sc[nf][r]);
  if (lr == 0) {
#pragma unroll
    for (int r = 0; r < 4; r++) {
      mlS[w][4 * kg + r][0] = mx[r];
      mlS[w][4 * kg + r][1] = ls[r];
    }
  }
  __syncthreads();
  f32x4 o4[8][2];
#pragma unroll
  for (int a = 0; a < 8; a++)
#pragma unroll
    for (int c = 0; c < 2; c++) o4[a][c] = (f32x4){0.f, 0.f, 0.f, 0.f};
#pragma unroll
  for (int wz = 0; wz < 8; wz++)
#pragma unroll
    for (int ti = 0; ti < 128; ti += 32) {
      s16x8 a = *(const s16x8*)&Pl[wz][lr][ti + 8 * kg];
#pragma unroll
      for (int nf = 0; nf < 2; nf++) {
        s16x8 bv = *(const s16x8*)(Vt + ((size_t)(b * HD_ + w * 32 + nf * 16 + lr)) * TPAD_ +
                                   wz * 128 + ti + 8 * kg);
        o4[wz][nf] = __builtin_amdgcn_mfma_f32_16x16x32_bf16(a, bv, o4[wz][nf], 0, 0, 0);
      }
    }
#pragma unroll
  for (int r = 0; r < 4; r++) {
    int row = 4 * kg + r;
    int s = rg * 16 + row;
    if (s >= HOR_) continue;
    float M = -3.0e38f;
#pragma unroll
    for (int wz = 0; wz < 8; wz++) M = fmaxf(M, mlS[wz][row][0]);
    float w8[8], Lden = 0.f;
#pragma unroll
    for (int wz = 0; wz < 8; wz++) {
      w8[wz] = expf(mlS[wz][row][0] - M);
      Lden += w8[wz] * mlS[wz][row][1];
    }
    float invL = 1.f / Lden;
#pragma unroll
    for (int nf = 0; nf < 2; nf++) {
      float o = 0.f;
#pragma unroll
      for (int wz = 0; wz < 8; wz++) o += w8[wz] * o4[wz][nf][r];
      attb[((size_t)(b * HOR_ + s)) * 2048 + h * HD_ + w * 32 + nf * 16 + lr] = f2bf(o * invL);
    }
  }
}

// ================================================================ projection GEMM + fused last-block reduce
// Stage-1 = validated gemmS core (NS=4, MS=2; 4 MFMA chains). grid (32 strips, 4 kz, 2 ms) = 256 blocks.
// 4th arriver per (strip,ms) sums the 4 partials (fixed z-order), applies gated residual, writes
// h (f32), normRaw = bf16(h*w2n), and per-strip row-ss partials. Counters self-reset.
template <int KSZ>
__global__ __launch_bounds__(512) void gemmR_k(const unsigned short* __restrict__ A, const float* __restrict__ W,
                                               float* __restrict__ part, int* __restrict__ cnt,
                                               const float* __restrict__ hprev, const float* __restrict__ gatev,
                                               const float* __restrict__ w2n, float* __restrict__ hout,
                                               unsigned short* __restrict__ normOut, float* __restrict__ ssOut) {
  const int strip = blockIdx.x, kz = blockIdx.y, ms = blockIdx.z;
  const int n0 = strip * 32;
  const int tid = threadIdx.x;
  const int wv = tid >> 6, l = tid & 63;
  const int lr = l & 15, lk = (l >> 4) << 2;
  const int KC = KSZ / 4;
  const int kbase = kz * KC;
  const int m0 = ms * 256 + wv * 32;

  __shared__ unsigned short Wt[2][32][LST_];
  const int pr = tid >> 3;
  const int c0 = (tid & 7) * 4;

  f32x4 acc[2][2];
#pragma unroll
  for (int a = 0; a < 2; a++)
#pragma unroll
    for (int b = 0; b < 2; b++) acc[a][b] = (f32x4){0.f, 0.f, 0.f, 0.f};

  constexpr int NITER = KSZ / 4 / KSTEP_;
  f32x4 pa0, pa1;

  auto LOADW = [&](int IT) {
    size_t kk = (size_t)(kbase + IT * KSTEP_ + 2 * pr);
    pa0 = *(const f32x4*)(W + kk * 1024 + n0 + c0);
    pa1 = *(const f32x4*)(W + (kk + 1) * 1024 + n0 + c0);
  };
  auto STOREW = [&](int BUF) {
#pragma unroll
    for (int j = 0; j < 4; j++) {
      unsigned v = (unsigned)f2bf(pa0[j]) | ((unsigned)f2bf(pa1[j]) << 16);
      *(unsigned*)&Wt[BUF][c0 + j][2 * pr] = v;
    }
  };

  LOADW(0);
  STOREW(0);
  __syncthreads();

  for (int it = 0; it < NITER; ++it) {
    if (it + 1 < NITER) LOADW(it + 1);
    const int cur = it & 1;
    const int kb = kbase + it * KSTEP_;
#pragma unroll
    for (int s = 0; s < 4; s++) {
      s16x8 bfr[2];
#pragma unroll
      for (int nf = 0; nf < 2; nf++) {
        const unsigned short* wp = &Wt[cur][nf * 16 + lr][s * 32 + 2 * lk];
        s16x4 b0 = *(const s16x4*)wp;
        s16x4 b1 = *(const s16x4*)(wp + 4);
#pragma unroll
        for (int j = 0; j < 4; j++) { bfr[nf][j] = b0[j]; bfr[nf][4 + j] = b1[j]; }
      }
#pragma unroll
      for (int mf = 0; mf < 2; mf++) {
        s16x8 a = *(const s16x8*)(A + (size_t)(m0 + mf * 16 + lr) * KSZ + kb + s * 32 + 2 * lk);
#pragma unroll
        for (int nf = 0; nf < 2; nf++)
          acc[mf][nf] = __builtin_amdgcn_mfma_f32_16x16x32_bf16(a, bfr[nf], acc[mf][nf], 0, 0, 0);
      }
    }
    if (it + 1 < NITER) STOREW((it + 1) & 1);
    __syncthreads();
  }

  // stage-1: write partials
#pragma unroll
  for (int mf = 0; mf < 2; mf++)
#pragma unroll
    for (int nf = 0; nf < 2; nf++)
#pragma unroll
      for (int r = 0; r < 4; r++) {
        int row = m0 + mf * 16 + lk + r;
        int col = n0 + nf * 16 + lr;
        part[((size_t)kz * MPAD_ + row) * 1024 + col] = acc[mf][nf][r];
      }

  // last-arriver reduction (no spin)
  __shared__ int lastS;
  __threadfence();
  __syncthreads();
  if (tid == 0) lastS = (atomicAdd(&cnt[strip * 2 + ms], 1) == 3);
  __syncthreads();
  if (!lastS) return;
  __threadfence();

  const int m0blk = ms * 256;
  for (int idx = tid; idx < 256 * 32; idx += 512) {
    int rr = idx >> 5, cc = idx & 31;
    int row = m0blk + rr, col = n0 + cc;
    size_t idxo = (size_t)row * 1024 + col;
    float h = 0.f;
    int bb = 0;
    if (row < MROWS_) {
      bb = row / HOR_;
      float s = part[((size_t)0 * MPAD_ + row) * 1024 + col] + part[((size_t)1 * MPAD_ + row) * 1024 + col] +
                part[((size_t)2 * MPAD_ + row) * 1024 + col] + part[((size_t)3 * MPAD_ + row) * 1024 + col];
      h = hprev[idxo] + gatev[(size_t)bb * 1024 + col] * s;
    }
    hout[idxo] = h;
    normOut[idxo] = f2bf(h * w2n[(size_t)bb * 1024 + col]);
    float p2 = h * h;
#pragma unroll
    for (int o = 16; o > 0; o >>= 1) p2 += __shfl_xor(p2, o);
    if ((idx & 31) == 0) ssOut[(size_t)strip * 512 + row] = p2;
  }
  if (tid == 0) cnt[strip * 2 + ms] = 0;   // self-reset for graph replay
}

// ================================================================ upgate dual GEMM (deferred rs) -> t=gelu(rs*g)*(rs*u)
// (validated round-11) grid (128 strips of 32, 2 m-halves), 512 thr, full-K NITER=8.
__global__ __launch_bounds__(512) void upg_k(const unsigned short* __restrict__ A, const float* __restrict__ ssP,
                                             const float* __restrict__ Wg, const float* __restrict__ Wu,
                                             unsigned short* __restrict__ tb) {
  const int st = blockIdx.x, mh = blockIdx.y;
  const int n0 = st * 32;
  const int tid = threadIdx.x, wv = tid >> 6, l = tid & 63;
  const int lr = l & 15, kg = l >> 4, lk = kg << 2;
  const int m0blk = mh * 256, m0 = m0blk + wv * 32;

  __shared__ unsigned short Wt[2][64][LST_];
  __shared__ float rsL[256];
  const int pr = tid >> 3, c0 = (tid & 7) * 4;

  if (tid < 256) {
    int row = m0blk + tid;
    float rs = 1.f;
    if (row < MROWS_) {
      float ss = 0.f;
#pragma unroll
      for (int p = 0; p < 32; p++) ss += ssP[(size_t)p * 512 + row];
      rs = rsqrtf(ss * (1.f / 1024.f) + 1e-6f);
    }
    rsL[tid] = rs;
  }

  f32x4 acc[2][4];
#pragma unroll
  for (int a = 0; a < 2; a++)
#pragma unroll
    for (int b = 0; b < 4; b++) acc[a][b] = (f32x4){0.f, 0.f, 0.f, 0.f};

  f32x4 pa0, pa1, pb0, pb1;
  auto LOADW = [&](int IT) {
    size_t kk = (size_t)IT * KSTEP_ + 2 * pr;
    pa0 = *(const f32x4*)(Wg + kk * 4096 + n0 + c0);
    pa1 = *(const f32x4*)(Wg + (kk + 1) * 4096 + n0 + c0);
    pb0 = *(const f32x4*)(Wu + kk * 4096 + n0 + c0);
    pb1 = *(const f32x4*)(Wu + (kk + 1) * 4096 + n0 + c0);
  };
  auto STOREW = [&](int BUF) {
#pragma unroll
    for (int j = 0; j < 4; j++) {
      unsigned v = (unsigned)f2bf(pa0[j]) | ((unsigned)f2bf(pa1[j]) << 16);
      *(unsigned*)&Wt[BUF][c0 + j][2 * pr] = v;
      unsigned u = (unsigned)f2bf(pb0[j]) | ((unsigned)f2bf(pb1[j]) << 16);
      *(unsigned*)&Wt[BUF][32 + c0 + j][2 * pr] = u;
    }
  };

  LOADW(0);
  STOREW(0);
  __syncthreads();

  for (int it = 0; it < 8; ++it) {
    if (it + 1 < 8) LOADW(it + 1);
    const int cur = it & 1, kb = it * KSTEP_;
#pragma unroll
    for (int s = 0; s < 4; s++) {
      s16x8 bfr[4];
#pragma unroll
      for (int nf = 0; nf < 4; nf++) {
        const unsigned short* wp = &Wt[cur][nf * 16 + lr][s * 32 + 2 * lk];
        s16x4 b0 = *(const s16x4*)wp;
        s16x4 b1 = *(const s16x4*)(wp + 4);
#pragma unroll
        for (int j = 0; j < 4; j++) { bfr[nf][j] = b0[j]; bfr[nf][4 + j] = b1[j]; }
      }
#pragma unroll
      for (int mf = 0; mf < 2; mf++) {
        s16x8 a = *(const s16x8*)(A + (size_t)(m0 + mf * 16 + lr) * H_ + kb + s * 32 + 8 * kg);
#pragma unroll
        for (int nf = 0; nf < 4; nf++)
          acc[mf][nf] = __builtin_amdgcn_mfma_f32_16x16x32_bf16(a, bfr[nf], acc[mf][nf], 0, 0, 0);
      }
    }
    if (it + 1 < 8) STOREW((it + 1) & 1);
    __syncthreads();
  }

#pragma unroll
  for (int mf = 0; mf < 2; mf++)
#pragma unroll
    for (int nf = 0; nf < 2; nf++)
#pragma unroll
      for (int r = 0; r < 4; r++) {
        int row = m0 + mf * 16 + lk + r;
        if (row >= MROWS_) continue;
        float rs = rsL[row - m0blk];
        int col = n0 + nf * 16 + lr;
        float g = rs * acc[mf][nf][r];
        float u = rs * acc[mf][nf + 2][r];
        g = 0.5f * g * (1.f + tanhf(0.7978845608028654f * (g + 0.044715f * g * g * g)));
        tb[(size_t)row * 4096 + col] = f2bf(g * u);
      }
}

// ---------------------------------------------------------------- out = rs*(normRaw @ action_out_w) + b
__global__ __launch_bounds__(256) void fout2_k(const unsigned short* __restrict__ nf, const float* __restrict__ ssA,
                                               const float* __restrict__ Wo, const float* __restrict__ bo,
                                               float* __restrict__ out) {
  int m = blockIdx.x, tid = threadIdx.x;
  __shared__ float rsS;
  if (tid < 32) {
    float s = ssA[(size_t)tid * 512 + m];
#pragma unroll
    for (int o = 16; o > 0; o >>= 1) s += __shfl_xor(s, o);
    if (tid == 0) rsS = rsqrtf(s * (1.f / 1024.f) + 1e-6f);
  }
  int n = tid & 31, kg = tid >> 5;
  float acc = 0.f;
  for (int k = kg * 128; k < kg * 128 + 128; k++)
    acc += bf2f(nf[(size_t)m * H_ + k]) * Wo[(size_t)k * AD_ + n];
  __shared__ float red[8][32];
  red[kg][n] = acc;
  __syncthreads();
  if (kg == 0) {
    float v = 0.f;
#pragma unroll
    for (int g = 0; g < 8; g++) v += red[g][n];
    out[(size_t)m * AD_ + n] = rsS * v + bo[n];
  }
}

// ================================================================ host
extern "C" void kernel_launch(void* const* d_in, const int* in_sizes, int n_in,
                              void* d_out, int out_size, void* d_ws, size_t ws_size,
                              hipStream_t stream) {
  const float* prefix_keys   = (const float*)d_in[0];
  const float* prefix_values = (const float*)d_in[1];
  const float* x_t           = (const float*)d_in[2];
  const float* timestep      = (const float*)d_in[3];
  const unsigned char* pad_mask = (const unsigned char*)d_in[4];
  const float* action_in_w   = (const float*)d_in[5];
  const float* action_in_b   = (const float*)d_in[6];
  const float* action_out_w  = (const float*)d_in[7];
  const float* action_out_b  = (const float*)d_in[8];
  const float* tmlp_in_w     = (const float*)d_in[9];
  const float* tmlp_in_b     = (const float*)d_in[10];
  const float* tmlp_out_w    = (const float*)d_in[11];
  const float* tmlp_out_b    = (const float*)d_in[12];
  const float* w_q    = (const float*)d_in[13];
  const float* w_k    = (const float*)d_in[14];
  const float* w_v    = (const float*)d_in[15];
  const float* w_o    = (const float*)d_in[16];
  const float* w_gate = (const float*)d_in[17];
  const float* w_up   = (const float*)d_in[18];
  const float* w_down = (const float*)d_in[19];
  const float* in_norm_w    = (const float*)d_in[20];
  const float* in_scale_w   = (const float*)d_in[21];
  const float* in_gate_w    = (const float*)d_in[22];
  const float* post_norm_w  = (const float*)d_in[23];
  const float* post_scale_w = (const float*)d_in[24];
  const float* post_gate_w  = (const float*)d_in[25];
  const float* fnorm_w       = (const float*)d_in[26];
  const float* fnorm_scale_w = (const float*)d_in[27];

  char* wsp = (char*)d_ws;
  auto alloc = [&](size_t bytes) { void* p = (void*)wsp; wsp += (bytes + 255) & ~(size_t)255; return p; };

  float* emb0   = (float*)alloc((size_t)8 * H_ * 4);
  float* emb1   = (float*)alloc((size_t)8 * H_ * 4);
  float* cond   = (float*)alloc((size_t)8 * H_ * 4);
  float* fscale = (float*)alloc((size_t)8 * H_ * 4);
  float* gates  = (float*)alloc((size_t)4 * L_ * 8 * H_ * 4);
  float* w2all  = (float*)alloc((size_t)37 * 8 * H_ * 4);
  int*   offs   = (int*)alloc(64);
  int*   cntA   = (int*)alloc(64 * 4);
  int*   cntB   = (int*)alloc(64 * 4);
  float* hbuf   = (float*)alloc((size_t)MPAD_ * H_ * 4);
  float* h1buf  = (float*)alloc((size_t)MPAD_ * H_ * 4);
  float* ssA    = (float*)alloc((size_t)32 * 512 * 4);
  float* ssP    = (float*)alloc((size_t)32 * 512 * 4);
  unsigned short* normed  = (unsigned short*)alloc((size_t)MPAD_ * H_ * 2);
  unsigned short* normed2 = (unsigned short*)alloc((size_t)MPAD_ * H_ * 2);
  unsigned short* q_r     = (unsigned short*)alloc((size_t)B_ * NH_ * 64 * HD_ * 2);
  unsigned short* Kf_all  = (unsigned short*)alloc((size_t)L_ * B_ * TPAD_ * HD_ * 2);
  unsigned short* Vt_all  = (unsigned short*)alloc((size_t)L_ * B_ * HD_ * TPAD_ * 2);
  unsigned short* attb    = (unsigned short*)alloc((size_t)MPAD_ * 2048 * 2);
  unsigned short* t_buf   = (unsigned short*)alloc((size_t)MPAD_ * FF_ * 2);
  float* wopart = (float*)alloc((size_t)4 * MPAD_ * 1024 * 4);
  float* dpart  = (float*)alloc((size_t)4 * MPAD_ * 1024 * 4);

  // counters start at 0 (self-reset each use; memset idempotent across replays)
  hipMemsetAsync(cntA, 0, 64 * 4, stream);
  hipMemsetAsync(cntB, 0, 64 * 4, stream);
  // attb pad rows never written by flash8: zero once (stays zero all layers)
  hipMemsetAsync(attb + (size_t)MROWS_ * 2048, 0, (size_t)(MPAD_ - MROWS_) * 2048 * 2, stream);

  emb_k<<<8, 256, 0, stream>>>(timestep, emb0);
  gemm8_k<<<16, 256, 0, stream>>>(emb0, tmlp_in_w, tmlp_in_b, emb1, 1);
  gemm8_k<<<16, 256, 0, stream>>>(emb1, tmlp_out_w, tmlp_out_b, cond, 1);
  gemm8_k<<<16, 256, 0, stream>>>(cond, fnorm_scale_w, nullptr, fscale, 0);
  gates_k<<<dim3(16, L_, 4), 256, 0, stream>>>(cond, in_scale_w, in_gate_w, post_scale_w, post_gate_w, gates);
  w2p_k<<<dim3(37, 8), 256, 0, stream>>>(in_norm_w, post_norm_w, fnorm_w, gates, fscale, w2all);
  offs_k<<<1, 256, 0, stream>>>(pad_mask, offs);
  action_in_k<<<(MPAD_ * H_) / 256, 256, 0, stream>>>(x_t, action_in_w, action_in_b, hbuf);
  prefixAll_k<<<dim3(16, B_, L_), 256, 0, stream>>>(prefix_keys, prefix_values, Kf_all, Vt_all);
  ada_k<<<MPAD_, 256, 0, stream>>>(hbuf, in_norm_w, gates, normed);  // layer-0: fully normed, rs folded

  for (int i = 0; i < L_; i++) {
    const float* wq_i = w_q + (size_t)i * H_ * 2048;
    const float* wk_i = w_k + (size_t)i * H_ * HD_;
    const float* wv_i = w_v + (size_t)i * H_ * HD_;
    const float* wo_i = w_o + (size_t)i * 2048 * H_;
    const float* wg_i = w_gate + (size_t)i * H_ * FF_;
    const float* wu_i = w_up + (size_t)i * H_ * FF_;
    const float* wd_i = w_down + (size_t)i * FF_ * H_;
    const float* g_in_gate   = gates + ((size_t)(1 * L_ + i) * 8) * H_;
    const float* g_post_gate = gates + ((size_t)(3 * L_ + i) * 8) * H_;
    const float* w2_post = w2all + (size_t)(18 + i) * 8 * H_;
    const float* w2_next = (i + 1 < L_) ? w2all + (size_t)(i + 1) * 8 * H_ : w2all + (size_t)36 * 8 * H_;
    unsigned short* Kf_l = Kf_all + (size_t)i * B_ * TPAD_ * HD_;
    unsigned short* Vt_l = Vt_all + (size_t)i * B_ * HD_ * TPAD_;

    qkvF_k<<<dim3(80, 2), 512, 0, stream>>>(normed, (i == 0) ? nullptr : ssA, wq_i, wk_i, wv_i, offs,
                                            q_r, Kf_l, Vt_l);
    flash8_k<<<dim3(B_, 4, NH_), 512, 0, stream>>>(q_r, Kf_l, Vt_l, attb);
    gemmR_k<2048><<<dim3(32, 4, 2), 512, 0, stream>>>(attb, wo_i, wopart, cntA, hbuf, g_in_gate,
                                                      w2_post, h1buf, normed2, ssP);
    upg_k<<<dim3(128, 2), 512, 0, stream>>>(normed2, ssP, wg_i, wu_i, t_buf);
    gemmR_k<4096><<<dim3(32, 4, 2), 512, 0, stream>>>(t_buf, wd_i, dpart, cntB, h1buf, g_post_gate,
                                                      w2_next, hbuf, normed, ssA);
  }

  fout2_k<<<MROWS_, 256, 0, stream>>>(normed, ssA, action_out_w, action_out_b, (float*)d_out);
}

// Round 14
// 2665.402 us; speedup vs baseline: 1.9978x; 1.9978x over previous
//
#include <hip/hip_runtime.h>

#define L_ 18
#define H_ 1024
#define NH_ 8
#define HD_ 256
#define FF_ 4096
#define HOR_ 50
#define PRE_ 968
#define B_ 8
#define AD_ 32
#define TPAD_ 1024
#define MROWS_ 400
#define MPAD_ 512
#define KSTEP_ 128
#define LST_ 132

typedef float f32x4 __attribute__((ext_vector_type(4)));
typedef short s16x4 __attribute__((ext_vector_type(4)));
typedef short s16x8 __attribute__((ext_vector_type(8)));
typedef unsigned short u16x8 __attribute__((ext_vector_type(8)));

__device__ __forceinline__ unsigned short f2bf(float f) {
  unsigned u = __float_as_uint(f);
  u += 0x7FFFu + ((u >> 16) & 1u);
  return (unsigned short)(u >> 16);
}
__device__ __forceinline__ float bf2f(unsigned short h) {
  return __uint_as_float(((unsigned)h) << 16);
}
__device__ __forceinline__ float wave_sum(float v) {
#pragma unroll
  for (int o = 32; o > 0; o >>= 1) v += __shfl_xor(v, o);
  return v;
}

// ---------------------------------------------------------------- time embedding
__global__ __launch_bounds__(256) void emb_k(const float* __restrict__ ts, float* __restrict__ emb) {
  int b = blockIdx.x, tid = threadIdx.x;
  float t = ts[b];
  for (int j = tid; j < 512; j += 256) {
    float ang = 1570.7963267948966f * expf((float)j * (-6.907755278982137f / 511.0f)) * t;
    emb[(size_t)b * H_ + j] = sinf(ang);
    emb[(size_t)b * H_ + 512 + j] = cosf(ang);
  }
}

// ---------------------------------------------------------------- [8,1024]@[1024,1024] (+bias,+silu)
__global__ __launch_bounds__(256) void gemm8_k(const float* __restrict__ A8, const float* __restrict__ W,
                                               const float* __restrict__ bias, float* __restrict__ out,
                                               int act) {
  __shared__ float a_s[8 * 1024];
  __shared__ float red[4][8][64];
  int tid = threadIdx.x;
  for (int i = tid; i < 8 * 1024; i += 256) a_s[i] = A8[i];
  __syncthreads();
  int nl = tid & 63, kg = tid >> 6;
  int n = blockIdx.x * 64 + nl;
  float acc[8];
#pragma unroll
  for (int m = 0; m < 8; m++) acc[m] = 0.f;
  for (int k = kg * 256; k < kg * 256 + 256; k++) {
    float wv = W[(size_t)k * 1024 + n];
#pragma unroll
    for (int m = 0; m < 8; m++) acc[m] += a_s[m * 1024 + k] * wv;
  }
#pragma unroll
  for (int m = 0; m < 8; m++) red[kg][m][nl] = acc[m];
  __syncthreads();
  if (kg == 0) {
#pragma unroll
    for (int m = 0; m < 8; m++) {
      float v = red[0][m][nl] + red[1][m][nl] + red[2][m][nl] + red[3][m][nl];
      if (bias) v += bias[n];
      if (act) v = v / (1.f + expf(-v));
      out[(size_t)m * 1024 + n] = v;
    }
  }
}

// ---------------------------------------------------------------- all 72 adaLN cond GEMMs in one grid
__global__ __launch_bounds__(256) void gates_k(const float* __restrict__ cond,
                                               const float* __restrict__ w0, const float* __restrict__ w1,
                                               const float* __restrict__ w2, const float* __restrict__ w3,
                                               float* __restrict__ gates) {
  __shared__ float a_s[8 * 1024];
  __shared__ float red[4][8][64];
  int tid = threadIdx.x;
  for (int i = tid; i < 8 * 1024; i += 256) a_s[i] = cond[i];
  __syncthreads();
  int z = blockIdx.z, layer = blockIdx.y;
  const float* W = (z == 0 ? w0 : z == 1 ? w1 : z == 2 ? w2 : w3) + (size_t)layer * H_ * H_;
  float* out = gates + ((size_t)(z * L_ + layer) * 8) * H_;
  int nl = tid & 63, kg = tid >> 6;
  int n = blockIdx.x * 64 + nl;
  float acc[8];
#pragma unroll
  for (int m = 0; m < 8; m++) acc[m] = 0.f;
  for (int k = kg * 256; k < kg * 256 + 256; k++) {
    float wv = W[(size_t)k * 1024 + n];
#pragma unroll
    for (int m = 0; m < 8; m++) acc[m] += a_s[m * 1024 + k] * wv;
  }
#pragma unroll
  for (int m = 0; m < 8; m++) red[kg][m][nl] = acc[m];
  __syncthreads();
  if (kg == 0) {
#pragma unroll
    for (int m = 0; m < 8; m++)
      out[(size_t)m * 1024 + n] = red[0][m][nl] + red[1][m][nl] + red[2][m][nl] + red[3][m][nl];
  }
}

// ---------------------------------------------------------------- pad-mask -> per-batch valid counts
__global__ void offs_k(const unsigned char* __restrict__ mask, int* __restrict__ offs) {
  __shared__ int cnt[8];
  __shared__ int mod4;
  int tid = threadIdx.x;
  if (tid < 8) cnt[tid] = 0;
  if (tid == 8) mod4 = 0;
  __syncthreads();
  for (int i = tid; i < B_ * PRE_; i += 256) {
    unsigned char v = mask[i];
    if (v) {
      atomicAdd(&cnt[i / PRE_], 1);
      if (i & 3) atomicAdd(&mod4, 1);
    }
  }
  __syncthreads();
  if (tid < 8) offs[tid] = (mod4 == 0) ? cnt[tid] * 4 : cnt[tid];
}

// ---------------------------------------------------------------- h = x_t @ action_in_w + b  (pad rows = 0)
__global__ __launch_bounds__(256) void action_in_k(const float* __restrict__ xt, const float* __restrict__ Wi,
                                                   const float* __restrict__ bi, float* __restrict__ h) {
  int idx = blockIdx.x * 256 + threadIdx.x;
  int m = idx >> 10, n = idx & 1023;
  float v = 0.f;
  if (m < MROWS_) {
    const float* xr = xt + (size_t)m * AD_;
#pragma unroll
    for (int k = 0; k < AD_; k++) v += xr[k] * Wi[(size_t)k * H_ + n];
    v += bi[n];
  }
  h[idx] = v;
}

// ---------------------------------------------------------------- AdaRMSNorm -> bf16 (pad rows = 0), layer-0 only
__global__ __launch_bounds__(256) void ada_k(const float* __restrict__ X, const float* __restrict__ nw,
                                             const float* __restrict__ sc, unsigned short* __restrict__ Y) {
  int m = blockIdx.x, tid = threadIdx.x;
  size_t base = (size_t)m * H_;
  if (m >= MROWS_) {
#pragma unroll
    for (int j = 0; j < 4; j++) Y[base + tid * 4 + j] = 0;
    return;
  }
  f32x4 x = *(const f32x4*)(X + base + tid * 4);
  float ss = x[0] * x[0] + x[1] * x[1] + x[2] * x[2] + x[3] * x[3];
  __shared__ float r4[4];
  float wsv = wave_sum(ss);
  if ((tid & 63) == 0) r4[tid >> 6] = wsv;
  __syncthreads();
  float rs = rsqrtf((r4[0] + r4[1] + r4[2] + r4[3]) * (1.f / 1024.f) + 1e-6f);
  int b = m / HOR_;
#pragma unroll
  for (int j = 0; j < 4; j++) {
    int n = tid * 4 + j;
    Y[base + n] = f2bf(x[j] * rs * (1.f + nw[n]) * (1.f + sc[(size_t)b * H_ + n]));
  }
}

// ---------------------------------------------------------------- all-layer prefix convert: K row-major, V transposed
__global__ __launch_bounds__(256) void prefixAll_k(const float* __restrict__ pk, const float* __restrict__ pv,
                                                   unsigned short* __restrict__ Kf_all,
                                                   unsigned short* __restrict__ Vt_all) {
  int b = blockIdx.y, t0 = blockIdx.x * 64, layer = blockIdx.z, tid = threadIdx.x;
  unsigned short* Kf = Kf_all + (size_t)layer * B_ * TPAD_ * HD_;
  unsigned short* Vt = Vt_all + (size_t)layer * B_ * HD_ * TPAD_;
  __shared__ unsigned short vt[256][72];
  const float* kp = pk + ((size_t)(b * L_ + layer)) * PRE_ * HD_;
  const float* vp = pv + ((size_t)(b * L_ + layer)) * PRE_ * HD_;
  for (int i = 0; i < 64; i++) {
    int t = t0 + i;
    float kv = 0.f, vv = 0.f;
    if (t < PRE_) {
      kv = kp[(size_t)t * HD_ + tid];
      vv = vp[(size_t)t * HD_ + tid];
    }
    Kf[((size_t)b * TPAD_ + t) * HD_ + tid] = f2bf(kv);  // suffix rows rewritten per layer by qkvF
    vt[tid][i] = f2bf(vv);
  }
  __syncthreads();
#pragma unroll
  for (int p = 0; p < 4; p++) {
    int d = p * 64 + (tid >> 2);
    int c0 = (tid & 3) * 16;
    u16x8 v0, v1;
#pragma unroll
    for (int j = 0; j < 8; j++) { v0[j] = vt[d][c0 + j]; v1[j] = vt[d][c0 + 8 + j]; }
    size_t dst = ((size_t)(b * HD_ + d)) * TPAD_ + t0 + c0;
    *(u16x8*)(Vt + dst) = v0;
    *(u16x8*)(Vt + dst + 8) = v1;
  }
}

// ================================================================ QKV GEMM (bf16 A, reg-pipelined) + RoPE/scatter
// grid (80 strips, 2 m-halves), 512 thr.
__global__ __launch_bounds__(512) void qkvF_k(const unsigned short* __restrict__ A,
                                              const float* __restrict__ Wq, const float* __restrict__ Wk,
                                              const float* __restrict__ Wv, const int* __restrict__ offs,
                                              unsigned short* __restrict__ q_r, unsigned short* __restrict__ Kf,
                                              unsigned short* __restrict__ Vt) {
  const int st = blockIdx.x, mh = blockIdx.y;
  const int tid = threadIdx.x, wv = tid >> 6, l = tid & 63;
  const int lr = l & 15, kg = l >> 4, lk = kg << 2;
  const int m0 = mh * 256 + wv * 32;

  const float* W;
  int ldw, wbase;
  bool paired;
  if (st < 64)      { W = Wq; ldw = 2048; wbase = (st >> 3) * 256 + (st & 7) * 16; paired = true; }
  else if (st < 72) { W = Wk; ldw = 256;  wbase = (st - 64) * 16; paired = true; }
  else              { W = Wv; ldw = 256;  wbase = (st - 72) * 32; paired = false; }

  __shared__ unsigned short Wt[2][32][LST_];
  __shared__ int offsL[8];
  const int pr = tid >> 3, c0 = (tid & 7) * 4;
  const int wcol = wbase + c0 + ((paired && c0 >= 16) ? 112 : 0);

  if (tid < 8) offsL[tid] = offs[tid];

  f32x4 acc[2][2];
#pragma unroll
  for (int a = 0; a < 2; a++)
#pragma unroll
    for (int b = 0; b < 2; b++) acc[a][b] = (f32x4){0.f, 0.f, 0.f, 0.f};

  f32x4 pa0, pa1;
  auto LOADW = [&](int IT) {
    size_t kk = (size_t)IT * KSTEP_ + 2 * pr;
    pa0 = *(const f32x4*)(W + kk * ldw + wcol);
    pa1 = *(const f32x4*)(W + (kk + 1) * ldw + wcol);
  };
  auto STOREW = [&](int BUF) {
#pragma unroll
    for (int j = 0; j < 4; j++) {
      unsigned v = (unsigned)f2bf(pa0[j]) | ((unsigned)f2bf(pa1[j]) << 16);
      *(unsigned*)&Wt[BUF][c0 + j][2 * pr] = v;
    }
  };

  // register-pipelined A fragments
  s16x8 aP[2][4];
  auto LOADA = [&](int IT) {
    const int kb = IT * KSTEP_;
#pragma unroll
    for (int s = 0; s < 4; s++)
#pragma unroll
      for (int mf = 0; mf < 2; mf++)
        aP[mf][s] = *(const s16x8*)(A + (size_t)(m0 + mf * 16 + lr) * H_ + kb + s * 32 + 8 * kg);
  };

  LOADW(0);
  LOADA(0);
  STOREW(0);
  __syncthreads();

  for (int it = 0; it < 8; ++it) {
    if (it + 1 < 8) LOADW(it + 1);
    const int cur = it & 1;
#pragma unroll
    for (int s = 0; s < 4; s++) {
      s16x8 bfr[2];
#pragma unroll
      for (int nf = 0; nf < 2; nf++) {
        const unsigned short* wp = &Wt[cur][nf * 16 + lr][s * 32 + 2 * lk];
        s16x4 b0 = *(const s16x4*)wp;
        s16x4 b1 = *(const s16x4*)(wp + 4);
#pragma unroll
        for (int j = 0; j < 4; j++) { bfr[nf][j] = b0[j]; bfr[nf][4 + j] = b1[j]; }
      }
#pragma unroll
      for (int mf = 0; mf < 2; mf++)
#pragma unroll
        for (int nf = 0; nf < 2; nf++)
          acc[mf][nf] = __builtin_amdgcn_mfma_f32_16x16x32_bf16(aP[mf][s], bfr[nf], acc[mf][nf], 0, 0, 0);
    }
    if (it + 1 < 8) {
      LOADA(it + 1);          // issue next-iter A before the barrier (hides L2 latency)
      STOREW((it + 1) & 1);
    }
    __syncthreads();
  }

  const float RK = -9.210340371976184f / 128.0f;
  if (st < 64) {  // Q: rope pair, write q_r
    const int h = st >> 3, x = (st & 7) * 16, dd = x + lr;
    const float inv = expf((float)dd * RK);
#pragma unroll
    for (int mf = 0; mf < 2; mf++)
#pragma unroll
      for (int r = 0; r < 4; r++) {
        int m = m0 + mf * 16 + lk + r;
        if (m >= MROWS_) continue;
        int b = m / HOR_, s = m - b * HOR_;
        float ang = (float)(offsL[b] + s) * inv;
        float cc = cosf(ang), sn = sinf(ang);
        float v1 = acc[mf][0][r], v2 = acc[mf][1][r];
        size_t base = ((size_t)(b * NH_ + h) * 64 + s) * HD_;
        q_r[base + dd] = f2bf(v1 * cc - v2 * sn);
        q_r[base + dd + 128] = f2bf(v2 * cc + v1 * sn);
      }
  } else if (st < 72) {  // K: rope pair, write Kf suffix rows
    const int x = (st - 64) * 16, dd = x + lr;
    const float inv = expf((float)dd * RK);
#pragma unroll
    for (int mf = 0; mf < 2; mf++)
#pragma unroll
      for (int r = 0; r < 4; r++) {
        int m = m0 + mf * 16 + lk + r;
        if (m >= MROWS_) continue;
        int b = m / HOR_, s = m - b * HOR_;
        float ang = (float)(offsL[b] + s) * inv;
        float cc = cosf(ang), sn = sinf(ang);
        float v1 = acc[mf][0][r], v2 = acc[mf][1][r];
        size_t base = ((size_t)b * TPAD_ + PRE_ + s) * HD_;
        Kf[base + dd] = f2bf(v1 * cc - v2 * sn);
        Kf[base + dd + 128] = f2bf(v2 * cc + v1 * sn);
      }
  } else {  // V: write Vt columns
    const int x = (st - 72) * 32;
#pragma unroll
    for (int mf = 0; mf < 2; mf++)
#pragma unroll
      for (int nf = 0; nf < 2; nf++)
#pragma unroll
        for (int r = 0; r < 4; r++) {
          int m = m0 + mf * 16 + lk + r;
          if (m >= MROWS_) continue;
          int b = m / HOR_, s = m - b * HOR_;
          int d = x + nf * 16 + lr;
          Vt[((size_t)(b * HD_ + d)) * TPAD_ + PRE_ + s] = f2bf(acc[mf][nf][r]);
        }
  }
}

// ================================================================ 8-wave flash attention (validated round-12)
// grid (B, 4 rg, NH) [b = bid%8 -> per-batch KV pinned to one XCD's L2]. 512 thr = 8 waves.
__global__ __launch_bounds__(512) void flash8_k(const unsigned short* __restrict__ qr,
                                                const unsigned short* __restrict__ Kf,
                                                const unsigned short* __restrict__ Vt,
                                                unsigned short* __restrict__ attb) {
  const int b = blockIdx.x, rg = blockIdx.y, h = blockIdx.z;
  const int bh = b * NH_ + h;
  const int tid = threadIdx.x, w = tid >> 6, l = tid & 63;
  const int lr = l & 15, kg = l >> 4;
  const int t0 = w * 128;

  __shared__ __align__(16) unsigned short Pl[8][16][136];
  __shared__ float mlS[8][16][2];

  const unsigned short* qbase = qr + ((size_t)bh * 64 + rg * 16 + lr) * HD_;
  s16x8 afr[8];
#pragma unroll
  for (int js = 0; js < 8; js++) afr[js] = *(const s16x8*)(qbase + js * 32 + 8 * kg);
  f32x4 sc[8];
#pragma unroll
  for (int nf = 0; nf < 8; nf++) sc[nf] = (f32x4){0.f, 0.f, 0.f, 0.f};
  const unsigned short* kb = Kf + ((size_t)b * TPAD_ + t0) * HD_;
#pragma unroll
  for (int js = 0; js < 8; js++)
#pragma unroll
    for (int nf = 0; nf < 8; nf++) {
      s16x8 bv = *(const s16x8*)(kb + (size_t)(nf * 16 + lr) * HD_ + js * 32 + 8 * kg);
      sc[nf] = __builtin_amdgcn_mfma_f32_16x16x32_bf16(afr[js], bv, sc[nf], 0, 0, 0);
    }
  float mx[4] = {-3.0e38f, -3.0e38f, -3.0e38f, -3.0e38f};
#pragma unroll
  for (int nf = 0; nf < 8; nf++) {
    int t = t0 + nf * 16 + lr;
#pragma unroll
    for (int r = 0; r < 4; r++) {
      int srw = rg * 16 + 4 * kg + r;
      float v = sc[nf][r] * 0.0625f;
      if (t >= PRE_ && (t - PRE_) > srw) v = -1e9f;
      sc[nf][r] = v;
      mx[r] = fmaxf(mx[r], v);
    }
  }
#pragma unroll
  for (int o = 8; o > 0; o >>= 1)
#pragma unroll
    for (int r = 0; r < 4; r++) mx[r] = fmaxf(mx[r], __shfl_xor(mx[r], o));
  float ls[4] = {0.f, 0.f, 0.f, 0.f};
#pragma unroll
  for (int nf = 0; nf < 8; nf++)
#pragma unroll
    for (int r = 0; r < 4; r++) {
      float p = expf(sc[nf][r] - mx[r]);
      sc[nf][r] = p;
      ls[r] += p;
    }
#pragma unroll
  for (int o = 8; o > 0; o >>= 1)
#pragma unroll
    for (int r = 0; r < 4; r++) ls[r] += __shfl_xor(ls[r], o);
#pragma unroll
  for (int nf = 0; nf < 8; nf++)
#pragma unroll
    for (int r = 0; r < 4; r++) Pl[w][4 * kg + r][nf * 16 + lr] = f2bf(sc[nf][r]);
  if (lr == 0) {
#pragma unroll
    for (int r = 0; r < 4; r++) {
      mlS[w][4 * kg + r][0] = mx[r];
      mlS[w][4 * kg + r][1] = ls[r];
    }
  }
  __syncthreads();
  f32x4 o4[8][2];
#pragma unroll
  for (int a = 0; a < 8; a++)
#pragma unroll
    for (int c = 0; c < 2; c++) o4[a][c] = (f32x4){0.f, 0.f, 0.f, 0.f};
#pragma unroll
  for (int wz = 0; wz < 8; wz++)
#pragma unroll
    for (int ti = 0; ti < 128; ti += 32) {
      s16x8 a = *(const s16x8*)&Pl[wz][lr][ti + 8 * kg];
#pragma unroll
      for (int nf = 0; nf < 2; nf++) {
        s16x8 bv = *(const s16x8*)(Vt + ((size_t)(b * HD_ + w * 32 + nf * 16 + lr)) * TPAD_ +
                                   wz * 128 + ti + 8 * kg);
        o4[wz][nf] = __builtin_amdgcn_mfma_f32_16x16x32_bf16(a, bv, o4[wz][nf], 0, 0, 0);
      }
    }
#pragma unroll
  for (int r = 0; r < 4; r++) {
    int row = 4 * kg + r;
    int s = rg * 16 + row;
    if (s >= HOR_) continue;
    float M = -3.0e38f;
#pragma unroll
    for (int wz = 0; wz < 8; wz++) M = fmaxf(M, mlS[wz][row][0]);
    float w8[8], Lden = 0.f;
#pragma unroll
    for (int wz = 0; wz < 8; wz++) {
      w8[wz] = expf(mlS[wz][row][0] - M);
      Lden += w8[wz] * mlS[wz][row][1];
    }
    float invL = 1.f / Lden;
#pragma unroll
    for (int nf = 0; nf < 2; nf++) {
      float o = 0.f;
#pragma unroll
      for (int wz = 0; wz < 8; wz++) o += w8[wz] * o4[wz][nf][r];
      attb[((size_t)(b * HOR_ + s)) * 2048 + h * HD_ + w * 32 + nf * 16 + lr] = f2bf(o * invL);
    }
  }
}

// ================================================================ split-K MFMA GEMM stage 1 (reg-pipelined A)
// MODE 1=WO, 2=UPGATE(dual; t=gelu(g)*u bf16), 3=DOWN. NS=K-split, MS=M-split. 512 thr.
template <int MODE, int NS, int MS>
__global__ __launch_bounds__(512) void gemmS_k(const unsigned short* __restrict__ A, int lda, int Ksz,
                                               const float* __restrict__ W0, const float* __restrict__ W1,
                                               float* __restrict__ part, unsigned short* __restrict__ outT) {
  constexpr int NCOL = (MODE == 2) ? 64 : 32;
  constexpr int NF = NCOL / 16;
  constexpr int RPW = 64 / MS;
  constexpr int MFC = RPW / 16;
  const int tid = threadIdx.x;
  const int wv = tid >> 6, l = tid & 63;
  const int lr = l & 15, lk = (l >> 4) << 2;
  const int n0 = blockIdx.x * 32;
  const int kz = blockIdx.y;
  const int KC = Ksz / NS;
  const int kbase = kz * KC;
  const int m0 = (int)blockIdx.z * (512 / MS) + wv * RPW;

  const float* Wg = W0;
  const float* Wu = W1;
  const int ldw = (MODE == 2) ? 4096 : 1024;

  __shared__ unsigned short Wt[2][NCOL][LST_];
  const int pr = tid >> 3;
  const int c0 = (tid & 7) * 4;

  f32x4 acc[MFC][NF];
#pragma unroll
  for (int a = 0; a < MFC; a++)
#pragma unroll
    for (int b = 0; b < NF; b++) acc[a][b] = (f32x4){0.f, 0.f, 0.f, 0.f};

  const int niter = KC / KSTEP_;
  f32x4 pa0, pa1, pb0, pb1;

  auto LOADW = [&](int IT) {
    size_t kk = (size_t)(kbase + IT * KSTEP_ + 2 * pr);
    pa0 = *(const f32x4*)(Wg + kk * ldw + n0 + c0);
    pa1 = *(const f32x4*)(Wg + (kk + 1) * ldw + n0 + c0);
    if (MODE == 2) {
      pb0 = *(const f32x4*)(Wu + kk * ldw + n0 + c0);
      pb1 = *(const f32x4*)(Wu + (kk + 1) * ldw + n0 + c0);
    }
  };
  auto STOREW = [&](int BUF) {
#pragma unroll
    for (int j = 0; j < 4; j++) {
      unsigned v = (unsigned)f2bf(pa0[j]) | ((unsigned)f2bf(pa1[j]) << 16);
      *(unsigned*)&Wt[BUF][c0 + j][2 * pr] = v;
      if (MODE == 2) {
        unsigned u = (unsigned)f2bf(pb0[j]) | ((unsigned)f2bf(pb1[j]) << 16);
        *(unsigned*)&Wt[BUF][32 + c0 + j][2 * pr] = u;
      }
    }
  };

  // register-pipelined A fragments
  s16x8 aP[MFC][4];
  auto LOADA = [&](int IT) {
    const int kb = kbase + IT * KSTEP_;
#pragma unroll
    for (int s = 0; s < 4; s++)
#pragma unroll
      for (int mf = 0; mf < MFC; mf++)
        aP[mf][s] = *(const s16x8*)(A + (size_t)(m0 + mf * 16 + lr) * lda + kb + s * 32 + 2 * lk);
  };

  LOADW(0);
  LOADA(0);
  STOREW(0);
  __syncthreads();

  for (int it = 0; it < niter; ++it) {
    if (it + 1 < niter) LOADW(it + 1);
    const int cur = it & 1;
#pragma unroll
    for (int s = 0; s < 4; s++) {
      s16x8 bfr[NF];
#pragma unroll
      for (int nf = 0; nf < NF; nf++) {
        const unsigned short* wp = &Wt[cur][nf * 16 + lr][s * 32 + 2 * lk];
        s16x4 b0 = *(const s16x4*)wp;
        s16x4 b1 = *(const s16x4*)(wp + 4);
#pragma unroll
        for (int j = 0; j < 4; j++) { bfr[nf][j] = b0[j]; bfr[nf][4 + j] = b1[j]; }
      }
#pragma unroll
      for (int mf = 0; mf < MFC; mf++)
#pragma unroll
        for (int nf = 0; nf < NF; nf++)
          acc[mf][nf] = __builtin_amdgcn_mfma_f32_16x16x32_bf16(aP[mf][s], bfr[nf], acc[mf][nf], 0, 0, 0);
    }
    if (it + 1 < niter) {
      LOADA(it + 1);          // issue next-iter A before the barrier
      STOREW((it + 1) & 1);
    }
    __syncthreads();
  }

  if (MODE == 2) {
#pragma unroll
    for (int mf = 0; mf < MFC; mf++)
#pragma unroll
      for (int nf = 0; nf < 2; nf++)
#pragma unroll
        for (int r = 0; r < 4; r++) {
          int row = m0 + mf * 16 + lk + r;
          if (row >= MROWS_) continue;
          int col = n0 + nf * 16 + lr;
          float g = acc[mf][nf][r];
          float u = acc[mf][nf + 2][r];
          g = 0.5f * g * (1.f + tanhf(0.7978845608028654f * (g + 0.044715f * g * g * g)));
          outT[(size_t)row * 4096 + col] = f2bf(g * u);
        }
  } else {
#pragma unroll
    for (int mf = 0; mf < MFC; mf++)
#pragma unroll
      for (int nf = 0; nf < NF; nf++)
#pragma unroll
        for (int r = 0; r < 4; r++) {
          int row = m0 + mf * 16 + lk + r;
          if (row >= MROWS_) continue;
          int col = n0 + nf * 16 + lr;
          part[((size_t)kz * MPAD_ + row) * 1024 + col] = acc[mf][nf][r];
        }
  }
}

// ---------------------------------------------------------------- split-K reduce + residual-gate + AdaRMSNorm
// grid = MROWS_ (pad rows untouched: normed/normed2 pads stay zero from layer-0 ada_k; MFMA pad rows only
// influence pad outputs which are discarded).
template <int NS>
__global__ __launch_bounds__(256) void redA_k(const float* __restrict__ part, const float* __restrict__ prev,
                                              const float* __restrict__ gatev, const float* __restrict__ nw,
                                              const float* __restrict__ sc, float* __restrict__ outH,
                                              unsigned short* __restrict__ outN) {
  int r = blockIdx.x, tid = threadIdx.x;
  int c = tid * 4;
  int b = r / HOR_;
  f32x4 v = (f32x4){0.f, 0.f, 0.f, 0.f};
#pragma unroll
  for (int z = 0; z < NS; z++) v += *(const f32x4*)(part + ((size_t)z * MPAD_ + r) * H_ + c);
  f32x4 pv = *(const f32x4*)(prev + (size_t)r * H_ + c);
  f32x4 gv = *(const f32x4*)(gatev + (size_t)b * H_ + c);
  f32x4 h = pv + gv * v;
  *(f32x4*)(outH + (size_t)r * H_ + c) = h;
  float ss = h[0] * h[0] + h[1] * h[1] + h[2] * h[2] + h[3] * h[3];
  __shared__ float r4[4];
  float wsv = wave_sum(ss);
  if ((tid & 63) == 0) r4[tid >> 6] = wsv;
  __syncthreads();
  float rs = rsqrtf((r4[0] + r4[1] + r4[2] + r4[3]) * (1.f / 1024.f) + 1e-6f);
#pragma unroll
  for (int j = 0; j < 4; j++) {
    int n = c + j;
    outN[(size_t)r * H_ + n] = f2bf(h[j] * rs * (1.f + nw[n]) * (1.f + sc[(size_t)b * H_ + n]));
  }
}

// ================================================================ upgate dual GEMM (reg-pipelined A)
// grid (128 strips of 32, 2 m-halves), 512 thr, full-K NITER=8.
__global__ __launch_bounds__(512) void upg_k(const unsigned short* __restrict__ A, const float* __restrict__ Wg,
                                             const float* __restrict__ Wu, unsigned short* __restrict__ tb) {
  const int st = blockIdx.x, mh = blockIdx.y;
  const int n0 = st * 32;
  const int tid = threadIdx.x, wv = tid >> 6, l = tid & 63;
  const int lr = l & 15, kg = l >> 4, lk = kg << 2;
  const int m0 = mh * 256 + wv * 32;

  __shared__ unsigned short Wt[2][64][LST_];
  const int pr = tid >> 3, c0 = (tid & 7) * 4;

  f32x4 acc[2][4];
#pragma unroll
  for (int a = 0; a < 2; a++)
#pragma unroll
    for (int b = 0; b < 4; b++) acc[a][b] = (f32x4){0.f, 0.f, 0.f, 0.f};

  f32x4 pa0, pa1, pb0, pb1;
  auto LOADW = [&](int IT) {
    size_t kk = (size_t)IT * KSTEP_ + 2 * pr;
    pa0 = *(const f32x4*)(Wg + kk * 4096 + n0 + c0);
    pa1 = *(const f32x4*)(Wg + (kk + 1) * 4096 + n0 + c0);
    pb0 = *(const f32x4*)(Wu + kk * 4096 + n0 + c0);
    pb1 = *(const f32x4*)(Wu + (kk + 1) * 4096 + n0 + c0);
  };
  auto STOREW = [&](int BUF) {
#pragma unroll
    for (int j = 0; j < 4; j++) {
      unsigned v = (unsigned)f2bf(pa0[j]) | ((unsigned)f2bf(pa1[j]) << 16);
      *(unsigned*)&Wt[BUF][c0 + j][2 * pr] = v;
      unsigned u = (unsigned)f2bf(pb0[j]) | ((unsigned)f2bf(pb1[j]) << 16);
      *(unsigned*)&Wt[BUF][32 + c0 + j][2 * pr] = u;
    }
  };

  s16x8 aP[2][4];
  auto LOADA = [&](int IT) {
    const int kb = IT * KSTEP_;
#pragma unroll
    for (int s = 0; s < 4; s++)
#pragma unroll
      for (int mf = 0; mf < 2; mf++)
        aP[mf][s] = *(const s16x8*)(A + (size_t)(m0 + mf * 16 + lr) * H_ + kb + s * 32 + 8 * kg);
  };

  LOADW(0);
  LOADA(0);
  STOREW(0);
  __syncthreads();

  for (int it = 0; it < 8; ++it) {
    if (it + 1 < 8) LOADW(it + 1);
    const int cur = it & 1;
#pragma unroll
    for (int s = 0; s < 4; s++) {
      s16x8 bfr[4];
#pragma unroll
      for (int nf = 0; nf < 4; nf++) {
        const unsigned short* wp = &Wt[cur][nf * 16 + lr][s * 32 + 2 * lk];
        s16x4 b0 = *(const s16x4*)wp;
        s16x4 b1 = *(const s16x4*)(wp + 4);
#pragma unroll
        for (int j = 0; j < 4; j++) { bfr[nf][j] = b0[j]; bfr[nf][4 + j] = b1[j]; }
      }
#pragma unroll
      for (int mf = 0; mf < 2; mf++)
#pragma unroll
        for (int nf = 0; nf < 4; nf++)
          acc[mf][nf] = __builtin_amdgcn_mfma_f32_16x16x32_bf16(aP[mf][s], bfr[nf], acc[mf][nf], 0, 0, 0);
    }
    if (it + 1 < 8) {
      LOADA(it + 1);
      STOREW((it + 1) & 1);
    }
    __syncthreads();
  }

#pragma unroll
  for (int mf = 0; mf < 2; mf++)
#pragma unroll
    for (int nf = 0; nf < 2; nf++)
#pragma unroll
      for (int r = 0; r < 4; r++) {
        int row = m0 + mf * 16 + lk + r;
        if (row >= MROWS_) continue;
        int col = n0 + nf * 16 + lr;
        float g = acc[mf][nf][r];
        float u = acc[mf][nf + 2][r];
        g = 0.5f * g * (1.f + tanhf(0.7978845608028654f * (g + 0.044715f * g * g * g)));
        tb[(size_t)row * 4096 + col] = f2bf(g * u);
      }
}

// ---------------------------------------------------------------- out = normedF @ action_out_w + b
__global__ __launch_bounds__(256) void fout_k(const unsigned short* __restrict__ nf, const float* __restrict__ Wo,
                                              const float* __restrict__ bo, float* __restrict__ out) {
  int m = blockIdx.x, tid = threadIdx.x;
  int n = tid & 31, kg = tid >> 5;
  float acc = 0.f;
  for (int k = kg * 128; k < kg * 128 + 128; k++)
    acc += bf2f(nf[(size_t)m * H_ + k]) * Wo[(size_t)k * AD_ + n];
  __shared__ float red[8][32];
  red[kg][n] = acc;
  __syncthreads();
  if (kg == 0) {
    float v = 0.f;
#pragma unroll
    for (int g = 0; g < 8; g++) v += red[g][n];
    out[(size_t)m * AD_ + n] = v + bo[n];
  }
}

// ================================================================ host
extern "C" void kernel_launch(void* const* d_in, const int* in_sizes, int n_in,
                              void* d_out, int out_size, void* d_ws, size_t ws_size,
                              hipStream_t stream) {
  const float* prefix_keys   = (const float*)d_in[0];
  const float* prefix_values = (const float*)d_in[1];
  const float* x_t           = (const float*)d_in[2];
  const float* timestep      = (const float*)d_in[3];
  const unsigned char* pad_mask = (const unsigned char*)d_in[4];
  const float* action_in_w   = (const float*)d_in[5];
  const float* action_in_b   = (const float*)d_in[6];
  const float* action_out_w  = (const float*)d_in[7];
  const float* action_out_b  = (const float*)d_in[8];
  const float* tmlp_in_w     = (const float*)d_in[9];
  const float* tmlp_in_b     = (const float*)d_in[10];
  const float* tmlp_out_w    = (const float*)d_in[11];
  const float* tmlp_out_b    = (const float*)d_in[12];
  const float* w_q    = (const float*)d_in[13];
  const float* w_k    = (const float*)d_in[14];
  const float* w_v    = (const float*)d_in[15];
  const float* w_o    = (const float*)d_in[16];
  const float* w_gate = (const float*)d_in[17];
  const float* w_up   = (const float*)d_in[18];
  const float* w_down = (const float*)d_in[19];
  const float* in_norm_w    = (const float*)d_in[20];
  const float* in_scale_w   = (const float*)d_in[21];
  const float* in_gate_w    = (const float*)d_in[22];
  const float* post_norm_w  = (const float*)d_in[23];
  const float* post_scale_w = (const float*)d_in[24];
  const float* post_gate_w  = (const float*)d_in[25];
  const float* fnorm_w       = (const float*)d_in[26];
  const float* fnorm_scale_w = (const float*)d_in[27];

  char* wsp = (char*)d_ws;
  auto alloc = [&](size_t bytes) { void* p = (void*)wsp; wsp += (bytes + 255) & ~(size_t)255; return p; };

  float* emb0   = (float*)alloc((size_t)8 * H_ * 4);
  float* emb1   = (float*)alloc((size_t)8 * H_ * 4);
  float* cond   = (float*)alloc((size_t)8 * H_ * 4);
  float* fscale = (float*)alloc((size_t)8 * H_ * 4);
  float* gates  = (float*)alloc((size_t)4 * L_ * 8 * H_ * 4);
  int*   offs   = (int*)alloc(64);
  float* hbuf   = (float*)alloc((size_t)MPAD_ * H_ * 4);
  float* h1buf  = (float*)alloc((size_t)MPAD_ * H_ * 4);
  unsigned short* normed  = (unsigned short*)alloc((size_t)MPAD_ * H_ * 2);
  unsigned short* normed2 = (unsigned short*)alloc((size_t)MPAD_ * H_ * 2);
  unsigned short* q_r     = (unsigned short*)alloc((size_t)B_ * NH_ * 64 * HD_ * 2);
  unsigned short* Kf_all  = (unsigned short*)alloc((size_t)L_ * B_ * TPAD_ * HD_ * 2);
  unsigned short* Vt_all  = (unsigned short*)alloc((size_t)L_ * B_ * HD_ * TPAD_ * 2);
  unsigned short* attb    = (unsigned short*)alloc((size_t)MPAD_ * 2048 * 2);
  unsigned short* t_buf   = (unsigned short*)alloc((size_t)MPAD_ * FF_ * 2);
  float* wopart = (float*)alloc((size_t)4 * MPAD_ * 1024 * 4);
  float* dpart  = (float*)alloc((size_t)4 * MPAD_ * 1024 * 4);

  // attb pad rows never written by flash8: zero once (stays zero all layers)
  hipMemsetAsync(attb + (size_t)MROWS_ * 2048, 0, (size_t)(MPAD_ - MROWS_) * 2048 * 2, stream);
  // normed2 pad rows never written (redA grid = 400): zero once so upg A-reads stay finite
  hipMemsetAsync(normed2 + (size_t)MROWS_ * H_, 0, (size_t)(MPAD_ - MROWS_) * H_ * 2, stream);
  // t_buf pad rows never written by upg: zero once
  hipMemsetAsync(t_buf + (size_t)MROWS_ * FF_, 0, (size_t)(MPAD_ - MROWS_) * FF_ * 2, stream);

  emb_k<<<8, 256, 0, stream>>>(timestep, emb0);
  gemm8_k<<<16, 256, 0, stream>>>(emb0, tmlp_in_w, tmlp_in_b, emb1, 1);
  gemm8_k<<<16, 256, 0, stream>>>(emb1, tmlp_out_w, tmlp_out_b, cond, 1);
  gemm8_k<<<16, 256, 0, stream>>>(cond, fnorm_scale_w, nullptr, fscale, 0);
  gates_k<<<dim3(16, L_, 4), 256, 0, stream>>>(cond, in_scale_w, in_gate_w, post_scale_w, post_gate_w, gates);
  offs_k<<<1, 256, 0, stream>>>(pad_mask, offs);
  action_in_k<<<(MPAD_ * H_) / 256, 256, 0, stream>>>(x_t, action_in_w, action_in_b, hbuf);
  prefixAll_k<<<dim3(16, B_, L_), 256, 0, stream>>>(prefix_keys, prefix_values, Kf_all, Vt_all);
  ada_k<<<MPAD_, 256, 0, stream>>>(hbuf, in_norm_w, gates, normed);  // layer-0 in_scale = gates z=0,l=0

  for (int i = 0; i < L_; i++) {
    const float* wq_i = w_q + (size_t)i * H_ * 2048;
    const float* wk_i = w_k + (size_t)i * H_ * HD_;
    const float* wv_i = w_v + (size_t)i * H_ * HD_;
    const float* wo_i = w_o + (size_t)i * 2048 * H_;
    const float* wg_i = w_gate + (size_t)i * H_ * FF_;
    const float* wu_i = w_up + (size_t)i * H_ * FF_;
    const float* wd_i = w_down + (size_t)i * FF_ * H_;
    const float* g_in_gate    = gates + ((size_t)(1 * L_ + i) * 8) * H_;
    const float* g_post_scale = gates + ((size_t)(2 * L_ + i) * 8) * H_;
    const float* g_post_gate  = gates + ((size_t)(3 * L_ + i) * 8) * H_;
    unsigned short* Kf_l = Kf_all + (size_t)i * B_ * TPAD_ * HD_;
    unsigned short* Vt_l = Vt_all + (size_t)i * B_ * HD_ * TPAD_;

    qkvF_k<<<dim3(80, 2), 512, 0, stream>>>(normed, wq_i, wk_i, wv_i, offs, q_r, Kf_l, Vt_l);
    flash8_k<<<dim3(B_, 4, NH_), 512, 0, stream>>>(q_r, Kf_l, Vt_l, attb);
    gemmS_k<1, 4, 2><<<dim3(32, 4, 2), 512, 0, stream>>>(attb, 2048, 2048, wo_i, nullptr, wopart, nullptr);
    redA_k<4><<<MROWS_, 256, 0, stream>>>(wopart, hbuf, g_in_gate, post_norm_w + (size_t)i * H_,
                                          g_post_scale, h1buf, normed2);
    upg_k<<<dim3(128, 2), 512, 0, stream>>>(normed2, wg_i, wu_i, t_buf);
    gemmS_k<3, 4, 2><<<dim3(32, 4, 2), 512, 0, stream>>>(t_buf, FF_, FF_, wd_i, nullptr, dpart, nullptr);
    const float* nw_next = (i + 1 < L_) ? in_norm_w + (size_t)(i + 1) * H_ : fnorm_w;
    const float* sc_next = (i + 1 < L_) ? gates + ((size_t)(i + 1) * 8) * H_ : fscale;
    redA_k<4><<<MROWS_, 256, 0, stream>>>(dpart, h1buf, g_post_gate, nw_next, sc_next, hbuf, normed);
  }

  fout_k<<<MROWS_, 256, 0, stream>>>(normed, action_out_w, action_out_b, (float*)d_out);
}

// Round 15
// 2646.806 us; speedup vs baseline: 2.0118x; 1.0070x over previous
//
#include <hip/hip_runtime.h>

#define L_ 18
#define H_ 1024
#define NH_ 8
#define HD_ 256
#define FF_ 4096
#define HOR_ 50
#define PRE_ 968
#define B_ 8
#define AD_ 32
#define TPAD_ 1024
#define MROWS_ 400
#define MPAD_ 512
#define KSTEP_ 128
#define LST_ 132

typedef float f32x4 __attribute__((ext_vector_type(4)));
typedef short s16x4 __attribute__((ext_vector_type(4)));
typedef short s16x8 __attribute__((ext_vector_type(8)));
typedef unsigned short u16x8 __attribute__((ext_vector_type(8)));

__device__ __forceinline__ unsigned short f2bf(float f) {
  unsigned u = __float_as_uint(f);
  u += 0x7FFFu + ((u >> 16) & 1u);
  return (unsigned short)(u >> 16);
}
__device__ __forceinline__ float bf2f(unsigned short h) {
  return __uint_as_float(((unsigned)h) << 16);
}
__device__ __forceinline__ float wave_sum(float v) {
#pragma unroll
  for (int o = 32; o > 0; o >>= 1) v += __shfl_xor(v, o);
  return v;
}

// ---------------------------------------------------------------- time embedding
__global__ __launch_bounds__(256) void emb_k(const float* __restrict__ ts, float* __restrict__ emb) {
  int b = blockIdx.x, tid = threadIdx.x;
  float t = ts[b];
  for (int j = tid; j < 512; j += 256) {
    float ang = 1570.7963267948966f * expf((float)j * (-6.907755278982137f / 511.0f)) * t;
    emb[(size_t)b * H_ + j] = sinf(ang);
    emb[(size_t)b * H_ + 512 + j] = cosf(ang);
  }
}

// ---------------------------------------------------------------- [8,1024]@[1024,1024] (+bias,+silu)
__global__ __launch_bounds__(256) void gemm8_k(const float* __restrict__ A8, const float* __restrict__ W,
                                               const float* __restrict__ bias, float* __restrict__ out,
                                               int act) {
  __shared__ float a_s[8 * 1024];
  __shared__ float red[4][8][64];
  int tid = threadIdx.x;
  for (int i = tid; i < 8 * 1024; i += 256) a_s[i] = A8[i];
  __syncthreads();
  int nl = tid & 63, kg = tid >> 6;
  int n = blockIdx.x * 64 + nl;
  float acc[8];
#pragma unroll
  for (int m = 0; m < 8; m++) acc[m] = 0.f;
  for (int k = kg * 256; k < kg * 256 + 256; k++) {
    float wv = W[(size_t)k * 1024 + n];
#pragma unroll
    for (int m = 0; m < 8; m++) acc[m] += a_s[m * 1024 + k] * wv;
  }
#pragma unroll
  for (int m = 0; m < 8; m++) red[kg][m][nl] = acc[m];
  __syncthreads();
  if (kg == 0) {
#pragma unroll
    for (int m = 0; m < 8; m++) {
      float v = red[0][m][nl] + red[1][m][nl] + red[2][m][nl] + red[3][m][nl];
      if (bias) v += bias[n];
      if (act) v = v / (1.f + expf(-v));
      out[(size_t)m * 1024 + n] = v;
    }
  }
}

// ---------------------------------------------------------------- all 72 adaLN cond GEMMs in one grid
__global__ __launch_bounds__(256) void gates_k(const float* __restrict__ cond,
                                               const float* __restrict__ w0, const float* __restrict__ w1,
                                               const float* __restrict__ w2, const float* __restrict__ w3,
                                               float* __restrict__ gates) {
  __shared__ float a_s[8 * 1024];
  __shared__ float red[4][8][64];
  int tid = threadIdx.x;
  for (int i = tid; i < 8 * 1024; i += 256) a_s[i] = cond[i];
  __syncthreads();
  int z = blockIdx.z, layer = blockIdx.y;
  const float* W = (z == 0 ? w0 : z == 1 ? w1 : z == 2 ? w2 : w3) + (size_t)layer * H_ * H_;
  float* out = gates + ((size_t)(z * L_ + layer) * 8) * H_;
  int nl = tid & 63, kg = tid >> 6;
  int n = blockIdx.x * 64 + nl;
  float acc[8];
#pragma unroll
  for (int m = 0; m < 8; m++) acc[m] = 0.f;
  for (int k = kg * 256; k < kg * 256 + 256; k++) {
    float wv = W[(size_t)k * 1024 + n];
#pragma unroll
    for (int m = 0; m < 8; m++) acc[m] += a_s[m * 1024 + k] * wv;
  }
#pragma unroll
  for (int m = 0; m < 8; m++) red[kg][m][nl] = acc[m];
  __syncthreads();
  if (kg == 0) {
#pragma unroll
    for (int m = 0; m < 8; m++)
      out[(size_t)m * 1024 + n] = red[0][m][nl] + red[1][m][nl] + red[2][m][nl] + red[3][m][nl];
  }
}

// ---------------------------------------------------------------- pad-mask -> per-batch valid counts
__global__ void offs_k(const unsigned char* __restrict__ mask, int* __restrict__ offs) {
  __shared__ int cnt[8];
  __shared__ int mod4;
  int tid = threadIdx.x;
  if (tid < 8) cnt[tid] = 0;
  if (tid == 8) mod4 = 0;
  __syncthreads();
  for (int i = tid; i < B_ * PRE_; i += 256) {
    unsigned char v = mask[i];
    if (v) {
      atomicAdd(&cnt[i / PRE_], 1);
      if (i & 3) atomicAdd(&mod4, 1);
    }
  }
  __syncthreads();
  if (tid < 8) offs[tid] = (mod4 == 0) ? cnt[tid] * 4 : cnt[tid];
}

// ---------------------------------------------------------------- h = x_t @ action_in_w + b  (pad rows = 0)
__global__ __launch_bounds__(256) void action_in_k(const float* __restrict__ xt, const float* __restrict__ Wi,
                                                   const float* __restrict__ bi, float* __restrict__ h) {
  int idx = blockIdx.x * 256 + threadIdx.x;
  int m = idx >> 10, n = idx & 1023;
  float v = 0.f;
  if (m < MROWS_) {
    const float* xr = xt + (size_t)m * AD_;
#pragma unroll
    for (int k = 0; k < AD_; k++) v += xr[k] * Wi[(size_t)k * H_ + n];
    v += bi[n];
  }
  h[idx] = v;
}

// ---------------------------------------------------------------- AdaRMSNorm -> bf16 (pad rows = 0), layer-0 only
__global__ __launch_bounds__(256) void ada_k(const float* __restrict__ X, const float* __restrict__ nw,
                                             const float* __restrict__ sc, unsigned short* __restrict__ Y) {
  int m = blockIdx.x, tid = threadIdx.x;
  size_t base = (size_t)m * H_;
  if (m >= MROWS_) {
#pragma unroll
    for (int j = 0; j < 4; j++) Y[base + tid * 4 + j] = 0;
    return;
  }
  f32x4 x = *(const f32x4*)(X + base + tid * 4);
  float ss = x[0] * x[0] + x[1] * x[1] + x[2] * x[2] + x[3] * x[3];
  __shared__ float r4[4];
  float wsv = wave_sum(ss);
  if ((tid & 63) == 0) r4[tid >> 6] = wsv;
  __syncthreads();
  float rs = rsqrtf((r4[0] + r4[1] + r4[2] + r4[3]) * (1.f / 1024.f) + 1e-6f);
  int b = m / HOR_;
#pragma unroll
  for (int j = 0; j < 4; j++) {
    int n = tid * 4 + j;
    Y[base + n] = f2bf(x[j] * rs * (1.f + nw[n]) * (1.f + sc[(size_t)b * H_ + n]));
  }
}

// ---------------------------------------------------------------- all-layer prefix convert: K row-major, V transposed
__global__ __launch_bounds__(256) void prefixAll_k(const float* __restrict__ pk, const float* __restrict__ pv,
                                                   unsigned short* __restrict__ Kf_all,
                                                   unsigned short* __restrict__ Vt_all) {
  int b = blockIdx.y, t0 = blockIdx.x * 64, layer = blockIdx.z, tid = threadIdx.x;
  unsigned short* Kf = Kf_all + (size_t)layer * B_ * TPAD_ * HD_;
  unsigned short* Vt = Vt_all + (size_t)layer * B_ * HD_ * TPAD_;
  __shared__ unsigned short vt[256][72];
  const float* kp = pk + ((size_t)(b * L_ + layer)) * PRE_ * HD_;
  const float* vp = pv + ((size_t)(b * L_ + layer)) * PRE_ * HD_;
  for (int i = 0; i < 64; i++) {
    int t = t0 + i;
    float kv = 0.f, vv = 0.f;
    if (t < PRE_) {
      kv = kp[(size_t)t * HD_ + tid];
      vv = vp[(size_t)t * HD_ + tid];
    }
    Kf[((size_t)b * TPAD_ + t) * HD_ + tid] = f2bf(kv);  // suffix rows rewritten per layer by qkvF
    vt[tid][i] = f2bf(vv);
  }
  __syncthreads();
#pragma unroll
  for (int p = 0; p < 4; p++) {
    int d = p * 64 + (tid >> 2);
    int c0 = (tid & 3) * 16;
    u16x8 v0, v1;
#pragma unroll
    for (int j = 0; j < 8; j++) { v0[j] = vt[d][c0 + j]; v1[j] = vt[d][c0 + 8 + j]; }
    size_t dst = ((size_t)(b * HD_ + d)) * TPAD_ + t0 + c0;
    *(u16x8*)(Vt + dst) = v0;
    *(u16x8*)(Vt + dst + 8) = v1;
  }
}

// ================================================================ QKV GEMM (2-deep W prefetch, reg A) + RoPE/scatter
// grid (80 strips, 2 m-halves), 512 thr. Full unroll => register slot indices compile-time.
__global__ __launch_bounds__(512) void qkvF_k(const unsigned short* __restrict__ A,
                                              const float* __restrict__ Wq, const float* __restrict__ Wk,
                                              const float* __restrict__ Wv, const int* __restrict__ offs,
                                              unsigned short* __restrict__ q_r, unsigned short* __restrict__ Kf,
                                              unsigned short* __restrict__ Vt) {
  const int st = blockIdx.x, mh = blockIdx.y;
  const int tid = threadIdx.x, wv = tid >> 6, l = tid & 63;
  const int lr = l & 15, kg = l >> 4, lk = kg << 2;
  const int m0 = mh * 256 + wv * 32;

  const float* W;
  int ldw, wbase;
  bool paired;
  if (st < 64)      { W = Wq; ldw = 2048; wbase = (st >> 3) * 256 + (st & 7) * 16; paired = true; }
  else if (st < 72) { W = Wk; ldw = 256;  wbase = (st - 64) * 16; paired = true; }
  else              { W = Wv; ldw = 256;  wbase = (st - 72) * 32; paired = false; }

  __shared__ unsigned short Wt[2][32][LST_];
  __shared__ int offsL[8];
  const int pr = tid >> 3, c0 = (tid & 7) * 4;
  const int wcol = wbase + c0 + ((paired && c0 >= 16) ? 112 : 0);

  if (tid < 8) offsL[tid] = offs[tid];

  f32x4 acc[2][2];
#pragma unroll
  for (int a = 0; a < 2; a++)
#pragma unroll
    for (int b = 0; b < 2; b++) acc[a][b] = (f32x4){0.f, 0.f, 0.f, 0.f};

  f32x4 pa0[2], pa1[2];   // 2-deep W register slots
  auto LOADW = [&](int IT) {
    int sl = IT & 1;
    size_t kk = (size_t)IT * KSTEP_ + 2 * pr;
    pa0[sl] = *(const f32x4*)(W + kk * ldw + wcol);
    pa1[sl] = *(const f32x4*)(W + (kk + 1) * ldw + wcol);
  };
  auto STOREW = [&](int IT) {
    int sl = IT & 1;
#pragma unroll
    for (int j = 0; j < 4; j++) {
      unsigned v = (unsigned)f2bf(pa0[sl][j]) | ((unsigned)f2bf(pa1[sl][j]) << 16);
      *(unsigned*)&Wt[sl][c0 + j][2 * pr] = v;
    }
  };

  s16x8 aP[2][4];
  auto LOADA = [&](int IT) {
    const int kb = IT * KSTEP_;
#pragma unroll
    for (int s = 0; s < 4; s++)
#pragma unroll
      for (int mf = 0; mf < 2; mf++)
        aP[mf][s] = *(const s16x8*)(A + (size_t)(m0 + mf * 16 + lr) * H_ + kb + s * 32 + 8 * kg);
  };

  LOADW(0);
  LOADW(1);
  LOADA(0);
  STOREW(0);
  __syncthreads();

#pragma unroll
  for (int it = 0; it < 8; ++it) {
    if (it + 2 < 8) LOADW(it + 2);   // 2-deep: issued 2 phases before its STOREW
#pragma unroll
    for (int s = 0; s < 4; s++) {
      s16x8 bfr[2];
#pragma unroll
      for (int nf = 0; nf < 2; nf++) {
        const unsigned short* wp = &Wt[it & 1][nf * 16 + lr][s * 32 + 2 * lk];
        s16x4 b0 = *(const s16x4*)wp;
        s16x4 b1 = *(const s16x4*)(wp + 4);
#pragma unroll
        for (int j = 0; j < 4; j++) { bfr[nf][j] = b0[j]; bfr[nf][4 + j] = b1[j]; }
      }
#pragma unroll
      for (int mf = 0; mf < 2; mf++)
#pragma unroll
        for (int nf = 0; nf < 2; nf++)
          acc[mf][nf] = __builtin_amdgcn_mfma_f32_16x16x32_bf16(aP[mf][s], bfr[nf], acc[mf][nf], 0, 0, 0);
    }
    if (it + 1 < 8) {
      LOADA(it + 1);
      STOREW(it + 1);
    }
    __syncthreads();
  }

  const float RK = -9.210340371976184f / 128.0f;
  if (st < 64) {  // Q: rope pair, write q_r
    const int h = st >> 3, x = (st & 7) * 16, dd = x + lr;
    const float inv = expf((float)dd * RK);
#pragma unroll
    for (int mf = 0; mf < 2; mf++)
#pragma unroll
      for (int r = 0; r < 4; r++) {
        int m = m0 + mf * 16 + lk + r;
        if (m >= MROWS_) continue;
        int b = m / HOR_, s = m - b * HOR_;
        float ang = (float)(offsL[b] + s) * inv;
        float cc = cosf(ang), sn = sinf(ang);
        float v1 = acc[mf][0][r], v2 = acc[mf][1][r];
        size_t base = ((size_t)(b * NH_ + h) * 64 + s) * HD_;
        q_r[base + dd] = f2bf(v1 * cc - v2 * sn);
        q_r[base + dd + 128] = f2bf(v2 * cc + v1 * sn);
      }
  } else if (st < 72) {  // K: rope pair, write Kf suffix rows
    const int x = (st - 64) * 16, dd = x + lr;
    const float inv = expf((float)dd * RK);
#pragma unroll
    for (int mf = 0; mf < 2; mf++)
#pragma unroll
      for (int r = 0; r < 4; r++) {
        int m = m0 + mf * 16 + lk + r;
        if (m >= MROWS_) continue;
        int b = m / HOR_, s = m - b * HOR_;
        float ang = (float)(offsL[b] + s) * inv;
        float cc = cosf(ang), sn = sinf(ang);
        float v1 = acc[mf][0][r], v2 = acc[mf][1][r];
        size_t base = ((size_t)b * TPAD_ + PRE_ + s) * HD_;
        Kf[base + dd] = f2bf(v1 * cc - v2 * sn);
        Kf[base + dd + 128] = f2bf(v2 * cc + v1 * sn);
      }
  } else {  // V: write Vt columns
    const int x = (st - 72) * 32;
#pragma unroll
    for (int mf = 0; mf < 2; mf++)
#pragma unroll
      for (int nf = 0; nf < 2; nf++)
#pragma unroll
        for (int r = 0; r < 4; r++) {
          int m = m0 + mf * 16 + lk + r;
          if (m >= MROWS_) continue;
          int b = m / HOR_, s = m - b * HOR_;
          int d = x + nf * 16 + lr;
          Vt[((size_t)(b * HD_ + d)) * TPAD_ + PRE_ + s] = f2bf(acc[mf][nf][r]);
        }
  }
}

// ================================================================ 8-wave flash attention (validated round-12)
// grid (B, 4 rg, NH) [b = bid%8 -> per-batch KV pinned to one XCD's L2]. 512 thr = 8 waves.
__global__ __launch_bounds__(512) void flash8_k(const unsigned short* __restrict__ qr,
                                                const unsigned short* __restrict__ Kf,
                                                const unsigned short* __restrict__ Vt,
                                                unsigned short* __restrict__ attb) {
  const int b = blockIdx.x, rg = blockIdx.y, h = blockIdx.z;
  const int bh = b * NH_ + h;
  const int tid = threadIdx.x, w = tid >> 6, l = tid & 63;
  const int lr = l & 15, kg = l >> 4;
  const int t0 = w * 128;

  __shared__ __align__(16) unsigned short Pl[8][16][136];
  __shared__ float mlS[8][16][2];

  const unsigned short* qbase = qr + ((size_t)bh * 64 + rg * 16 + lr) * HD_;
  s16x8 afr[8];
#pragma unroll
  for (int js = 0; js < 8; js++) afr[js] = *(const s16x8*)(qbase + js * 32 + 8 * kg);
  f32x4 sc[8];
#pragma unroll
  for (int nf = 0; nf < 8; nf++) sc[nf] = (f32x4){0.f, 0.f, 0.f, 0.f};
  const unsigned short* kb = Kf + ((size_t)b * TPAD_ + t0) * HD_;
#pragma unroll
  for (int js = 0; js < 8; js++)
#pragma unroll
    for (int nf = 0; nf < 8; nf++) {
      s16x8 bv = *(const s16x8*)(kb + (size_t)(nf * 16 + lr) * HD_ + js * 32 + 8 * kg);
      sc[nf] = __builtin_amdgcn_mfma_f32_16x16x32_bf16(afr[js], bv, sc[nf], 0, 0, 0);
    }
  float mx[4] = {-3.0e38f, -3.0e38f, -3.0e38f, -3.0e38f};
#pragma unroll
  for (int nf = 0; nf < 8; nf++) {
    int t = t0 + nf * 16 + lr;
#pragma unroll
    for (int r = 0; r < 4; r++) {
      int srw = rg * 16 + 4 * kg + r;
      float v = sc[nf][r] * 0.0625f;
      if (t >= PRE_ && (t - PRE_) > srw) v = -1e9f;
      sc[nf][r] = v;
      mx[r] = fmaxf(mx[r], v);
    }
  }
#pragma unroll
  for (int o = 8; o > 0; o >>= 1)
#pragma unroll
    for (int r = 0; r < 4; r++) mx[r] = fmaxf(mx[r], __shfl_xor(mx[r], o));
  float ls[4] = {0.f, 0.f, 0.f, 0.f};
#pragma unroll
  for (int nf = 0; nf < 8; nf++)
#pragma unroll
    for (int r = 0; r < 4; r++) {
      float p = expf(sc[nf][r] - mx[r]);
      sc[nf][r] = p;
      ls[r] += p;
    }
#pragma unroll
  for (int o = 8; o > 0; o >>= 1)
#pragma unroll
    for (int r = 0; r < 4; r++) ls[r] += __shfl_xor(ls[r], o);
#pragma unroll
  for (int nf = 0; nf < 8; nf++)
#pragma unroll
    for (int r = 0; r < 4; r++) Pl[w][4 * kg + r][nf * 16 + lr] = f2bf(sc[nf][r]);
  if (lr == 0) {
#pragma unroll
    for (int r = 0; r < 4; r++) {
      mlS[w][4 * kg + r][0] = mx[r];
      mlS[w][4 * kg + r][1] = ls[r];
    }
  }
  __syncthreads();
  f32x4 o4[8][2];
#pragma unroll
  for (int a = 0; a < 8; a++)
#pragma unroll
    for (int c = 0; c < 2; c++) o4[a][c] = (f32x4){0.f, 0.f, 0.f, 0.f};
#pragma unroll
  for (int wz = 0; wz < 8; wz++)
#pragma unroll
    for (int ti = 0; ti < 128; ti += 32) {
      s16x8 a = *(const s16x8*)&Pl[wz][lr][ti + 8 * kg];
#pragma unroll
      for (int nf = 0; nf < 2; nf++) {
        s16x8 bv = *(const s16x8*)(Vt + ((size_t)(b * HD_ + w * 32 + nf * 16 + lr)) * TPAD_ +
                                   wz * 128 + ti + 8 * kg);
        o4[wz][nf] = __builtin_amdgcn_mfma_f32_16x16x32_bf16(a, bv, o4[wz][nf], 0, 0, 0);
      }
    }
#pragma unroll
  for (int r = 0; r < 4; r++) {
    int row = 4 * kg + r;
    int s = rg * 16 + row;
    if (s >= HOR_) continue;
    float M = -3.0e38f;
#pragma unroll
    for (int wz = 0; wz < 8; wz++) M = fmaxf(M, mlS[wz][row][0]);
    float w8[8], Lden = 0.f;
#pragma unroll
    for (int wz = 0; wz < 8; wz++) {
      w8[wz] = expf(mlS[wz][row][0] - M);
      Lden += w8[wz] * mlS[wz][row][1];
    }
    float invL = 1.f / Lden;
#pragma unroll
    for (int nf = 0; nf < 2; nf++) {
      float o = 0.f;
#pragma unroll
      for (int wz = 0; wz < 8; wz++) o += w8[wz] * o4[wz][nf][r];
      attb[((size_t)(b * HOR_ + s)) * 2048 + h * HD_ + w * 32 + nf * 16 + lr] = f2bf(o * invL);
    }
  }
}

// ================================================================ split-K MFMA GEMM stage 1 (2-deep W, reg A)
// MODE 1=WO, 3=DOWN. KSZT compile-time => full unroll, register slots compile-time. 512 thr.
template <int MODE, int NS, int MS, int KSZT>
__global__ __launch_bounds__(512) void gemmS_k(const unsigned short* __restrict__ A,
                                               const float* __restrict__ W0,
                                               float* __restrict__ part) {
  constexpr int NF = 2;
  constexpr int RPW = 64 / MS;
  constexpr int MFC = RPW / 16;
  constexpr int KC = KSZT / NS;
  constexpr int NITER = KC / KSTEP_;
  const int tid = threadIdx.x;
  const int wv = tid >> 6, l = tid & 63;
  const int lr = l & 15, lk = (l >> 4) << 2;
  const int n0 = blockIdx.x * 32;
  const int kz = blockIdx.y;
  const int kbase = kz * KC;
  const int m0 = (int)blockIdx.z * (512 / MS) + wv * RPW;

  __shared__ unsigned short Wt[2][32][LST_];
  const int pr = tid >> 3;
  const int c0 = (tid & 7) * 4;

  f32x4 acc[MFC][NF];
#pragma unroll
  for (int a = 0; a < MFC; a++)
#pragma unroll
    for (int b = 0; b < NF; b++) acc[a][b] = (f32x4){0.f, 0.f, 0.f, 0.f};

  f32x4 pa0[2], pa1[2];
  auto LOADW = [&](int IT) {
    int sl = IT & 1;
    size_t kk = (size_t)(kbase + IT * KSTEP_ + 2 * pr);
    pa0[sl] = *(const f32x4*)(W0 + kk * 1024 + n0 + c0);
    pa1[sl] = *(const f32x4*)(W0 + (kk + 1) * 1024 + n0 + c0);
  };
  auto STOREW = [&](int IT) {
    int sl = IT & 1;
#pragma unroll
    for (int j = 0; j < 4; j++) {
      unsigned v = (unsigned)f2bf(pa0[sl][j]) | ((unsigned)f2bf(pa1[sl][j]) << 16);
      *(unsigned*)&Wt[sl][c0 + j][2 * pr] = v;
    }
  };

  s16x8 aP[MFC][4];
  auto LOADA = [&](int IT) {
    const int kb = kbase + IT * KSTEP_;
#pragma unroll
    for (int s = 0; s < 4; s++)
#pragma unroll
      for (int mf = 0; mf < MFC; mf++)
        aP[mf][s] = *(const s16x8*)(A + (size_t)(m0 + mf * 16 + lr) * KSZT + kb + s * 32 + 2 * lk);
  };

  LOADW(0);
  if (NITER > 1) LOADW(1);
  LOADA(0);
  STOREW(0);
  __syncthreads();

#pragma unroll
  for (int it = 0; it < NITER; ++it) {
    if (it + 2 < NITER) LOADW(it + 2);
#pragma unroll
    for (int s = 0; s < 4; s++) {
      s16x8 bfr[NF];
#pragma unroll
      for (int nf = 0; nf < NF; nf++) {
        const unsigned short* wp = &Wt[it & 1][nf * 16 + lr][s * 32 + 2 * lk];
        s16x4 b0 = *(const s16x4*)wp;
        s16x4 b1 = *(const s16x4*)(wp + 4);
#pragma unroll
        for (int j = 0; j < 4; j++) { bfr[nf][j] = b0[j]; bfr[nf][4 + j] = b1[j]; }
      }
#pragma unroll
      for (int mf = 0; mf < MFC; mf++)
#pragma unroll
        for (int nf = 0; nf < NF; nf++)
          acc[mf][nf] = __builtin_amdgcn_mfma_f32_16x16x32_bf16(aP[mf][s], bfr[nf], acc[mf][nf], 0, 0, 0);
    }
    if (it + 1 < NITER) {
      LOADA(it + 1);
      STOREW(it + 1);
    }
    __syncthreads();
  }

#pragma unroll
  for (int mf = 0; mf < MFC; mf++)
#pragma unroll
    for (int nf = 0; nf < NF; nf++)
#pragma unroll
      for (int r = 0; r < 4; r++) {
        int row = m0 + mf * 16 + lk + r;
        if (row >= MROWS_) continue;
        int col = n0 + nf * 16 + lr;
        part[((size_t)kz * MPAD_ + row) * 1024 + col] = acc[mf][nf][r];
      }
}

// ---------------------------------------------------------------- split-K reduce + residual-gate + AdaRMSNorm
template <int NS>
__global__ __launch_bounds__(256) void redA_k(const float* __restrict__ part, const float* __restrict__ prev,
                                              const float* __restrict__ gatev, const float* __restrict__ nw,
                                              const float* __restrict__ sc, float* __restrict__ outH,
                                              unsigned short* __restrict__ outN) {
  int r = blockIdx.x, tid = threadIdx.x;
  int c = tid * 4;
  int b = r / HOR_;
  f32x4 v = (f32x4){0.f, 0.f, 0.f, 0.f};
#pragma unroll
  for (int z = 0; z < NS; z++) v += *(const f32x4*)(part + ((size_t)z * MPAD_ + r) * H_ + c);
  f32x4 pv = *(const f32x4*)(prev + (size_t)r * H_ + c);
  f32x4 gv = *(const f32x4*)(gatev + (size_t)b * H_ + c);
  f32x4 h = pv + gv * v;
  *(f32x4*)(outH + (size_t)r * H_ + c) = h;
  float ss = h[0] * h[0] + h[1] * h[1] + h[2] * h[2] + h[3] * h[3];
  __shared__ float r4[4];
  float wsv = wave_sum(ss);
  if ((tid & 63) == 0) r4[tid >> 6] = wsv;
  __syncthreads();
  float rs = rsqrtf((r4[0] + r4[1] + r4[2] + r4[3]) * (1.f / 1024.f) + 1e-6f);
#pragma unroll
  for (int j = 0; j < 4; j++) {
    int n = c + j;
    outN[(size_t)r * H_ + n] = f2bf(h[j] * rs * (1.f + nw[n]) * (1.f + sc[(size_t)b * H_ + n]));
  }
}

// ================================================================ upgate dual GEMM (reg-pipelined A, validated r14)
// grid (128 strips of 32, 2 m-halves), 512 thr, full-K NITER=8.
__global__ __launch_bounds__(512) void upg_k(const unsigned short* __restrict__ A, const float* __restrict__ Wg,
                                             const float* __restrict__ Wu, unsigned short* __restrict__ tb) {
  const int st = blockIdx.x, mh = blockIdx.y;
  const int n0 = st * 32;
  const int tid = threadIdx.x, wv = tid >> 6, l = tid & 63;
  const int lr = l & 15, kg = l >> 4, lk = kg << 2;
  const int m0 = mh * 256 + wv * 32;

  __shared__ unsigned short Wt[2][64][LST_];
  const int pr = tid >> 3, c0 = (tid & 7) * 4;

  f32x4 acc[2][4];
#pragma unroll
  for (int a = 0; a < 2; a++)
#pragma unroll
    for (int b = 0; b < 4; b++) acc[a][b] = (f32x4){0.f, 0.f, 0.f, 0.f};

  f32x4 pa0, pa1, pb0, pb1;
  auto LOADW = [&](int IT) {
    size_t kk = (size_t)IT * KSTEP_ + 2 * pr;
    pa0 = *(const f32x4*)(Wg + kk * 4096 + n0 + c0);
    pa1 = *(const f32x4*)(Wg + (kk + 1) * 4096 + n0 + c0);
    pb0 = *(const f32x4*)(Wu + kk * 4096 + n0 + c0);
    pb1 = *(const f32x4*)(Wu + (kk + 1) * 4096 + n0 + c0);
  };
  auto STOREW = [&](int BUF) {
#pragma unroll
    for (int j = 0; j < 4; j++) {
      unsigned v = (unsigned)f2bf(pa0[j]) | ((unsigned)f2bf(pa1[j]) << 16);
      *(unsigned*)&Wt[BUF][c0 + j][2 * pr] = v;
      unsigned u = (unsigned)f2bf(pb0[j]) | ((unsigned)f2bf(pb1[j]) << 16);
      *(unsigned*)&Wt[BUF][32 + c0 + j][2 * pr] = u;
    }
  };

  s16x8 aP[2][4];
  auto LOADA = [&](int IT) {
    const int kb = IT * KSTEP_;
#pragma unroll
    for (int s = 0; s < 4; s++)
#pragma unroll
      for (int mf = 0; mf < 2; mf++)
        aP[mf][s] = *(const s16x8*)(A + (size_t)(m0 + mf * 16 + lr) * H_ + kb + s * 32 + 8 * kg);
  };

  LOADW(0);
  LOADA(0);
  STOREW(0);
  __syncthreads();

  for (int it = 0; it < 8; ++it) {
    if (it + 1 < 8) LOADW(it + 1);
    const int cur = it & 1;
#pragma unroll
    for (int s = 0; s < 4; s++) {
      s16x8 bfr[4];
#pragma unroll
      for (int nf = 0; nf < 4; nf++) {
        const unsigned short* wp = &Wt[cur][nf * 16 + lr][s * 32 + 2 * lk];
        s16x4 b0 = *(const s16x4*)wp;
        s16x4 b1 = *(const s16x4*)(wp + 4);
#pragma unroll
        for (int j = 0; j < 4; j++) { bfr[nf][j] = b0[j]; bfr[nf][4 + j] = b1[j]; }
      }
#pragma unroll
      for (int mf = 0; mf < 2; mf++)
#pragma unroll
        for (int nf = 0; nf < 4; nf++)
          acc[mf][nf] = __builtin_amdgcn_mfma_f32_16x16x32_bf16(aP[mf][s], bfr[nf], acc[mf][nf], 0, 0, 0);
    }
    if (it + 1 < 8) {
      LOADA(it + 1);
      STOREW((it + 1) & 1);
    }
    __syncthreads();
  }

#pragma unroll
  for (int mf = 0; mf < 2; mf++)
#pragma unroll
    for (int nf = 0; nf < 2; nf++)
#pragma unroll
      for (int r = 0; r < 4; r++) {
        int row = m0 + mf * 16 + lk + r;
        if (row >= MROWS_) continue;
        int col = n0 + nf * 16 + lr;
        float g = acc[mf][nf][r];
        float u = acc[mf][nf + 2][r];
        g = 0.5f * g * (1.f + tanhf(0.7978845608028654f * (g + 0.044715f * g * g * g)));
        tb[(size_t)row * 4096 + col] = f2bf(g * u);
      }
}

// ---------------------------------------------------------------- out = normedF @ action_out_w + b
__global__ __launch_bounds__(256) void fout_k(const unsigned short* __restrict__ nf, const float* __restrict__ Wo,
                                              const float* __restrict__ bo, float* __restrict__ out) {
  int m = blockIdx.x, tid = threadIdx.x;
  int n = tid & 31, kg = tid >> 5;
  float acc = 0.f;
  for (int k = kg * 128; k < kg * 128 + 128; k++)
    acc += bf2f(nf[(size_t)m * H_ + k]) * Wo[(size_t)k * AD_ + n];
  __shared__ float red[8][32];
  red[kg][n] = acc;
  __syncthreads();
  if (kg == 0) {
    float v = 0.f;
#pragma unroll
    for (int g = 0; g < 8; g++) v += red[g][n];
    out[(size_t)m * AD_ + n] = v + bo[n];
  }
}

// ================================================================ host
extern "C" void kernel_launch(void* const* d_in, const int* in_sizes, int n_in,
                              void* d_out, int out_size, void* d_ws, size_t ws_size,
                              hipStream_t stream) {
  const float* prefix_keys   = (const float*)d_in[0];
  const float* prefix_values = (const float*)d_in[1];
  const float* x_t           = (const float*)d_in[2];
  const float* timestep      = (const float*)d_in[3];
  const unsigned char* pad_mask = (const unsigned char*)d_in[4];
  const float* action_in_w   = (const float*)d_in[5];
  const float* action_in_b   = (const float*)d_in[6];
  const float* action_out_w  = (const float*)d_in[7];
  const float* action_out_b  = (const float*)d_in[8];
  const float* tmlp_in_w     = (const float*)d_in[9];
  const float* tmlp_in_b     = (const float*)d_in[10];
  const float* tmlp_out_w    = (const float*)d_in[11];
  const float* tmlp_out_b    = (const float*)d_in[12];
  const float* w_q    = (const float*)d_in[13];
  const float* w_k    = (const float*)d_in[14];
  const float* w_v    = (const float*)d_in[15];
  const float* w_o    = (const float*)d_in[16];
  const float* w_gate = (const float*)d_in[17];
  const float* w_up   = (const float*)d_in[18];
  const float* w_down = (const float*)d_in[19];
  const float* in_norm_w    = (const float*)d_in[20];
  const float* in_scale_w   = (const float*)d_in[21];
  const float* in_gate_w    = (const float*)d_in[22];
  const float* post_norm_w  = (const float*)d_in[23];
  const float* post_scale_w = (const float*)d_in[24];
  const float* post_gate_w  = (const float*)d_in[25];
  const float* fnorm_w       = (const float*)d_in[26];
  const float* fnorm_scale_w = (const float*)d_in[27];

  char* wsp = (char*)d_ws;
  auto alloc = [&](size_t bytes) { void* p = (void*)wsp; wsp += (bytes + 255) & ~(size_t)255; return p; };

  float* emb0   = (float*)alloc((size_t)8 * H_ * 4);
  float* emb1   = (float*)alloc((size_t)8 * H_ * 4);
  float* cond   = (float*)alloc((size_t)8 * H_ * 4);
  float* fscale = (float*)alloc((size_t)8 * H_ * 4);
  float* gates  = (float*)alloc((size_t)4 * L_ * 8 * H_ * 4);
  int*   offs   = (int*)alloc(64);
  float* hbuf   = (float*)alloc((size_t)MPAD_ * H_ * 4);
  float* h1buf  = (float*)alloc((size_t)MPAD_ * H_ * 4);
  unsigned short* normed  = (unsigned short*)alloc((size_t)MPAD_ * H_ * 2);
  unsigned short* normed2 = (unsigned short*)alloc((size_t)MPAD_ * H_ * 2);
  unsigned short* q_r     = (unsigned short*)alloc((size_t)B_ * NH_ * 64 * HD_ * 2);
  unsigned short* Kf_all  = (unsigned short*)alloc((size_t)L_ * B_ * TPAD_ * HD_ * 2);
  unsigned short* Vt_all  = (unsigned short*)alloc((size_t)L_ * B_ * HD_ * TPAD_ * 2);
  unsigned short* attb    = (unsigned short*)alloc((size_t)MPAD_ * 2048 * 2);
  unsigned short* t_buf   = (unsigned short*)alloc((size_t)MPAD_ * FF_ * 2);
  float* wopart = (float*)alloc((size_t)4 * MPAD_ * 1024 * 4);
  float* dpart  = (float*)alloc((size_t)4 * MPAD_ * 1024 * 4);

  // attb pad rows never written by flash8: zero once (stays zero all layers)
  hipMemsetAsync(attb + (size_t)MROWS_ * 2048, 0, (size_t)(MPAD_ - MROWS_) * 2048 * 2, stream);
  // normed2 pad rows never written (redA grid = 400): zero once so upg A-reads stay finite
  hipMemsetAsync(normed2 + (size_t)MROWS_ * H_, 0, (size_t)(MPAD_ - MROWS_) * H_ * 2, stream);
  // t_buf pad rows never written by upg: zero once
  hipMemsetAsync(t_buf + (size_t)MROWS_ * FF_, 0, (size_t)(MPAD_ - MROWS_) * FF_ * 2, stream);

  emb_k<<<8, 256, 0, stream>>>(timestep, emb0);
  gemm8_k<<<16, 256, 0, stream>>>(emb0, tmlp_in_w, tmlp_in_b, emb1, 1);
  gemm8_k<<<16, 256, 0, stream>>>(emb1, tmlp_out_w, tmlp_out_b, cond, 1);
  gemm8_k<<<16, 256, 0, stream>>>(cond, fnorm_scale_w, nullptr, fscale, 0);
  gates_k<<<dim3(16, L_, 4), 256, 0, stream>>>(cond, in_scale_w, in_gate_w, post_scale_w, post_gate_w, gates);
  offs_k<<<1, 256, 0, stream>>>(pad_mask, offs);
  action_in_k<<<(MPAD_ * H_) / 256, 256, 0, stream>>>(x_t, action_in_w, action_in_b, hbuf);
  prefixAll_k<<<dim3(16, B_, L_), 256, 0, stream>>>(prefix_keys, prefix_values, Kf_all, Vt_all);
  ada_k<<<MPAD_, 256, 0, stream>>>(hbuf, in_norm_w, gates, normed);  // layer-0 in_scale = gates z=0,l=0

  for (int i = 0; i < L_; i++) {
    const float* wq_i = w_q + (size_t)i * H_ * 2048;
    const float* wk_i = w_k + (size_t)i * H_ * HD_;
    const float* wv_i = w_v + (size_t)i * H_ * HD_;
    const float* wo_i = w_o + (size_t)i * 2048 * H_;
    const float* wg_i = w_gate + (size_t)i * H_ * FF_;
    const float* wu_i = w_up + (size_t)i * H_ * FF_;
    const float* wd_i = w_down + (size_t)i * FF_ * H_;
    const float* g_in_gate    = gates + ((size_t)(1 * L_ + i) * 8) * H_;
    const float* g_post_scale = gates + ((size_t)(2 * L_ + i) * 8) * H_;
    const float* g_post_gate  = gates + ((size_t)(3 * L_ + i) * 8) * H_;
    unsigned short* Kf_l = Kf_all + (size_t)i * B_ * TPAD_ * HD_;
    unsigned short* Vt_l = Vt_all + (size_t)i * B_ * HD_ * TPAD_;

    qkvF_k<<<dim3(80, 2), 512, 0, stream>>>(normed, wq_i, wk_i, wv_i, offs, q_r, Kf_l, Vt_l);
    flash8_k<<<dim3(B_, 4, NH_), 512, 0, stream>>>(q_r, Kf_l, Vt_l, attb);
    gemmS_k<1, 4, 2, 2048><<<dim3(32, 4, 2), 512, 0, stream>>>(attb, wo_i, wopart);
    redA_k<4><<<MROWS_, 256, 0, stream>>>(wopart, hbuf, g_in_gate, post_norm_w + (size_t)i * H_,
                                          g_post_scale, h1buf, normed2);
    upg_k<<<dim3(128, 2), 512, 0, stream>>>(normed2, wg_i, wu_i, t_buf);
    gemmS_k<3, 4, 2, 4096><<<dim3(32, 4, 2), 512, 0, stream>>>(t_buf, wd_i, dpart);
    const float* nw_next = (i + 1 < L_) ? in_norm_w + (size_t)(i + 1) * H_ : fnorm_w;
    const float* sc_next = (i + 1 < L_) ? gates + ((size_t)(i + 1) * 8) * H_ : fscale;
    redA_k<4><<<MROWS_, 256, 0, stream>>>(dpart, h1buf, g_post_gate, nw_next, sc_next, hbuf, normed);
  }

  fout_k<<<MROWS_, 256, 0, stream>>>(normed, action_out_w, action_out_b, (float*)d_out);
}

// Round 16
// 2639.140 us; speedup vs baseline: 2.0176x; 1.0029x over previous
//
#include <hip/hip_runtime.h>

#define L_ 18
#define H_ 1024
#define NH_ 8
#define HD_ 256
#define FF_ 4096
#define HOR_ 50
#define PRE_ 968
#define B_ 8
#define AD_ 32
#define TPAD_ 1024
#define MROWS_ 400
#define MPAD_ 512
#define KSTEP_ 128
#define LST_ 132

typedef float f32x4 __attribute__((ext_vector_type(4)));
typedef short s16x4 __attribute__((ext_vector_type(4)));
typedef short s16x8 __attribute__((ext_vector_type(8)));
typedef unsigned short u16x8 __attribute__((ext_vector_type(8)));

__device__ __forceinline__ unsigned short f2bf(float f) {
  unsigned u = __float_as_uint(f);
  u += 0x7FFFu + ((u >> 16) & 1u);
  return (unsigned short)(u >> 16);
}
__device__ __forceinline__ float bf2f(unsigned short h) {
  return __uint_as_float(((unsigned)h) << 16);
}
__device__ __forceinline__ float wave_sum(float v) {
#pragma unroll
  for (int o = 32; o > 0; o >>= 1) v += __shfl_xor(v, o);
  return v;
}

// ---------------------------------------------------------------- time embedding
__global__ __launch_bounds__(256) void emb_k(const float* __restrict__ ts, float* __restrict__ emb) {
  int b = blockIdx.x, tid = threadIdx.x;
  float t = ts[b];
  for (int j = tid; j < 512; j += 256) {
    float ang = 1570.7963267948966f * expf((float)j * (-6.907755278982137f / 511.0f)) * t;
    emb[(size_t)b * H_ + j] = sinf(ang);
    emb[(size_t)b * H_ + 512 + j] = cosf(ang);
  }
}

// ---------------------------------------------------------------- [8,1024]@[1024,1024] (+bias,+silu)
__global__ __launch_bounds__(256) void gemm8_k(const float* __restrict__ A8, const float* __restrict__ W,
                                               const float* __restrict__ bias, float* __restrict__ out,
                                               int act) {
  __shared__ float a_s[8 * 1024];
  __shared__ float red[4][8][64];
  int tid = threadIdx.x;
  for (int i = tid; i < 8 * 1024; i += 256) a_s[i] = A8[i];
  __syncthreads();
  int nl = tid & 63, kg = tid >> 6;
  int n = blockIdx.x * 64 + nl;
  float acc[8];
#pragma unroll
  for (int m = 0; m < 8; m++) acc[m] = 0.f;
  for (int k = kg * 256; k < kg * 256 + 256; k++) {
    float wv = W[(size_t)k * 1024 + n];
#pragma unroll
    for (int m = 0; m < 8; m++) acc[m] += a_s[m * 1024 + k] * wv;
  }
#pragma unroll
  for (int m = 0; m < 8; m++) red[kg][m][nl] = acc[m];
  __syncthreads();
  if (kg == 0) {
#pragma unroll
    for (int m = 0; m < 8; m++) {
      float v = red[0][m][nl] + red[1][m][nl] + red[2][m][nl] + red[3][m][nl];
      if (bias) v += bias[n];
      if (act) v = v / (1.f + expf(-v));
      out[(size_t)m * 1024 + n] = v;
    }
  }
}

// ---------------------------------------------------------------- all 72 adaLN cond GEMMs in one grid
__global__ __launch_bounds__(256) void gates_k(const float* __restrict__ cond,
                                               const float* __restrict__ w0, const float* __restrict__ w1,
                                               const float* __restrict__ w2, const float* __restrict__ w3,
                                               float* __restrict__ gates) {
  __shared__ float a_s[8 * 1024];
  __shared__ float red[4][8][64];
  int tid = threadIdx.x;
  for (int i = tid; i < 8 * 1024; i += 256) a_s[i] = cond[i];
  __syncthreads();
  int z = blockIdx.z, layer = blockIdx.y;
  const float* W = (z == 0 ? w0 : z == 1 ? w1 : z == 2 ? w2 : w3) + (size_t)layer * H_ * H_;
  float* out = gates + ((size_t)(z * L_ + layer) * 8) * H_;
  int nl = tid & 63, kg = tid >> 6;
  int n = blockIdx.x * 64 + nl;
  float acc[8];
#pragma unroll
  for (int m = 0; m < 8; m++) acc[m] = 0.f;
  for (int k = kg * 256; k < kg * 256 + 256; k++) {
    float wv = W[(size_t)k * 1024 + n];
#pragma unroll
    for (int m = 0; m < 8; m++) acc[m] += a_s[m * 1024 + k] * wv;
  }
#pragma unroll
  for (int m = 0; m < 8; m++) red[kg][m][nl] = acc[m];
  __syncthreads();
  if (kg == 0) {
#pragma unroll
    for (int m = 0; m < 8; m++)
      out[(size_t)m * 1024 + n] = red[0][m][nl] + red[1][m][nl] + red[2][m][nl] + red[3][m][nl];
  }
}

// ---------------------------------------------------------------- pad-mask -> per-batch valid counts
__global__ void offs_k(const unsigned char* __restrict__ mask, int* __restrict__ offs) {
  __shared__ int cnt[8];
  __shared__ int mod4;
  int tid = threadIdx.x;
  if (tid < 8) cnt[tid] = 0;
  if (tid == 8) mod4 = 0;
  __syncthreads();
  for (int i = tid; i < B_ * PRE_; i += 256) {
    unsigned char v = mask[i];
    if (v) {
      atomicAdd(&cnt[i / PRE_], 1);
      if (i & 3) atomicAdd(&mod4, 1);
    }
  }
  __syncthreads();
  if (tid < 8) offs[tid] = (mod4 == 0) ? cnt[tid] * 4 : cnt[tid];
}

// ---------------------------------------------------------------- h = x_t @ action_in_w + b  (pad rows = 0)
__global__ __launch_bounds__(256) void action_in_k(const float* __restrict__ xt, const float* __restrict__ Wi,
                                                   const float* __restrict__ bi, float* __restrict__ h) {
  int idx = blockIdx.x * 256 + threadIdx.x;
  int m = idx >> 10, n = idx & 1023;
  float v = 0.f;
  if (m < MROWS_) {
    const float* xr = xt + (size_t)m * AD_;
#pragma unroll
    for (int k = 0; k < AD_; k++) v += xr[k] * Wi[(size_t)k * H_ + n];
    v += bi[n];
  }
  h[idx] = v;
}

// ---------------------------------------------------------------- AdaRMSNorm -> bf16 (pad rows = 0), layer-0 only
__global__ __launch_bounds__(256) void ada_k(const float* __restrict__ X, const float* __restrict__ nw,
                                             const float* __restrict__ sc, unsigned short* __restrict__ Y) {
  int m = blockIdx.x, tid = threadIdx.x;
  size_t base = (size_t)m * H_;
  if (m >= MROWS_) {
#pragma unroll
    for (int j = 0; j < 4; j++) Y[base + tid * 4 + j] = 0;
    return;
  }
  f32x4 x = *(const f32x4*)(X + base + tid * 4);
  float ss = x[0] * x[0] + x[1] * x[1] + x[2] * x[2] + x[3] * x[3];
  __shared__ float r4[4];
  float wsv = wave_sum(ss);
  if ((tid & 63) == 0) r4[tid >> 6] = wsv;
  __syncthreads();
  float rs = rsqrtf((r4[0] + r4[1] + r4[2] + r4[3]) * (1.f / 1024.f) + 1e-6f);
  int b = m / HOR_;
#pragma unroll
  for (int j = 0; j < 4; j++) {
    int n = tid * 4 + j;
    Y[base + n] = f2bf(x[j] * rs * (1.f + nw[n]) * (1.f + sc[(size_t)b * H_ + n]));
  }
}

// ---------------------------------------------------------------- all-layer prefix convert: K row-major, V transposed
__global__ __launch_bounds__(256) void prefixAll_k(const float* __restrict__ pk, const float* __restrict__ pv,
                                                   unsigned short* __restrict__ Kf_all,
                                                   unsigned short* __restrict__ Vt_all) {
  int b = blockIdx.y, t0 = blockIdx.x * 64, layer = blockIdx.z, tid = threadIdx.x;
  unsigned short* Kf = Kf_all + (size_t)layer * B_ * TPAD_ * HD_;
  unsigned short* Vt = Vt_all + (size_t)layer * B_ * HD_ * TPAD_;
  __shared__ unsigned short vt[256][72];
  const float* kp = pk + ((size_t)(b * L_ + layer)) * PRE_ * HD_;
  const float* vp = pv + ((size_t)(b * L_ + layer)) * PRE_ * HD_;
  for (int i = 0; i < 64; i++) {
    int t = t0 + i;
    float kv = 0.f, vv = 0.f;
    if (t < PRE_) {
      kv = kp[(size_t)t * HD_ + tid];
      vv = vp[(size_t)t * HD_ + tid];
    }
    Kf[((size_t)b * TPAD_ + t) * HD_ + tid] = f2bf(kv);  // suffix rows rewritten per layer by qkvF
    vt[tid][i] = f2bf(vv);
  }
  __syncthreads();
#pragma unroll
  for (int p = 0; p < 4; p++) {
    int d = p * 64 + (tid >> 2);
    int c0 = (tid & 3) * 16;
    u16x8 v0, v1;
#pragma unroll
    for (int j = 0; j < 8; j++) { v0[j] = vt[d][c0 + j]; v1[j] = vt[d][c0 + 8 + j]; }
    size_t dst = ((size_t)(b * HD_ + d)) * TPAD_ + t0 + c0;
    *(u16x8*)(Vt + dst) = v0;
    *(u16x8*)(Vt + dst + 8) = v1;
  }
}

// ================================================================ QKV GEMM (XCD-contiguous strips) + RoPE/scatter
// grid (80 strips, 2 m-halves), 512 thr. Strip remap: XCD j (=x%8) owns strips 10j..10j+9 so each
// XCD's L2 streams a contiguous column panel of W (dense DRAM bursts instead of 128B/4KB slivers).
__global__ __launch_bounds__(512) void qkvF_k(const unsigned short* __restrict__ A,
                                              const float* __restrict__ Wq, const float* __restrict__ Wk,
                                              const float* __restrict__ Wv, const int* __restrict__ offs,
                                              unsigned short* __restrict__ q_r, unsigned short* __restrict__ Kf,
                                              unsigned short* __restrict__ Vt) {
  const int stRaw = blockIdx.x;
  const int st = (stRaw & 7) * 10 + (stRaw >> 3);   // bijective on [0,80): XCD-contiguous strips
  const int mh = blockIdx.y;
  const int tid = threadIdx.x, wv = tid >> 6, l = tid & 63;
  const int lr = l & 15, kg = l >> 4, lk = kg << 2;
  const int m0 = mh * 256 + wv * 32;

  const float* W;
  int ldw, wbase;
  bool paired;
  if (st < 64)      { W = Wq; ldw = 2048; wbase = (st >> 3) * 256 + (st & 7) * 16; paired = true; }
  else if (st < 72) { W = Wk; ldw = 256;  wbase = (st - 64) * 16; paired = true; }
  else              { W = Wv; ldw = 256;  wbase = (st - 72) * 32; paired = false; }

  __shared__ unsigned short Wt[2][32][LST_];
  __shared__ int offsL[8];
  const int pr = tid >> 3, c0 = (tid & 7) * 4;
  const int wcol = wbase + c0 + ((paired && c0 >= 16) ? 112 : 0);

  if (tid < 8) offsL[tid] = offs[tid];

  f32x4 acc[2][2];
#pragma unroll
  for (int a = 0; a < 2; a++)
#pragma unroll
    for (int b = 0; b < 2; b++) acc[a][b] = (f32x4){0.f, 0.f, 0.f, 0.f};

  f32x4 pa0[2], pa1[2];
  auto LOADW = [&](int IT) {
    int sl = IT & 1;
    size_t kk = (size_t)IT * KSTEP_ + 2 * pr;
    pa0[sl] = *(const f32x4*)(W + kk * ldw + wcol);
    pa1[sl] = *(const f32x4*)(W + (kk + 1) * ldw + wcol);
  };
  auto STOREW = [&](int IT) {
    int sl = IT & 1;
#pragma unroll
    for (int j = 0; j < 4; j++) {
      unsigned v = (unsigned)f2bf(pa0[sl][j]) | ((unsigned)f2bf(pa1[sl][j]) << 16);
      *(unsigned*)&Wt[sl][c0 + j][2 * pr] = v;
    }
  };

  s16x8 aP[2][4];
  auto LOADA = [&](int IT) {
    const int kb = IT * KSTEP_;
#pragma unroll
    for (int s = 0; s < 4; s++)
#pragma unroll
      for (int mf = 0; mf < 2; mf++)
        aP[mf][s] = *(const s16x8*)(A + (size_t)(m0 + mf * 16 + lr) * H_ + kb + s * 32 + 8 * kg);
  };

  LOADW(0);
  LOADW(1);
  LOADA(0);
  STOREW(0);
  __syncthreads();

#pragma unroll
  for (int it = 0; it < 8; ++it) {
    if (it + 2 < 8) LOADW(it + 2);
#pragma unroll
    for (int s = 0; s < 4; s++) {
      s16x8 bfr[2];
#pragma unroll
      for (int nf = 0; nf < 2; nf++) {
        const unsigned short* wp = &Wt[it & 1][nf * 16 + lr][s * 32 + 2 * lk];
        s16x4 b0 = *(const s16x4*)wp;
        s16x4 b1 = *(const s16x4*)(wp + 4);
#pragma unroll
        for (int j = 0; j < 4; j++) { bfr[nf][j] = b0[j]; bfr[nf][4 + j] = b1[j]; }
      }
#pragma unroll
      for (int mf = 0; mf < 2; mf++)
#pragma unroll
        for (int nf = 0; nf < 2; nf++)
          acc[mf][nf] = __builtin_amdgcn_mfma_f32_16x16x32_bf16(aP[mf][s], bfr[nf], acc[mf][nf], 0, 0, 0);
    }
    if (it + 1 < 8) {
      LOADA(it + 1);
      STOREW(it + 1);
    }
    __syncthreads();
  }

  const float RK = -9.210340371976184f / 128.0f;
  if (st < 64) {  // Q: rope pair, write q_r
    const int h = st >> 3, x = (st & 7) * 16, dd = x + lr;
    const float inv = expf((float)dd * RK);
#pragma unroll
    for (int mf = 0; mf < 2; mf++)
#pragma unroll
      for (int r = 0; r < 4; r++) {
        int m = m0 + mf * 16 + lk + r;
        if (m >= MROWS_) continue;
        int b = m / HOR_, s = m - b * HOR_;
        float ang = (float)(offsL[b] + s) * inv;
        float cc = cosf(ang), sn = sinf(ang);
        float v1 = acc[mf][0][r], v2 = acc[mf][1][r];
        size_t base = ((size_t)(b * NH_ + h) * 64 + s) * HD_;
        q_r[base + dd] = f2bf(v1 * cc - v2 * sn);
        q_r[base + dd + 128] = f2bf(v2 * cc + v1 * sn);
      }
  } else if (st < 72) {  // K: rope pair, write Kf suffix rows
    const int x = (st - 64) * 16, dd = x + lr;
    const float inv = expf((float)dd * RK);
#pragma unroll
    for (int mf = 0; mf < 2; mf++)
#pragma unroll
      for (int r = 0; r < 4; r++) {
        int m = m0 + mf * 16 + lk + r;
        if (m >= MROWS_) continue;
        int b = m / HOR_, s = m - b * HOR_;
        float ang = (float)(offsL[b] + s) * inv;
        float cc = cosf(ang), sn = sinf(ang);
        float v1 = acc[mf][0][r], v2 = acc[mf][1][r];
        size_t base = ((size_t)b * TPAD_ + PRE_ + s) * HD_;
        Kf[base + dd] = f2bf(v1 * cc - v2 * sn);
        Kf[base + dd + 128] = f2bf(v2 * cc + v1 * sn);
      }
  } else {  // V: write Vt columns
    const int x = (st - 72) * 32;
#pragma unroll
    for (int mf = 0; mf < 2; mf++)
#pragma unroll
      for (int nf = 0; nf < 2; nf++)
#pragma unroll
        for (int r = 0; r < 4; r++) {
          int m = m0 + mf * 16 + lk + r;
          if (m >= MROWS_) continue;
          int b = m / HOR_, s = m - b * HOR_;
          int d = x + nf * 16 + lr;
          Vt[((size_t)(b * HD_ + d)) * TPAD_ + PRE_ + s] = f2bf(acc[mf][nf][r]);
        }
  }
}

// ================================================================ 8-wave flash attention (validated round-12)
// grid (B, 4 rg, NH) [b = bid%8 -> per-batch KV pinned to one XCD's L2]. 512 thr = 8 waves.
__global__ __launch_bounds__(512) void flash8_k(const unsigned short* __restrict__ qr,
                                                const unsigned short* __restrict__ Kf,
                                                const unsigned short* __restrict__ Vt,
                                                unsigned short* __restrict__ attb) {
  const int b = blockIdx.x, rg = blockIdx.y, h = blockIdx.z;
  const int bh = b * NH_ + h;
  const int tid = threadIdx.x, w = tid >> 6, l = tid & 63;
  const int lr = l & 15, kg = l >> 4;
  const int t0 = w * 128;

  __shared__ __align__(16) unsigned short Pl[8][16][136];
  __shared__ float mlS[8][16][2];

  const unsigned short* qbase = qr + ((size_t)bh * 64 + rg * 16 + lr) * HD_;
  s16x8 afr[8];
#pragma unroll
  for (int js = 0; js < 8; js++) afr[js] = *(const s16x8*)(qbase + js * 32 + 8 * kg);
  f32x4 sc[8];
#pragma unroll
  for (int nf = 0; nf < 8; nf++) sc[nf] = (f32x4){0.f, 0.f, 0.f, 0.f};
  const unsigned short* kb = Kf + ((size_t)b * TPAD_ + t0) * HD_;
#pragma unroll
  for (int js = 0; js < 8; js++)
#pragma unroll
    for (int nf = 0; nf < 8; nf++) {
      s16x8 bv = *(const s16x8*)(kb + (size_t)(nf * 16 + lr) * HD_ + js * 32 + 8 * kg);
      sc[nf] = __builtin_amdgcn_mfma_f32_16x16x32_bf16(afr[js], bv, sc[nf], 0, 0, 0);
    }
  float mx[4] = {-3.0e38f, -3.0e38f, -3.0e38f, -3.0e38f};
#pragma unroll
  for (int nf = 0; nf < 8; nf++) {
    int t = t0 + nf * 16 + lr;
#pragma unroll
    for (int r = 0; r < 4; r++) {
      int srw = rg * 16 + 4 * kg + r;
      float v = sc[nf][r] * 0.0625f;
      if (t >= PRE_ && (t - PRE_) > srw) v = -1e9f;
      sc[nf][r] = v;
      mx[r] = fmaxf(mx[r], v);
    }
  }
#pragma unroll
  for (int o = 8; o > 0; o >>= 1)
#pragma unroll
    for (int r = 0; r < 4; r++) mx[r] = fmaxf(mx[r], __shfl_xor(mx[r], o));
  float ls[4] = {0.f, 0.f, 0.f, 0.f};
#pragma unroll
  for (int nf = 0; nf < 8; nf++)
#pragma unroll
    for (int r = 0; r < 4; r++) {
      float p = expf(sc[nf][r] - mx[r]);
      sc[nf][r] = p;
      ls[r] += p;
    }
#pragma unroll
  for (int o = 8; o > 0; o >>= 1)
#pragma unroll
    for (int r = 0; r < 4; r++) ls[r] += __shfl_xor(ls[r], o);
#pragma unroll
  for (int nf = 0; nf < 8; nf++)
#pragma unroll
    for (int r = 0; r < 4; r++) Pl[w][4 * kg + r][nf * 16 + lr] = f2bf(sc[nf][r]);
  if (lr == 0) {
#pragma unroll
    for (int r = 0; r < 4; r++) {
      mlS[w][4 * kg + r][0] = mx[r];
      mlS[w][4 * kg + r][1] = ls[r];
    }
  }
  __syncthreads();
  f32x4 o4[8][2];
#pragma unroll
  for (int a = 0; a < 8; a++)
#pragma unroll
    for (int c = 0; c < 2; c++) o4[a][c] = (f32x4){0.f, 0.f, 0.f, 0.f};
#pragma unroll
  for (int wz = 0; wz < 8; wz++)
#pragma unroll
    for (int ti = 0; ti < 128; ti += 32) {
      s16x8 a = *(const s16x8*)&Pl[wz][lr][ti + 8 * kg];
#pragma unroll
      for (int nf = 0; nf < 2; nf++) {
        s16x8 bv = *(const s16x8*)(Vt + ((size_t)(b * HD_ + w * 32 + nf * 16 + lr)) * TPAD_ +
                                   wz * 128 + ti + 8 * kg);
        o4[wz][nf] = __builtin_amdgcn_mfma_f32_16x16x32_bf16(a, bv, o4[wz][nf], 0, 0, 0);
      }
    }
#pragma unroll
  for (int r = 0; r < 4; r++) {
    int row = 4 * kg + r;
    int s = rg * 16 + row;
    if (s >= HOR_) continue;
    float M = -3.0e38f;
#pragma unroll
    for (int wz = 0; wz < 8; wz++) M = fmaxf(M, mlS[wz][row][0]);
    float w8[8], Lden = 0.f;
#pragma unroll
    for (int wz = 0; wz < 8; wz++) {
      w8[wz] = expf(mlS[wz][row][0] - M);
      Lden += w8[wz] * mlS[wz][row][1];
    }
    float invL = 1.f / Lden;
#pragma unroll
    for (int nf = 0; nf < 2; nf++) {
      float o = 0.f;
#pragma unroll
      for (int wz = 0; wz < 8; wz++) o += w8[wz] * o4[wz][nf][r];
      attb[((size_t)(b * HOR_ + s)) * 2048 + h * HD_ + w * 32 + nf * 16 + lr] = f2bf(o * invL);
    }
  }
}

// ================================================================ split-K MFMA GEMM stage 1 (XCD-contiguous strips)
// MODE 1=WO, 3=DOWN. KSZT compile-time. Strip remap: XCD j (=x%8) owns strips 4j..4j+3.
template <int MODE, int NS, int MS, int KSZT>
__global__ __launch_bounds__(512) void gemmS_k(const unsigned short* __restrict__ A,
                                               const float* __restrict__ W0,
                                               float* __restrict__ part) {
  constexpr int NF = 2;
  constexpr int RPW = 64 / MS;
  constexpr int MFC = RPW / 16;
  constexpr int KC = KSZT / NS;
  constexpr int NITER = KC / KSTEP_;
  const int tid = threadIdx.x;
  const int wv = tid >> 6, l = tid & 63;
  const int lr = l & 15, lk = (l >> 4) << 2;
  const int stRaw = blockIdx.x;
  const int n0 = ((stRaw & 7) * 4 + (stRaw >> 3)) * 32;   // XCD-contiguous strip remap (32 strips)
  const int kz = blockIdx.y;
  const int kbase = kz * KC;
  const int m0 = (int)blockIdx.z * (512 / MS) + wv * RPW;

  __shared__ unsigned short Wt[2][32][LST_];
  const int pr = tid >> 3;
  const int c0 = (tid & 7) * 4;

  f32x4 acc[MFC][NF];
#pragma unroll
  for (int a = 0; a < MFC; a++)
#pragma unroll
    for (int b = 0; b < NF; b++) acc[a][b] = (f32x4){0.f, 0.f, 0.f, 0.f};

  f32x4 pa0[2], pa1[2];
  auto LOADW = [&](int IT) {
    int sl = IT & 1;
    size_t kk = (size_t)(kbase + IT * KSTEP_ + 2 * pr);
    pa0[sl] = *(const f32x4*)(W0 + kk * 1024 + n0 + c0);
    pa1[sl] = *(const f32x4*)(W0 + (kk + 1) * 1024 + n0 + c0);
  };
  auto STOREW = [&](int IT) {
    int sl = IT & 1;
#pragma unroll
    for (int j = 0; j < 4; j++) {
      unsigned v = (unsigned)f2bf(pa0[sl][j]) | ((unsigned)f2bf(pa1[sl][j]) << 16);
      *(unsigned*)&Wt[sl][c0 + j][2 * pr] = v;
    }
  };

  s16x8 aP[MFC][4];
  auto LOADA = [&](int IT) {
    const int kb = kbase + IT * KSTEP_;
#pragma unroll
    for (int s = 0; s < 4; s++)
#pragma unroll
      for (int mf = 0; mf < MFC; mf++)
        aP[mf][s] = *(const s16x8*)(A + (size_t)(m0 + mf * 16 + lr) * KSZT + kb + s * 32 + 2 * lk);
  };

  LOADW(0);
  if (NITER > 1) LOADW(1);
  LOADA(0);
  STOREW(0);
  __syncthreads();

#pragma unroll
  for (int it = 0; it < NITER; ++it) {
    if (it + 2 < NITER) LOADW(it + 2);
#pragma unroll
    for (int s = 0; s < 4; s++) {
      s16x8 bfr[NF];
#pragma unroll
      for (int nf = 0; nf < NF; nf++) {
        const unsigned short* wp = &Wt[it & 1][nf * 16 + lr][s * 32 + 2 * lk];
        s16x4 b0 = *(const s16x4*)wp;
        s16x4 b1 = *(const s16x4*)(wp + 4);
#pragma unroll
        for (int j = 0; j < 4; j++) { bfr[nf][j] = b0[j]; bfr[nf][4 + j] = b1[j]; }
      }
#pragma unroll
      for (int mf = 0; mf < MFC; mf++)
#pragma unroll
        for (int nf = 0; nf < NF; nf++)
          acc[mf][nf] = __builtin_amdgcn_mfma_f32_16x16x32_bf16(aP[mf][s], bfr[nf], acc[mf][nf], 0, 0, 0);
    }
    if (it + 1 < NITER) {
      LOADA(it + 1);
      STOREW(it + 1);
    }
    __syncthreads();
  }

#pragma unroll
  for (int mf = 0; mf < MFC; mf++)
#pragma unroll
    for (int nf = 0; nf < NF; nf++)
#pragma unroll
      for (int r = 0; r < 4; r++) {
        int row = m0 + mf * 16 + lk + r;
        if (row >= MROWS_) continue;
        int col = n0 + nf * 16 + lr;
        part[((size_t)kz * MPAD_ + row) * 1024 + col] = acc[mf][nf][r];
      }
}

// ---------------------------------------------------------------- split-K reduce + residual-gate + AdaRMSNorm
template <int NS>
__global__ __launch_bounds__(256) void redA_k(const float* __restrict__ part, const float* __restrict__ prev,
                                              const float* __restrict__ gatev, const float* __restrict__ nw,
                                              const float* __restrict__ sc, float* __restrict__ outH,
                                              unsigned short* __restrict__ outN) {
  int r = blockIdx.x, tid = threadIdx.x;
  int c = tid * 4;
  int b = r / HOR_;
  f32x4 v = (f32x4){0.f, 0.f, 0.f, 0.f};
#pragma unroll
  for (int z = 0; z < NS; z++) v += *(const f32x4*)(part + ((size_t)z * MPAD_ + r) * H_ + c);
  f32x4 pv = *(const f32x4*)(prev + (size_t)r * H_ + c);
  f32x4 gv = *(const f32x4*)(gatev + (size_t)b * H_ + c);
  f32x4 h = pv + gv * v;
  *(f32x4*)(outH + (size_t)r * H_ + c) = h;
  float ss = h[0] * h[0] + h[1] * h[1] + h[2] * h[2] + h[3] * h[3];
  __shared__ float r4[4];
  float wsv = wave_sum(ss);
  if ((tid & 63) == 0) r4[tid >> 6] = wsv;
  __syncthreads();
  float rs = rsqrtf((r4[0] + r4[1] + r4[2] + r4[3]) * (1.f / 1024.f) + 1e-6f);
#pragma unroll
  for (int j = 0; j < 4; j++) {
    int n = c + j;
    outN[(size_t)r * H_ + n] = f2bf(h[j] * rs * (1.f + nw[n]) * (1.f + sc[(size_t)b * H_ + n]));
  }
}

// ================================================================ upgate dual GEMM (XCD-contiguous strips)
// grid (128 strips of 32, 2 m-halves), 512 thr, full-K NITER=8. Strip remap: XCD j owns strips 16j..16j+15.
__global__ __launch_bounds__(512) void upg_k(const unsigned short* __restrict__ A, const float* __restrict__ Wg,
                                             const float* __restrict__ Wu, unsigned short* __restrict__ tb) {
  const int stRaw = blockIdx.x;
  const int st = (stRaw & 7) * 16 + (stRaw >> 3);   // bijective on [0,128)
  const int mh = blockIdx.y;
  const int n0 = st * 32;
  const int tid = threadIdx.x, wv = tid >> 6, l = tid & 63;
  const int lr = l & 15, kg = l >> 4, lk = kg << 2;
  const int m0 = mh * 256 + wv * 32;

  __shared__ unsigned short Wt[2][64][LST_];
  const int pr = tid >> 3, c0 = (tid & 7) * 4;

  f32x4 acc[2][4];
#pragma unroll
  for (int a = 0; a < 2; a++)
#pragma unroll
    for (int b = 0; b < 4; b++) acc[a][b] = (f32x4){0.f, 0.f, 0.f, 0.f};

  f32x4 pa0, pa1, pb0, pb1;
  auto LOADW = [&](int IT) {
    size_t kk = (size_t)IT * KSTEP_ + 2 * pr;
    pa0 = *(const f32x4*)(Wg + kk * 4096 + n0 + c0);
    pa1 = *(const f32x4*)(Wg + (kk + 1) * 4096 + n0 + c0);
    pb0 = *(const f32x4*)(Wu + kk * 4096 + n0 + c0);
    pb1 = *(const f32x4*)(Wu + (kk + 1) * 4096 + n0 + c0);
  };
  auto STOREW = [&](int BUF) {
#pragma unroll
    for (int j = 0; j < 4; j++) {
      unsigned v = (unsigned)f2bf(pa0[j]) | ((unsigned)f2bf(pa1[j]) << 16);
      *(unsigned*)&Wt[BUF][c0 + j][2 * pr] = v;
      unsigned u = (unsigned)f2bf(pb0[j]) | ((unsigned)f2bf(pb1[j]) << 16);
      *(unsigned*)&Wt[BUF][32 + c0 + j][2 * pr] = u;
    }
  };

  s16x8 aP[2][4];
  auto LOADA = [&](int IT) {
    const int kb = IT * KSTEP_;
#pragma unroll
    for (int s = 0; s < 4; s++)
#pragma unroll
      for (int mf = 0; mf < 2; mf++)
        aP[mf][s] = *(const s16x8*)(A + (size_t)(m0 + mf * 16 + lr) * H_ + kb + s * 32 + 8 * kg);
  };

  LOADW(0);
  LOADA(0);
  STOREW(0);
  __syncthreads();

  for (int it = 0; it < 8; ++it) {
    if (it + 1 < 8) LOADW(it + 1);
    const int cur = it & 1;
#pragma unroll
    for (int s = 0; s < 4; s++) {
      s16x8 bfr[4];
#pragma unroll
      for (int nf = 0; nf < 4; nf++) {
        const unsigned short* wp = &Wt[cur][nf * 16 + lr][s * 32 + 2 * lk];
        s16x4 b0 = *(const s16x4*)wp;
        s16x4 b1 = *(const s16x4*)(wp + 4);
#pragma unroll
        for (int j = 0; j < 4; j++) { bfr[nf][j] = b0[j]; bfr[nf][4 + j] = b1[j]; }
      }
#pragma unroll
      for (int mf = 0; mf < 2; mf++)
#pragma unroll
        for (int nf = 0; nf < 4; nf++)
          acc[mf][nf] = __builtin_amdgcn_mfma_f32_16x16x32_bf16(aP[mf][s], bfr[nf], acc[mf][nf], 0, 0, 0);
    }
    if (it + 1 < 8) {
      LOADA(it + 1);
      STOREW((it + 1) & 1);
    }
    __syncthreads();
  }

#pragma unroll
  for (int mf = 0; mf < 2; mf++)
#pragma unroll
    for (int nf = 0; nf < 2; nf++)
#pragma unroll
      for (int r = 0; r < 4; r++) {
        int row = m0 + mf * 16 + lk + r;
        if (row >= MROWS_) continue;
        int col = n0 + nf * 16 + lr;
        float g = acc[mf][nf][r];
        float u = acc[mf][nf + 2][r];
        g = 0.5f * g * (1.f + tanhf(0.7978845608028654f * (g + 0.044715f * g * g * g)));
        tb[(size_t)row * 4096 + col] = f2bf(g * u);
      }
}

// ---------------------------------------------------------------- out = normedF @ action_out_w + b
__global__ __launch_bounds__(256) void fout_k(const unsigned short* __restrict__ nf, const float* __restrict__ Wo,
                                              const float* __restrict__ bo, float* __restrict__ out) {
  int m = blockIdx.x, tid = threadIdx.x;
  int n = tid & 31, kg = tid >> 5;
  float acc = 0.f;
  for (int k = kg * 128; k < kg * 128 + 128; k++)
    acc += bf2f(nf[(size_t)m * H_ + k]) * Wo[(size_t)k * AD_ + n];
  __shared__ float red[8][32];
  red[kg][n] = acc;
  __syncthreads();
  if (kg == 0) {
    float v = 0.f;
#pragma unroll
    for (int g = 0; g < 8; g++) v += red[g][n];
    out[(size_t)m * AD_ + n] = v + bo[n];
  }
}

// ================================================================ host
extern "C" void kernel_launch(void* const* d_in, const int* in_sizes, int n_in,
                              void* d_out, int out_size, void* d_ws, size_t ws_size,
                              hipStream_t stream) {
  const float* prefix_keys   = (const float*)d_in[0];
  const float* prefix_values = (const float*)d_in[1];
  const float* x_t           = (const float*)d_in[2];
  const float* timestep      = (const float*)d_in[3];
  const unsigned char* pad_mask = (const unsigned char*)d_in[4];
  const float* action_in_w   = (const float*)d_in[5];
  const float* action_in_b   = (const float*)d_in[6];
  const float* action_out_w  = (const float*)d_in[7];
  const float* action_out_b  = (const float*)d_in[8];
  const float* tmlp_in_w     = (const float*)d_in[9];
  const float* tmlp_in_b     = (const float*)d_in[10];
  const float* tmlp_out_w    = (const float*)d_in[11];
  const float* tmlp_out_b    = (const float*)d_in[12];
  const float* w_q    = (const float*)d_in[13];
  const float* w_k    = (const float*)d_in[14];
  const float* w_v    = (const float*)d_in[15];
  const float* w_o    = (const float*)d_in[16];
  const float* w_gate = (const float*)d_in[17];
  const float* w_up   = (const float*)d_in[18];
  const float* w_down = (const float*)d_in[19];
  const float* in_norm_w    = (const float*)d_in[20];
  const float* in_scale_w   = (const float*)d_in[21];
  const float* in_gate_w    = (const float*)d_in[22];
  const float* post_norm_w  = (const float*)d_in[23];
  const float* post_scale_w = (const float*)d_in[24];
  const float* post_gate_w  = (const float*)d_in[25];
  const float* fnorm_w       = (const float*)d_in[26];
  const float* fnorm_scale_w = (const float*)d_in[27];

  char* wsp = (char*)d_ws;
  auto alloc = [&](size_t bytes) { void* p = (void*)wsp; wsp += (bytes + 255) & ~(size_t)255; return p; };

  float* emb0   = (float*)alloc((size_t)8 * H_ * 4);
  float* emb1   = (float*)alloc((size_t)8 * H_ * 4);
  float* cond   = (float*)alloc((size_t)8 * H_ * 4);
  float* fscale = (float*)alloc((size_t)8 * H_ * 4);
  float* gates  = (float*)alloc((size_t)4 * L_ * 8 * H_ * 4);
  int*   offs   = (int*)alloc(64);
  float* hbuf   = (float*)alloc((size_t)MPAD_ * H_ * 4);
  float* h1buf  = (float*)alloc((size_t)MPAD_ * H_ * 4);
  unsigned short* normed  = (unsigned short*)alloc((size_t)MPAD_ * H_ * 2);
  unsigned short* normed2 = (unsigned short*)alloc((size_t)MPAD_ * H_ * 2);
  unsigned short* q_r     = (unsigned short*)alloc((size_t)B_ * NH_ * 64 * HD_ * 2);
  unsigned short* Kf_all  = (unsigned short*)alloc((size_t)L_ * B_ * TPAD_ * HD_ * 2);
  unsigned short* Vt_all  = (unsigned short*)alloc((size_t)L_ * B_ * HD_ * TPAD_ * 2);
  unsigned short* attb    = (unsigned short*)alloc((size_t)MPAD_ * 2048 * 2);
  unsigned short* t_buf   = (unsigned short*)alloc((size_t)MPAD_ * FF_ * 2);
  float* wopart = (float*)alloc((size_t)4 * MPAD_ * 1024 * 4);
  float* dpart  = (float*)alloc((size_t)4 * MPAD_ * 1024 * 4);

  // attb pad rows never written by flash8: zero once (stays zero all layers)
  hipMemsetAsync(attb + (size_t)MROWS_ * 2048, 0, (size_t)(MPAD_ - MROWS_) * 2048 * 2, stream);
  // normed2 pad rows never written (redA grid = 400): zero once so upg A-reads stay finite
  hipMemsetAsync(normed2 + (size_t)MROWS_ * H_, 0, (size_t)(MPAD_ - MROWS_) * H_ * 2, stream);
  // t_buf pad rows never written by upg: zero once
  hipMemsetAsync(t_buf + (size_t)MROWS_ * FF_, 0, (size_t)(MPAD_ - MROWS_) * FF_ * 2, stream);

  emb_k<<<8, 256, 0, stream>>>(timestep, emb0);
  gemm8_k<<<16, 256, 0, stream>>>(emb0, tmlp_in_w, tmlp_in_b, emb1, 1);
  gemm8_k<<<16, 256, 0, stream>>>(emb1, tmlp_out_w, tmlp_out_b, cond, 1);
  gemm8_k<<<16, 256, 0, stream>>>(cond, fnorm_scale_w, nullptr, fscale, 0);
  gates_k<<<dim3(16, L_, 4), 256, 0, stream>>>(cond, in_scale_w, in_gate_w, post_scale_w, post_gate_w, gates);
  offs_k<<<1, 256, 0, stream>>>(pad_mask, offs);
  action_in_k<<<(MPAD_ * H_) / 256, 256, 0, stream>>>(x_t, action_in_w, action_in_b, hbuf);
  prefixAll_k<<<dim3(16, B_, L_), 256, 0, stream>>>(prefix_keys, prefix_values, Kf_all, Vt_all);
  ada_k<<<MPAD_, 256, 0, stream>>>(hbuf, in_norm_w, gates, normed);  // layer-0 in_scale = gates z=0,l=0

  for (int i = 0; i < L_; i++) {
    const float* wq_i = w_q + (size_t)i * H_ * 2048;
    const float* wk_i = w_k + (size_t)i * H_ * HD_;
    const float* wv_i = w_v + (size_t)i * H_ * HD_;
    const float* wo_i = w_o + (size_t)i * 2048 * H_;
    const float* wg_i = w_gate + (size_t)i * H_ * FF_;
    const float* wu_i = w_up + (size_t)i * H_ * FF_;
    const float* wd_i = w_down + (size_t)i * FF_ * H_;
    const float* g_in_gate    = gates + ((size_t)(1 * L_ + i) * 8) * H_;
    const float* g_post_scale = gates + ((size_t)(2 * L_ + i) * 8) * H_;
    const float* g_post_gate  = gates + ((size_t)(3 * L_ + i) * 8) * H_;
    unsigned short* Kf_l = Kf_all + (size_t)i * B_ * TPAD_ * HD_;
    unsigned short* Vt_l = Vt_all + (size_t)i * B_ * HD_ * TPAD_;

    qkvF_k<<<dim3(80, 2), 512, 0, stream>>>(normed, wq_i, wk_i, wv_i, offs, q_r, Kf_l, Vt_l);
    flash8_k<<<dim3(B_, 4, NH_), 512, 0, stream>>>(q_r, Kf_l, Vt_l, attb);
    gemmS_k<1, 4, 2, 2048><<<dim3(32, 4, 2), 512, 0, stream>>>(attb, wo_i, wopart);
    redA_k<4><<<MROWS_, 256, 0, stream>>>(wopart, hbuf, g_in_gate, post_norm_w + (size_t)i * H_,
                                          g_post_scale, h1buf, normed2);
    upg_k<<<dim3(128, 2), 512, 0, stream>>>(normed2, wg_i, wu_i, t_buf);
    gemmS_k<3, 4, 2, 4096><<<dim3(32, 4, 2), 512, 0, stream>>>(t_buf, wd_i, dpart);
    const float* nw_next = (i + 1 < L_) ? in_norm_w + (size_t)(i + 1) * H_ : fnorm_w;
    const float* sc_next = (i + 1 < L_) ? gates + ((size_t)(i + 1) * 8) * H_ : fscale;
    redA_k<4><<<MROWS_, 256, 0, stream>>>(dpart, h1buf, g_post_gate, nw_next, sc_next, hbuf, normed);
  }

  fout_k<<<MROWS_, 256, 0, stream>>>(normed, action_out_w, action_out_b, (float*)d_out);
}

// Round 17
// 2633.444 us; speedup vs baseline: 2.0220x; 1.0022x over previous
//
#include <hip/hip_runtime.h>

#define L_ 18
#define H_ 1024
#define NH_ 8
#define HD_ 256
#define FF_ 4096
#define HOR_ 50
#define PRE_ 968
#define B_ 8
#define AD_ 32
#define TPAD_ 1024
#define MROWS_ 400
#define MPAD_ 512
#define KSTEP_ 128
#define LST_ 132

typedef float f32x4 __attribute__((ext_vector_type(4)));
typedef short s16x4 __attribute__((ext_vector_type(4)));
typedef short s16x8 __attribute__((ext_vector_type(8)));
typedef unsigned short u16x8 __attribute__((ext_vector_type(8)));

__device__ __forceinline__ unsigned short f2bf(float f) {
  unsigned u = __float_as_uint(f);
  u += 0x7FFFu + ((u >> 16) & 1u);
  return (unsigned short)(u >> 16);
}
__device__ __forceinline__ float bf2f(unsigned short h) {
  return __uint_as_float(((unsigned)h) << 16);
}
__device__ __forceinline__ float wave_sum(float v) {
#pragma unroll
  for (int o = 32; o > 0; o >>= 1) v += __shfl_xor(v, o);
  return v;
}

// ---------------------------------------------------------------- time embedding
__global__ __launch_bounds__(256) void emb_k(const float* __restrict__ ts, float* __restrict__ emb) {
  int b = blockIdx.x, tid = threadIdx.x;
  float t = ts[b];
  for (int j = tid; j < 512; j += 256) {
    float ang = 1570.7963267948966f * expf((float)j * (-6.907755278982137f / 511.0f)) * t;
    emb[(size_t)b * H_ + j] = sinf(ang);
    emb[(size_t)b * H_ + 512 + j] = cosf(ang);
  }
}

// ---------------------------------------------------------------- [8,1024]@[1024,1024] (+bias,+silu)
__global__ __launch_bounds__(256) void gemm8_k(const float* __restrict__ A8, const float* __restrict__ W,
                                               const float* __restrict__ bias, float* __restrict__ out,
                                               int act) {
  __shared__ float a_s[8 * 1024];
  __shared__ float red[4][8][64];
  int tid = threadIdx.x;
  for (int i = tid; i < 8 * 1024; i += 256) a_s[i] = A8[i];
  __syncthreads();
  int nl = tid & 63, kg = tid >> 6;
  int n = blockIdx.x * 64 + nl;
  float acc[8];
#pragma unroll
  for (int m = 0; m < 8; m++) acc[m] = 0.f;
  for (int k = kg * 256; k < kg * 256 + 256; k++) {
    float wv = W[(size_t)k * 1024 + n];
#pragma unroll
    for (int m = 0; m < 8; m++) acc[m] += a_s[m * 1024 + k] * wv;
  }
#pragma unroll
  for (int m = 0; m < 8; m++) red[kg][m][nl] = acc[m];
  __syncthreads();
  if (kg == 0) {
#pragma unroll
    for (int m = 0; m < 8; m++) {
      float v = red[0][m][nl] + red[1][m][nl] + red[2][m][nl] + red[3][m][nl];
      if (bias) v += bias[n];
      if (act) v = v / (1.f + expf(-v));
      out[(size_t)m * 1024 + n] = v;
    }
  }
}

// ---------------------------------------------------------------- all 72 adaLN cond GEMMs in one grid
__global__ __launch_bounds__(256) void gates_k(const float* __restrict__ cond,
                                               const float* __restrict__ w0, const float* __restrict__ w1,
                                               const float* __restrict__ w2, const float* __restrict__ w3,
                                               float* __restrict__ gates) {
  __shared__ float a_s[8 * 1024];
  __shared__ float red[4][8][64];
  int tid = threadIdx.x;
  for (int i = tid; i < 8 * 1024; i += 256) a_s[i] = cond[i];
  __syncthreads();
  int z = blockIdx.z, layer = blockIdx.y;
  const float* W = (z == 0 ? w0 : z == 1 ? w1 : z == 2 ? w2 : w3) + (size_t)layer * H_ * H_;
  float* out = gates + ((size_t)(z * L_ + layer) * 8) * H_;
  int nl = tid & 63, kg = tid >> 6;
  int n = blockIdx.x * 64 + nl;
  float acc[8];
#pragma unroll
  for (int m = 0; m < 8; m++) acc[m] = 0.f;
  for (int k = kg * 256; k < kg * 256 + 256; k++) {
    float wv = W[(size_t)k * 1024 + n];
#pragma unroll
    for (int m = 0; m < 8; m++) acc[m] += a_s[m * 1024 + k] * wv;
  }
#pragma unroll
  for (int m = 0; m < 8; m++) red[kg][m][nl] = acc[m];
  __syncthreads();
  if (kg == 0) {
#pragma unroll
    for (int m = 0; m < 8; m++)
      out[(size_t)m * 1024 + n] = red[0][m][nl] + red[1][m][nl] + red[2][m][nl] + red[3][m][nl];
  }
}

// ---------------------------------------------------------------- pad-mask -> per-batch valid counts
__global__ void offs_k(const unsigned char* __restrict__ mask, int* __restrict__ offs) {
  __shared__ int cnt[8];
  __shared__ int mod4;
  int tid = threadIdx.x;
  if (tid < 8) cnt[tid] = 0;
  if (tid == 8) mod4 = 0;
  __syncthreads();
  for (int i = tid; i < B_ * PRE_; i += 256) {
    unsigned char v = mask[i];
    if (v) {
      atomicAdd(&cnt[i / PRE_], 1);
      if (i & 3) atomicAdd(&mod4, 1);
    }
  }
  __syncthreads();
  if (tid < 8) offs[tid] = (mod4 == 0) ? cnt[tid] * 4 : cnt[tid];
}

// ---------------------------------------------------------------- h = x_t @ action_in_w + b  (pad rows = 0)
__global__ __launch_bounds__(256) void action_in_k(const float* __restrict__ xt, const float* __restrict__ Wi,
                                                   const float* __restrict__ bi, float* __restrict__ h) {
  int idx = blockIdx.x * 256 + threadIdx.x;
  int m = idx >> 10, n = idx & 1023;
  float v = 0.f;
  if (m < MROWS_) {
    const float* xr = xt + (size_t)m * AD_;
#pragma unroll
    for (int k = 0; k < AD_; k++) v += xr[k] * Wi[(size_t)k * H_ + n];
    v += bi[n];
  }
  h[idx] = v;
}

// ---------------------------------------------------------------- AdaRMSNorm -> bf16 (pad rows = 0), layer-0 only
__global__ __launch_bounds__(256) void ada_k(const float* __restrict__ X, const float* __restrict__ nw,
                                             const float* __restrict__ sc, unsigned short* __restrict__ Y) {
  int m = blockIdx.x, tid = threadIdx.x;
  size_t base = (size_t)m * H_;
  if (m >= MROWS_) {
#pragma unroll
    for (int j = 0; j < 4; j++) Y[base + tid * 4 + j] = 0;
    return;
  }
  f32x4 x = *(const f32x4*)(X + base + tid * 4);
  float ss = x[0] * x[0] + x[1] * x[1] + x[2] * x[2] + x[3] * x[3];
  __shared__ float r4[4];
  float wsv = wave_sum(ss);
  if ((tid & 63) == 0) r4[tid >> 6] = wsv;
  __syncthreads();
  float rs = rsqrtf((r4[0] + r4[1] + r4[2] + r4[3]) * (1.f / 1024.f) + 1e-6f);
  int b = m / HOR_;
#pragma unroll
  for (int j = 0; j < 4; j++) {
    int n = tid * 4 + j;
    Y[base + n] = f2bf(x[j] * rs * (1.f + nw[n]) * (1.f + sc[(size_t)b * H_ + n]));
  }
}

// ---------------------------------------------------------------- all-layer prefix convert: K row-major, V transposed
__global__ __launch_bounds__(256) void prefixAll_k(const float* __restrict__ pk, const float* __restrict__ pv,
                                                   unsigned short* __restrict__ Kf_all,
                                                   unsigned short* __restrict__ Vt_all) {
  int b = blockIdx.y, t0 = blockIdx.x * 64, layer = blockIdx.z, tid = threadIdx.x;
  unsigned short* Kf = Kf_all + (size_t)layer * B_ * TPAD_ * HD_;
  unsigned short* Vt = Vt_all + (size_t)layer * B_ * HD_ * TPAD_;
  __shared__ unsigned short vt[256][72];
  const float* kp = pk + ((size_t)(b * L_ + layer)) * PRE_ * HD_;
  const float* vp = pv + ((size_t)(b * L_ + layer)) * PRE_ * HD_;
  for (int i = 0; i < 64; i++) {
    int t = t0 + i;
    float kv = 0.f, vv = 0.f;
    if (t < PRE_) {
      kv = kp[(size_t)t * HD_ + tid];
      vv = vp[(size_t)t * HD_ + tid];
    }
    Kf[((size_t)b * TPAD_ + t) * HD_ + tid] = f2bf(kv);  // suffix rows rewritten per layer by qkvF
    vt[tid][i] = f2bf(vv);
  }
  __syncthreads();
#pragma unroll
  for (int p = 0; p < 4; p++) {
    int d = p * 64 + (tid >> 2);
    int c0 = (tid & 3) * 16;
    u16x8 v0, v1;
#pragma unroll
    for (int j = 0; j < 8; j++) { v0[j] = vt[d][c0 + j]; v1[j] = vt[d][c0 + 8 + j]; }
    size_t dst = ((size_t)(b * HD_ + d)) * TPAD_ + t0 + c0;
    *(u16x8*)(Vt + dst) = v0;
    *(u16x8*)(Vt + dst + 8) = v1;
  }
}

// ================================================================ QKV GEMM (2-deep A+W, top-issued) + RoPE/scatter
// grid (80 strips, 2 m-halves), 512 thr. Full unroll => register slot indices compile-time.
__global__ __launch_bounds__(512) void qkvF_k(const unsigned short* __restrict__ A,
                                              const float* __restrict__ Wq, const float* __restrict__ Wk,
                                              const float* __restrict__ Wv, const int* __restrict__ offs,
                                              unsigned short* __restrict__ q_r, unsigned short* __restrict__ Kf,
                                              unsigned short* __restrict__ Vt) {
  const int stRaw = blockIdx.x;
  const int st = (stRaw & 7) * 10 + (stRaw >> 3);   // XCD-contiguous strips (validated r16)
  const int mh = blockIdx.y;
  const int tid = threadIdx.x, wv = tid >> 6, l = tid & 63;
  const int lr = l & 15, kg = l >> 4, lk = kg << 2;
  const int m0 = mh * 256 + wv * 32;

  const float* W;
  int ldw, wbase;
  bool paired;
  if (st < 64)      { W = Wq; ldw = 2048; wbase = (st >> 3) * 256 + (st & 7) * 16; paired = true; }
  else if (st < 72) { W = Wk; ldw = 256;  wbase = (st - 64) * 16; paired = true; }
  else              { W = Wv; ldw = 256;  wbase = (st - 72) * 32; paired = false; }

  __shared__ unsigned short Wt[2][32][LST_];
  __shared__ int offsL[8];
  const int pr = tid >> 3, c0 = (tid & 7) * 4;
  const int wcol = wbase + c0 + ((paired && c0 >= 16) ? 112 : 0);

  if (tid < 8) offsL[tid] = offs[tid];

  f32x4 acc[2][2];
#pragma unroll
  for (int a = 0; a < 2; a++)
#pragma unroll
    for (int b = 0; b < 2; b++) acc[a][b] = (f32x4){0.f, 0.f, 0.f, 0.f};

  f32x4 pa0[2], pa1[2];
  auto LOADW = [&](int IT) {
    int sl = IT & 1;
    size_t kk = (size_t)IT * KSTEP_ + 2 * pr;
    pa0[sl] = *(const f32x4*)(W + kk * ldw + wcol);
    pa1[sl] = *(const f32x4*)(W + (kk + 1) * ldw + wcol);
  };
  auto STOREW = [&](int IT) {
    int sl = IT & 1;
#pragma unroll
    for (int j = 0; j < 4; j++) {
      unsigned v = (unsigned)f2bf(pa0[sl][j]) | ((unsigned)f2bf(pa1[sl][j]) << 16);
      *(unsigned*)&Wt[sl][c0 + j][2 * pr] = v;
    }
  };

  // 2-deep A register pipeline: slot = IT&1, issued one full iteration early
  s16x8 aP[2][2][4];
  auto LOADA = [&](int IT) {
    int sl = IT & 1;
    const int kb = IT * KSTEP_;
#pragma unroll
    for (int s = 0; s < 4; s++)
#pragma unroll
      for (int mf = 0; mf < 2; mf++)
        aP[sl][mf][s] = *(const s16x8*)(A + (size_t)(m0 + mf * 16 + lr) * H_ + kb + s * 32 + 8 * kg);
  };

  LOADW(0);
  LOADW(1);
  LOADA(0);
  STOREW(0);
  __syncthreads();

#pragma unroll
  for (int it = 0; it < 8; ++it) {
    if (it + 2 < 8) LOADW(it + 2);
    if (it + 1 < 8) LOADA(it + 1);   // issued BEFORE this iteration's MFMAs: full phase of slack
#pragma unroll
    for (int s = 0; s < 4; s++) {
      s16x8 bfr[2];
#pragma unroll
      for (int nf = 0; nf < 2; nf++) {
        const unsigned short* wp = &Wt[it & 1][nf * 16 + lr][s * 32 + 2 * lk];
        s16x4 b0 = *(const s16x4*)wp;
        s16x4 b1 = *(const s16x4*)(wp + 4);
#pragma unroll
        for (int j = 0; j < 4; j++) { bfr[nf][j] = b0[j]; bfr[nf][4 + j] = b1[j]; }
      }
#pragma unroll
      for (int mf = 0; mf < 2; mf++)
#pragma unroll
        for (int nf = 0; nf < 2; nf++)
          acc[mf][nf] = __builtin_amdgcn_mfma_f32_16x16x32_bf16(aP[it & 1][mf][s], bfr[nf], acc[mf][nf], 0, 0, 0);
    }
    if (it + 1 < 8) STOREW(it + 1);
    __syncthreads();
  }

  const float RK = -9.210340371976184f / 128.0f;
  if (st < 64) {  // Q: rope pair, write q_r
    const int h = st >> 3, x = (st & 7) * 16, dd = x + lr;
    const float inv = expf((float)dd * RK);
#pragma unroll
    for (int mf = 0; mf < 2; mf++)
#pragma unroll
      for (int r = 0; r < 4; r++) {
        int m = m0 + mf * 16 + lk + r;
        if (m >= MROWS_) continue;
        int b = m / HOR_, s = m - b * HOR_;
        float ang = (float)(offsL[b] + s) * inv;
        float cc = cosf(ang), sn = sinf(ang);
        float v1 = acc[mf][0][r], v2 = acc[mf][1][r];
        size_t base = ((size_t)(b * NH_ + h) * 64 + s) * HD_;
        q_r[base + dd] = f2bf(v1 * cc - v2 * sn);
        q_r[base + dd + 128] = f2bf(v2 * cc + v1 * sn);
      }
  } else if (st < 72) {  // K: rope pair, write Kf suffix rows
    const int x = (st - 64) * 16, dd = x + lr;
    const float inv = expf((float)dd * RK);
#pragma unroll
    for (int mf = 0; mf < 2; mf++)
#pragma unroll
      for (int r = 0; r < 4; r++) {
        int m = m0 + mf * 16 + lk + r;
        if (m >= MROWS_) continue;
        int b = m / HOR_, s = m - b * HOR_;
        float ang = (float)(offsL[b] + s) * inv;
        float cc = cosf(ang), sn = sinf(ang);
        float v1 = acc[mf][0][r], v2 = acc[mf][1][r];
        size_t base = ((size_t)b * TPAD_ + PRE_ + s) * HD_;
        Kf[base + dd] = f2bf(v1 * cc - v2 * sn);
        Kf[base + dd + 128] = f2bf(v2 * cc + v1 * sn);
      }
  } else {  // V: write Vt columns
    const int x = (st - 72) * 32;
#pragma unroll
    for (int mf = 0; mf < 2; mf++)
#pragma unroll
      for (int nf = 0; nf < 2; nf++)
#pragma unroll
        for (int r = 0; r < 4; r++) {
          int m = m0 + mf * 16 + lk + r;
          if (m >= MROWS_) continue;
          int b = m / HOR_, s = m - b * HOR_;
          int d = x + nf * 16 + lr;
          Vt[((size_t)(b * HD_ + d)) * TPAD_ + PRE_ + s] = f2bf(acc[mf][nf][r]);
        }
  }
}

// ================================================================ 8-wave flash attention (validated round-12)
// grid (B, 4 rg, NH) [b = bid%8 -> per-batch KV pinned to one XCD's L2]. 512 thr = 8 waves.
__global__ __launch_bounds__(512) void flash8_k(const unsigned short* __restrict__ qr,
                                                const unsigned short* __restrict__ Kf,
                                                const unsigned short* __restrict__ Vt,
                                                unsigned short* __restrict__ attb) {
  const int b = blockIdx.x, rg = blockIdx.y, h = blockIdx.z;
  const int bh = b * NH_ + h;
  const int tid = threadIdx.x, w = tid >> 6, l = tid & 63;
  const int lr = l & 15, kg = l >> 4;
  const int t0 = w * 128;

  __shared__ __align__(16) unsigned short Pl[8][16][136];
  __shared__ float mlS[8][16][2];

  const unsigned short* qbase = qr + ((size_t)bh * 64 + rg * 16 + lr) * HD_;
  s16x8 afr[8];
#pragma unroll
  for (int js = 0; js < 8; js++) afr[js] = *(const s16x8*)(qbase + js * 32 + 8 * kg);
  f32x4 sc[8];
#pragma unroll
  for (int nf = 0; nf < 8; nf++) sc[nf] = (f32x4){0.f, 0.f, 0.f, 0.f};
  const unsigned short* kb = Kf + ((size_t)b * TPAD_ + t0) * HD_;
#pragma unroll
  for (int js = 0; js < 8; js++)
#pragma unroll
    for (int nf = 0; nf < 8; nf++) {
      s16x8 bv = *(const s16x8*)(kb + (size_t)(nf * 16 + lr) * HD_ + js * 32 + 8 * kg);
      sc[nf] = __builtin_amdgcn_mfma_f32_16x16x32_bf16(afr[js], bv, sc[nf], 0, 0, 0);
    }
  float mx[4] = {-3.0e38f, -3.0e38f, -3.0e38f, -3.0e38f};
#pragma unroll
  for (int nf = 0; nf < 8; nf++) {
    int t = t0 + nf * 16 + lr;
#pragma unroll
    for (int r = 0; r < 4; r++) {
      int srw = rg * 16 + 4 * kg + r;
      float v = sc[nf][r] * 0.0625f;
      if (t >= PRE_ && (t - PRE_) > srw) v = -1e9f;
      sc[nf][r] = v;
      mx[r] = fmaxf(mx[r], v);
    }
  }
#pragma unroll
  for (int o = 8; o > 0; o >>= 1)
#pragma unroll
    for (int r = 0; r < 4; r++) mx[r] = fmaxf(mx[r], __shfl_xor(mx[r], o));
  float ls[4] = {0.f, 0.f, 0.f, 0.f};
#pragma unroll
  for (int nf = 0; nf < 8; nf++)
#pragma unroll
    for (int r = 0; r < 4; r++) {
      float p = expf(sc[nf][r] - mx[r]);
      sc[nf][r] = p;
      ls[r] += p;
    }
#pragma unroll
  for (int o = 8; o > 0; o >>= 1)
#pragma unroll
    for (int r = 0; r < 4; r++) ls[r] += __shfl_xor(ls[r], o);
#pragma unroll
  for (int nf = 0; nf < 8; nf++)
#pragma unroll
    for (int r = 0; r < 4; r++) Pl[w][4 * kg + r][nf * 16 + lr] = f2bf(sc[nf][r]);
  if (lr == 0) {
#pragma unroll
    for (int r = 0; r < 4; r++) {
      mlS[w][4 * kg + r][0] = mx[r];
      mlS[w][4 * kg + r][1] = ls[r];
    }
  }
  __syncthreads();
  f32x4 o4[8][2];
#pragma unroll
  for (int a = 0; a < 8; a++)
#pragma unroll
    for (int c = 0; c < 2; c++) o4[a][c] = (f32x4){0.f, 0.f, 0.f, 0.f};
#pragma unroll
  for (int wz = 0; wz < 8; wz++)
#pragma unroll
    for (int ti = 0; ti < 128; ti += 32) {
      s16x8 a = *(const s16x8*)&Pl[wz][lr][ti + 8 * kg];
#pragma unroll
      for (int nf = 0; nf < 2; nf++) {
        s16x8 bv = *(const s16x8*)(Vt + ((size_t)(b * HD_ + w * 32 + nf * 16 + lr)) * TPAD_ +
                                   wz * 128 + ti + 8 * kg);
        o4[wz][nf] = __builtin_amdgcn_mfma_f32_16x16x32_bf16(a, bv, o4[wz][nf], 0, 0, 0);
      }
    }
#pragma unroll
  for (int r = 0; r < 4; r++) {
    int row = 4 * kg + r;
    int s = rg * 16 + row;
    if (s >= HOR_) continue;
    float M = -3.0e38f;
#pragma unroll
    for (int wz = 0; wz < 8; wz++) M = fmaxf(M, mlS[wz][row][0]);
    float w8[8], Lden = 0.f;
#pragma unroll
    for (int wz = 0; wz < 8; wz++) {
      w8[wz] = expf(mlS[wz][row][0] - M);
      Lden += w8[wz] * mlS[wz][row][1];
    }
    float invL = 1.f / Lden;
#pragma unroll
    for (int nf = 0; nf < 2; nf++) {
      float o = 0.f;
#pragma unroll
      for (int wz = 0; wz < 8; wz++) o += w8[wz] * o4[wz][nf][r];
      attb[((size_t)(b * HOR_ + s)) * 2048 + h * HD_ + w * 32 + nf * 16 + lr] = f2bf(o * invL);
    }
  }
}

// ================================================================ split-K MFMA GEMM stage 1 (2-deep A+W, top-issued)
// MODE 1=WO, 3=DOWN. KSZT compile-time. XCD-contiguous strip remap (validated r16).
template <int MODE, int NS, int MS, int KSZT>
__global__ __launch_bounds__(512) void gemmS_k(const unsigned short* __restrict__ A,
                                               const float* __restrict__ W0,
                                               float* __restrict__ part) {
  constexpr int NF = 2;
  constexpr int RPW = 64 / MS;
  constexpr int MFC = RPW / 16;
  constexpr int KC = KSZT / NS;
  constexpr int NITER = KC / KSTEP_;
  const int tid = threadIdx.x;
  const int wv = tid >> 6, l = tid & 63;
  const int lr = l & 15, lk = (l >> 4) << 2;
  const int stRaw = blockIdx.x;
  const int n0 = ((stRaw & 7) * 4 + (stRaw >> 3)) * 32;
  const int kz = blockIdx.y;
  const int kbase = kz * KC;
  const int m0 = (int)blockIdx.z * (512 / MS) + wv * RPW;

  __shared__ unsigned short Wt[2][32][LST_];
  const int pr = tid >> 3;
  const int c0 = (tid & 7) * 4;

  f32x4 acc[MFC][NF];
#pragma unroll
  for (int a = 0; a < MFC; a++)
#pragma unroll
    for (int b = 0; b < NF; b++) acc[a][b] = (f32x4){0.f, 0.f, 0.f, 0.f};

  f32x4 pa0[2], pa1[2];
  auto LOADW = [&](int IT) {
    int sl = IT & 1;
    size_t kk = (size_t)(kbase + IT * KSTEP_ + 2 * pr);
    pa0[sl] = *(const f32x4*)(W0 + kk * 1024 + n0 + c0);
    pa1[sl] = *(const f32x4*)(W0 + (kk + 1) * 1024 + n0 + c0);
  };
  auto STOREW = [&](int IT) {
    int sl = IT & 1;
#pragma unroll
    for (int j = 0; j < 4; j++) {
      unsigned v = (unsigned)f2bf(pa0[sl][j]) | ((unsigned)f2bf(pa1[sl][j]) << 16);
      *(unsigned*)&Wt[sl][c0 + j][2 * pr] = v;
    }
  };

  s16x8 aP[2][MFC][4];
  auto LOADA = [&](int IT) {
    int sl = IT & 1;
    const int kb = kbase + IT * KSTEP_;
#pragma unroll
    for (int s = 0; s < 4; s++)
#pragma unroll
      for (int mf = 0; mf < MFC; mf++)
        aP[sl][mf][s] = *(const s16x8*)(A + (size_t)(m0 + mf * 16 + lr) * KSZT + kb + s * 32 + 2 * lk);
  };

  LOADW(0);
  if (NITER > 1) LOADW(1);
  LOADA(0);
  STOREW(0);
  __syncthreads();

#pragma unroll
  for (int it = 0; it < NITER; ++it) {
    if (it + 2 < NITER) LOADW(it + 2);
    if (it + 1 < NITER) LOADA(it + 1);   // top-issued: full phase of slack before barrier drain
#pragma unroll
    for (int s = 0; s < 4; s++) {
      s16x8 bfr[NF];
#pragma unroll
      for (int nf = 0; nf < NF; nf++) {
        const unsigned short* wp = &Wt[it & 1][nf * 16 + lr][s * 32 + 2 * lk];
        s16x4 b0 = *(const s16x4*)wp;
        s16x4 b1 = *(const s16x4*)(wp + 4);
#pragma unroll
        for (int j = 0; j < 4; j++) { bfr[nf][j] = b0[j]; bfr[nf][4 + j] = b1[j]; }
      }
#pragma unroll
      for (int mf = 0; mf < MFC; mf++)
#pragma unroll
        for (int nf = 0; nf < NF; nf++)
          acc[mf][nf] = __builtin_amdgcn_mfma_f32_16x16x32_bf16(aP[it & 1][mf][s], bfr[nf], acc[mf][nf], 0, 0, 0);
    }
    if (it + 1 < NITER) STOREW(it + 1);
    __syncthreads();
  }

#pragma unroll
  for (int mf = 0; mf < MFC; mf++)
#pragma unroll
    for (int nf = 0; nf < NF; nf++)
#pragma unroll
      for (int r = 0; r < 4; r++) {
        int row = m0 + mf * 16 + lk + r;
        if (row >= MROWS_) continue;
        int col = n0 + nf * 16 + lr;
        part[((size_t)kz * MPAD_ + row) * 1024 + col] = acc[mf][nf][r];
      }
}

// ---------------------------------------------------------------- split-K reduce + residual-gate + AdaRMSNorm
template <int NS>
__global__ __launch_bounds__(256) void redA_k(const float* __restrict__ part, const float* __restrict__ prev,
                                              const float* __restrict__ gatev, const float* __restrict__ nw,
                                              const float* __restrict__ sc, float* __restrict__ outH,
                                              unsigned short* __restrict__ outN) {
  int r = blockIdx.x, tid = threadIdx.x;
  int c = tid * 4;
  int b = r / HOR_;
  f32x4 v = (f32x4){0.f, 0.f, 0.f, 0.f};
#pragma unroll
  for (int z = 0; z < NS; z++) v += *(const f32x4*)(part + ((size_t)z * MPAD_ + r) * H_ + c);
  f32x4 pv = *(const f32x4*)(prev + (size_t)r * H_ + c);
  f32x4 gv = *(const f32x4*)(gatev + (size_t)b * H_ + c);
  f32x4 h = pv + gv * v;
  *(f32x4*)(outH + (size_t)r * H_ + c) = h;
  float ss = h[0] * h[0] + h[1] * h[1] + h[2] * h[2] + h[3] * h[3];
  __shared__ float r4[4];
  float wsv = wave_sum(ss);
  if ((tid & 63) == 0) r4[tid >> 6] = wsv;
  __syncthreads();
  float rs = rsqrtf((r4[0] + r4[1] + r4[2] + r4[3]) * (1.f / 1024.f) + 1e-6f);
#pragma unroll
  for (int j = 0; j < 4; j++) {
    int n = c + j;
    outN[(size_t)r * H_ + n] = f2bf(h[j] * rs * (1.f + nw[n]) * (1.f + sc[(size_t)b * H_ + n]));
  }
}

// ================================================================ upgate dual GEMM (2-deep A, top-issued)
// grid (128 strips of 32, 2 m-halves), 512 thr, full-K NITER=8, fully unrolled.
__global__ __launch_bounds__(512) void upg_k(const unsigned short* __restrict__ A, const float* __restrict__ Wg,
                                             const float* __restrict__ Wu, unsigned short* __restrict__ tb) {
  const int stRaw = blockIdx.x;
  const int st = (stRaw & 7) * 16 + (stRaw >> 3);   // XCD-contiguous (validated r16)
  const int mh = blockIdx.y;
  const int n0 = st * 32;
  const int tid = threadIdx.x, wv = tid >> 6, l = tid & 63;
  const int lr = l & 15, kg = l >> 4, lk = kg << 2;
  const int m0 = mh * 256 + wv * 32;

  __shared__ unsigned short Wt[2][64][LST_];
  const int pr = tid >> 3, c0 = (tid & 7) * 4;

  f32x4 acc[2][4];
#pragma unroll
  for (int a = 0; a < 2; a++)
#pragma unroll
    for (int b = 0; b < 4; b++) acc[a][b] = (f32x4){0.f, 0.f, 0.f, 0.f};

  f32x4 pa0, pa1, pb0, pb1;
  auto LOADW = [&](int IT) {
    size_t kk = (size_t)IT * KSTEP_ + 2 * pr;
    pa0 = *(const f32x4*)(Wg + kk * 4096 + n0 + c0);
    pa1 = *(const f32x4*)(Wg + (kk + 1) * 4096 + n0 + c0);
    pb0 = *(const f32x4*)(Wu + kk * 4096 + n0 + c0);
    pb1 = *(const f32x4*)(Wu + (kk + 1) * 4096 + n0 + c0);
  };
  auto STOREW = [&](int BUF) {
#pragma unroll
    for (int j = 0; j < 4; j++) {
      unsigned v = (unsigned)f2bf(pa0[j]) | ((unsigned)f2bf(pa1[j]) << 16);
      *(unsigned*)&Wt[BUF][c0 + j][2 * pr] = v;
      unsigned u = (unsigned)f2bf(pb0[j]) | ((unsigned)f2bf(pb1[j]) << 16);
      *(unsigned*)&Wt[BUF][32 + c0 + j][2 * pr] = u;
    }
  };

  s16x8 aP[2][2][4];
  auto LOADA = [&](int IT) {
    int sl = IT & 1;
    const int kb = IT * KSTEP_;
#pragma unroll
    for (int s = 0; s < 4; s++)
#pragma unroll
      for (int mf = 0; mf < 2; mf++)
        aP[sl][mf][s] = *(const s16x8*)(A + (size_t)(m0 + mf * 16 + lr) * H_ + kb + s * 32 + 8 * kg);
  };

  LOADW(0);
  LOADA(0);
  STOREW(0);
  __syncthreads();

#pragma unroll
  for (int it = 0; it < 8; ++it) {
    if (it + 1 < 8) {
      LOADW(it + 1);
      LOADA(it + 1);   // top-issued into opposite slot
    }
#pragma unroll
    for (int s = 0; s < 4; s++) {
      s16x8 bfr[4];
#pragma unroll
      for (int nf = 0; nf < 4; nf++) {
        const unsigned short* wp = &Wt[it & 1][nf * 16 + lr][s * 32 + 2 * lk];
        s16x4 b0 = *(const s16x4*)wp;
        s16x4 b1 = *(const s16x4*)(wp + 4);
#pragma unroll
        for (int j = 0; j < 4; j++) { bfr[nf][j] = b0[j]; bfr[nf][4 + j] = b1[j]; }
      }
#pragma unroll
      for (int mf = 0; mf < 2; mf++)
#pragma unroll
        for (int nf = 0; nf < 4; nf++)
          acc[mf][nf] = __builtin_amdgcn_mfma_f32_16x16x32_bf16(aP[it & 1][mf][s], bfr[nf], acc[mf][nf], 0, 0, 0);
    }
    if (it + 1 < 8) STOREW((it + 1) & 1);
    __syncthreads();
  }

#pragma unroll
  for (int mf = 0; mf < 2; mf++)
#pragma unroll
    for (int nf = 0; nf < 2; nf++)
#pragma unroll
      for (int r = 0; r < 4; r++) {
        int row = m0 + mf * 16 + lk + r;
        if (row >= MROWS_) continue;
        int col = n0 + nf * 16 + lr;
        float g = acc[mf][nf][r];
        float u = acc[mf][nf + 2][r];
        g = 0.5f * g * (1.f + tanhf(0.7978845608028654f * (g + 0.044715f * g * g * g)));
        tb[(size_t)row * 4096 + col] = f2bf(g * u);
      }
}

// ---------------------------------------------------------------- out = normedF @ action_out_w + b
__global__ __launch_bounds__(256) void fout_k(const unsigned short* __restrict__ nf, const float* __restrict__ Wo,
                                              const float* __restrict__ bo, float* __restrict__ out) {
  int m = blockIdx.x, tid = threadIdx.x;
  int n = tid & 31, kg = tid >> 5;
  float acc = 0.f;
  for (int k = kg * 128; k < kg * 128 + 128; k++)
    acc += bf2f(nf[(size_t)m * H_ + k]) * Wo[(size_t)k * AD_ + n];
  __shared__ float red[8][32];
  red[kg][n] = acc;
  __syncthreads();
  if (kg == 0) {
    float v = 0.f;
#pragma unroll
    for (int g = 0; g < 8; g++) v += red[g][n];
    out[(size_t)m * AD_ + n] = v + bo[n];
  }
}

// ================================================================ host
extern "C" void kernel_launch(void* const* d_in, const int* in_sizes, int n_in,
                              void* d_out, int out_size, void* d_ws, size_t ws_size,
                              hipStream_t stream) {
  const float* prefix_keys   = (const float*)d_in[0];
  const float* prefix_values = (const float*)d_in[1];
  const float* x_t           = (const float*)d_in[2];
  const float* timestep      = (const float*)d_in[3];
  const unsigned char* pad_mask = (const unsigned char*)d_in[4];
  const float* action_in_w   = (const float*)d_in[5];
  const float* action_in_b   = (const float*)d_in[6];
  const float* action_out_w  = (const float*)d_in[7];
  const float* action_out_b  = (const float*)d_in[8];
  const float* tmlp_in_w     = (const float*)d_in[9];
  const float* tmlp_in_b     = (const float*)d_in[10];
  const float* tmlp_out_w    = (const float*)d_in[11];
  const float* tmlp_out_b    = (const float*)d_in[12];
  const float* w_q    = (const float*)d_in[13];
  const float* w_k    = (const float*)d_in[14];
  const float* w_v    = (const float*)d_in[15];
  const float* w_o    = (const float*)d_in[16];
  const float* w_gate = (const float*)d_in[17];
  const float* w_up   = (const float*)d_in[18];
  const float* w_down = (const float*)d_in[19];
  const float* in_norm_w    = (const float*)d_in[20];
  const float* in_scale_w   = (const float*)d_in[21];
  const float* in_gate_w    = (const float*)d_in[22];
  const float* post_norm_w  = (const float*)d_in[23];
  const float* post_scale_w = (const float*)d_in[24];
  const float* post_gate_w  = (const float*)d_in[25];
  const float* fnorm_w       = (const float*)d_in[26];
  const float* fnorm_scale_w = (const float*)d_in[27];

  char* wsp = (char*)d_ws;
  auto alloc = [&](size_t bytes) { void* p = (void*)wsp; wsp += (bytes + 255) & ~(size_t)255; return p; };

  float* emb0   = (float*)alloc((size_t)8 * H_ * 4);
  float* emb1   = (float*)alloc((size_t)8 * H_ * 4);
  float* cond   = (float*)alloc((size_t)8 * H_ * 4);
  float* fscale = (float*)alloc((size_t)8 * H_ * 4);
  float* gates  = (float*)alloc((size_t)4 * L_ * 8 * H_ * 4);
  int*   offs   = (int*)alloc(64);
  float* hbuf   = (float*)alloc((size_t)MPAD_ * H_ * 4);
  float* h1buf  = (float*)alloc((size_t)MPAD_ * H_ * 4);
  unsigned short* normed  = (unsigned short*)alloc((size_t)MPAD_ * H_ * 2);
  unsigned short* normed2 = (unsigned short*)alloc((size_t)MPAD_ * H_ * 2);
  unsigned short* q_r     = (unsigned short*)alloc((size_t)B_ * NH_ * 64 * HD_ * 2);
  unsigned short* Kf_all  = (unsigned short*)alloc((size_t)L_ * B_ * TPAD_ * HD_ * 2);
  unsigned short* Vt_all  = (unsigned short*)alloc((size_t)L_ * B_ * HD_ * TPAD_ * 2);
  unsigned short* attb    = (unsigned short*)alloc((size_t)MPAD_ * 2048 * 2);
  unsigned short* t_buf   = (unsigned short*)alloc((size_t)MPAD_ * FF_ * 2);
  float* wopart = (float*)alloc((size_t)4 * MPAD_ * 1024 * 4);
  float* dpart  = (float*)alloc((size_t)4 * MPAD_ * 1024 * 4);

  // attb pad rows never written by flash8: zero once (stays zero all layers)
  hipMemsetAsync(attb + (size_t)MROWS_ * 2048, 0, (size_t)(MPAD_ - MROWS_) * 2048 * 2, stream);
  // normed2 pad rows never written (redA grid = 400): zero once so upg A-reads stay finite
  hipMemsetAsync(normed2 + (size_t)MROWS_ * H_, 0, (size_t)(MPAD_ - MROWS_) * H_ * 2, stream);
  // t_buf pad rows never written by upg: zero once
  hipMemsetAsync(t_buf + (size_t)MROWS_ * FF_, 0, (size_t)(MPAD_ - MROWS_) * FF_ * 2, stream);

  emb_k<<<8, 256, 0, stream>>>(timestep, emb0);
  gemm8_k<<<16, 256, 0, stream>>>(emb0, tmlp_in_w, tmlp_in_b, emb1, 1);
  gemm8_k<<<16, 256, 0, stream>>>(emb1, tmlp_out_w, tmlp_out_b, cond, 1);
  gemm8_k<<<16, 256, 0, stream>>>(cond, fnorm_scale_w, nullptr, fscale, 0);
  gates_k<<<dim3(16, L_, 4), 256, 0, stream>>>(cond, in_scale_w, in_gate_w, post_scale_w, post_gate_w, gates);
  offs_k<<<1, 256, 0, stream>>>(pad_mask, offs);
  action_in_k<<<(MPAD_ * H_) / 256, 256, 0, stream>>>(x_t, action_in_w, action_in_b, hbuf);
  prefixAll_k<<<dim3(16, B_, L_), 256, 0, stream>>>(prefix_keys, prefix_values, Kf_all, Vt_all);
  ada_k<<<MPAD_, 256, 0, stream>>>(hbuf, in_norm_w, gates, normed);  // layer-0 in_scale = gates z=0,l=0

  for (int i = 0; i < L_; i++) {
    const float* wq_i = w_q + (size_t)i * H_ * 2048;
    const float* wk_i = w_k + (size_t)i * H_ * HD_;
    const float* wv_i = w_v + (size_t)i * H_ * HD_;
    const float* wo_i = w_o + (size_t)i * 2048 * H_;
    const float* wg_i = w_gate + (size_t)i * H_ * FF_;
    const float* wu_i = w_up + (size_t)i * H_ * FF_;
    const float* wd_i = w_down + (size_t)i * FF_ * H_;
    const float* g_in_gate    = gates + ((size_t)(1 * L_ + i) * 8) * H_;
    const float* g_post_scale = gates + ((size_t)(2 * L_ + i) * 8) * H_;
    const float* g_post_gate  = gates + ((size_t)(3 * L_ + i) * 8) * H_;
    unsigned short* Kf_l = Kf_all + (size_t)i * B_ * TPAD_ * HD_;
    unsigned short* Vt_l = Vt_all + (size_t)i * B_ * HD_ * TPAD_;

    qkvF_k<<<dim3(80, 2), 512, 0, stream>>>(normed, wq_i, wk_i, wv_i, offs, q_r, Kf_l, Vt_l);
    flash8_k<<<dim3(B_, 4, NH_), 512, 0, stream>>>(q_r, Kf_l, Vt_l, attb);
    gemmS_k<1, 4, 2, 2048><<<dim3(32, 4, 2), 512, 0, stream>>>(attb, wo_i, wopart);
    redA_k<4><<<MROWS_, 256, 0, stream>>>(wopart, hbuf, g_in_gate, post_norm_w + (size_t)i * H_,
                                          g_post_scale, h1buf, normed2);
    upg_k<<<dim3(128, 2), 512, 0, stream>>>(normed2, wg_i, wu_i, t_buf);
    gemmS_k<3, 4, 2, 4096><<<dim3(32, 4, 2), 512, 0, stream>>>(t_buf, wd_i, dpart);
    const float* nw_next = (i + 1 < L_) ? in_norm_w + (size_t)(i + 1) * H_ : fnorm_w;
    const float* sc_next = (i + 1 < L_) ? gates + ((size_t)(i + 1) * 8) * H_ : fscale;
    redA_k<4><<<MROWS_, 256, 0, stream>>>(dpart, h1buf, g_post_gate, nw_next, sc_next, hbuf, normed);
  }

  fout_k<<<MROWS_, 256, 0, stream>>>(normed, action_out_w, action_out_b, (float*)d_out);
}

// Round 18
// 2594.919 us; speedup vs baseline: 2.0520x; 1.0148x over previous
//
#include <hip/hip_runtime.h>

#define L_ 18
#define H_ 1024
#define NH_ 8
#define HD_ 256
#define FF_ 4096
#define HOR_ 50
#define PRE_ 968
#define B_ 8
#define AD_ 32
#define TPAD_ 1024
#define MROWS_ 400
#define MPAD_ 512
#define KSTEP_ 128
#define LST_ 132

typedef float f32x4 __attribute__((ext_vector_type(4)));
typedef short s16x4 __attribute__((ext_vector_type(4)));
typedef short s16x8 __attribute__((ext_vector_type(8)));
typedef unsigned short u16x8 __attribute__((ext_vector_type(8)));

__device__ __forceinline__ unsigned short f2bf(float f) {
  unsigned u = __float_as_uint(f);
  u += 0x7FFFu + ((u >> 16) & 1u);
  return (unsigned short)(u >> 16);
}
__device__ __forceinline__ float bf2f(unsigned short h) {
  return __uint_as_float(((unsigned)h) << 16);
}
__device__ __forceinline__ float wave_sum(float v) {
#pragma unroll
  for (int o = 32; o > 0; o >>= 1) v += __shfl_xor(v, o);
  return v;
}

// LDS-only barrier: drains DS ops (cross-wave Wt handoff) but leaves global loads in flight
// (register destinations, per-wave — no cross-wave hazard). Avoids __syncthreads()'s vmcnt(0) drain.
__device__ __forceinline__ void lds_barrier() {
  asm volatile("s_waitcnt lgkmcnt(0)" ::: "memory");
  __builtin_amdgcn_s_barrier();
  __builtin_amdgcn_sched_barrier(0);
}

// ---------------------------------------------------------------- time embedding
__global__ __launch_bounds__(256) void emb_k(const float* __restrict__ ts, float* __restrict__ emb) {
  int b = blockIdx.x, tid = threadIdx.x;
  float t = ts[b];
  for (int j = tid; j < 512; j += 256) {
    float ang = 1570.7963267948966f * expf((float)j * (-6.907755278982137f / 511.0f)) * t;
    emb[(size_t)b * H_ + j] = sinf(ang);
    emb[(size_t)b * H_ + 512 + j] = cosf(ang);
  }
}

// ---------------------------------------------------------------- [8,1024]@[1024,1024] (+bias,+silu)
__global__ __launch_bounds__(256) void gemm8_k(const float* __restrict__ A8, const float* __restrict__ W,
                                               const float* __restrict__ bias, float* __restrict__ out,
                                               int act) {
  __shared__ float a_s[8 * 1024];
  __shared__ float red[4][8][64];
  int tid = threadIdx.x;
  for (int i = tid; i < 8 * 1024; i += 256) a_s[i] = A8[i];
  __syncthreads();
  int nl = tid & 63, kg = tid >> 6;
  int n = blockIdx.x * 64 + nl;
  float acc[8];
#pragma unroll
  for (int m = 0; m < 8; m++) acc[m] = 0.f;
  for (int k = kg * 256; k < kg * 256 + 256; k++) {
    float wv = W[(size_t)k * 1024 + n];
#pragma unroll
    for (int m = 0; m < 8; m++) acc[m] += a_s[m * 1024 + k] * wv;
  }
#pragma unroll
  for (int m = 0; m < 8; m++) red[kg][m][nl] = acc[m];
  __syncthreads();
  if (kg == 0) {
#pragma unroll
    for (int m = 0; m < 8; m++) {
      float v = red[0][m][nl] + red[1][m][nl] + red[2][m][nl] + red[3][m][nl];
      if (bias) v += bias[n];
      if (act) v = v / (1.f + expf(-v));
      out[(size_t)m * 1024 + n] = v;
    }
  }
}

// ---------------------------------------------------------------- all 72 adaLN cond GEMMs in one grid
__global__ __launch_bounds__(256) void gates_k(const float* __restrict__ cond,
                                               const float* __restrict__ w0, const float* __restrict__ w1,
                                               const float* __restrict__ w2, const float* __restrict__ w3,
                                               float* __restrict__ gates) {
  __shared__ float a_s[8 * 1024];
  __shared__ float red[4][8][64];
  int tid = threadIdx.x;
  for (int i = tid; i < 8 * 1024; i += 256) a_s[i] = cond[i];
  __syncthreads();
  int z = blockIdx.z, layer = blockIdx.y;
  const float* W = (z == 0 ? w0 : z == 1 ? w1 : z == 2 ? w2 : w3) + (size_t)layer * H_ * H_;
  float* out = gates + ((size_t)(z * L_ + layer) * 8) * H_;
  int nl = tid & 63, kg = tid >> 6;
  int n = blockIdx.x * 64 + nl;
  float acc[8];
#pragma unroll
  for (int m = 0; m < 8; m++) acc[m] = 0.f;
  for (int k = kg * 256; k < kg * 256 + 256; k++) {
    float wv = W[(size_t)k * 1024 + n];
#pragma unroll
    for (int m = 0; m < 8; m++) acc[m] += a_s[m * 1024 + k] * wv;
  }
#pragma unroll
  for (int m = 0; m < 8; m++) red[kg][m][nl] = acc[m];
  __syncthreads();
  if (kg == 0) {
#pragma unroll
    for (int m = 0; m < 8; m++)
      out[(size_t)m * 1024 + n] = red[0][m][nl] + red[1][m][nl] + red[2][m][nl] + red[3][m][nl];
  }
}

// ---------------------------------------------------------------- pad-mask -> per-batch valid counts
__global__ void offs_k(const unsigned char* __restrict__ mask, int* __restrict__ offs) {
  __shared__ int cnt[8];
  __shared__ int mod4;
  int tid = threadIdx.x;
  if (tid < 8) cnt[tid] = 0;
  if (tid == 8) mod4 = 0;
  __syncthreads();
  for (int i = tid; i < B_ * PRE_; i += 256) {
    unsigned char v = mask[i];
    if (v) {
      atomicAdd(&cnt[i / PRE_], 1);
      if (i & 3) atomicAdd(&mod4, 1);
    }
  }
  __syncthreads();
  if (tid < 8) offs[tid] = (mod4 == 0) ? cnt[tid] * 4 : cnt[tid];
}

// ---------------------------------------------------------------- h = x_t @ action_in_w + b  (pad rows = 0)
__global__ __launch_bounds__(256) void action_in_k(const float* __restrict__ xt, const float* __restrict__ Wi,
                                                   const float* __restrict__ bi, float* __restrict__ h) {
  int idx = blockIdx.x * 256 + threadIdx.x;
  int m = idx >> 10, n = idx & 1023;
  float v = 0.f;
  if (m < MROWS_) {
    const float* xr = xt + (size_t)m * AD_;
#pragma unroll
    for (int k = 0; k < AD_; k++) v += xr[k] * Wi[(size_t)k * H_ + n];
    v += bi[n];
  }
  h[idx] = v;
}

// ---------------------------------------------------------------- AdaRMSNorm -> bf16 (pad rows = 0), layer-0 only
__global__ __launch_bounds__(256) void ada_k(const float* __restrict__ X, const float* __restrict__ nw,
                                             const float* __restrict__ sc, unsigned short* __restrict__ Y) {
  int m = blockIdx.x, tid = threadIdx.x;
  size_t base = (size_t)m * H_;
  if (m >= MROWS_) {
#pragma unroll
    for (int j = 0; j < 4; j++) Y[base + tid * 4 + j] = 0;
    return;
  }
  f32x4 x = *(const f32x4*)(X + base + tid * 4);
  float ss = x[0] * x[0] + x[1] * x[1] + x[2] * x[2] + x[3] * x[3];
  __shared__ float r4[4];
  float wsv = wave_sum(ss);
  if ((tid & 63) == 0) r4[tid >> 6] = wsv;
  __syncthreads();
  float rs = rsqrtf((r4[0] + r4[1] + r4[2] + r4[3]) * (1.f / 1024.f) + 1e-6f);
  int b = m / HOR_;
#pragma unroll
  for (int j = 0; j < 4; j++) {
    int n = tid * 4 + j;
    Y[base + n] = f2bf(x[j] * rs * (1.f + nw[n]) * (1.f + sc[(size_t)b * H_ + n]));
  }
}

// ---------------------------------------------------------------- all-layer prefix convert: K row-major, V transposed
__global__ __launch_bounds__(256) void prefixAll_k(const float* __restrict__ pk, const float* __restrict__ pv,
                                                   unsigned short* __restrict__ Kf_all,
                                                   unsigned short* __restrict__ Vt_all) {
  int b = blockIdx.y, t0 = blockIdx.x * 64, layer = blockIdx.z, tid = threadIdx.x;
  unsigned short* Kf = Kf_all + (size_t)layer * B_ * TPAD_ * HD_;
  unsigned short* Vt = Vt_all + (size_t)layer * B_ * HD_ * TPAD_;
  __shared__ unsigned short vt[256][72];
  const float* kp = pk + ((size_t)(b * L_ + layer)) * PRE_ * HD_;
  const float* vp = pv + ((size_t)(b * L_ + layer)) * PRE_ * HD_;
  for (int i = 0; i < 64; i++) {
    int t = t0 + i;
    float kv = 0.f, vv = 0.f;
    if (t < PRE_) {
      kv = kp[(size_t)t * HD_ + tid];
      vv = vp[(size_t)t * HD_ + tid];
    }
    Kf[((size_t)b * TPAD_ + t) * HD_ + tid] = f2bf(kv);  // suffix rows rewritten per layer by qkvF
    vt[tid][i] = f2bf(vv);
  }
  __syncthreads();
#pragma unroll
  for (int p = 0; p < 4; p++) {
    int d = p * 64 + (tid >> 2);
    int c0 = (tid & 3) * 16;
    u16x8 v0, v1;
#pragma unroll
    for (int j = 0; j < 8; j++) { v0[j] = vt[d][c0 + j]; v1[j] = vt[d][c0 + 8 + j]; }
    size_t dst = ((size_t)(b * HD_ + d)) * TPAD_ + t0 + c0;
    *(u16x8*)(Vt + dst) = v0;
    *(u16x8*)(Vt + dst + 8) = v1;
  }
}

// ================================================================ QKV GEMM (counted-wait barrier) + RoPE/scatter
// grid (80 strips, 2 m-halves), 512 thr. Full unroll => register slot indices compile-time.
__global__ __launch_bounds__(512) void qkvF_k(const unsigned short* __restrict__ A,
                                              const float* __restrict__ Wq, const float* __restrict__ Wk,
                                              const float* __restrict__ Wv, const int* __restrict__ offs,
                                              unsigned short* __restrict__ q_r, unsigned short* __restrict__ Kf,
                                              unsigned short* __restrict__ Vt) {
  const int stRaw = blockIdx.x;
  const int st = (stRaw & 7) * 10 + (stRaw >> 3);   // XCD-contiguous strips (validated r16)
  const int mh = blockIdx.y;
  const int tid = threadIdx.x, wv = tid >> 6, l = tid & 63;
  const int lr = l & 15, kg = l >> 4, lk = kg << 2;
  const int m0 = mh * 256 + wv * 32;

  const float* W;
  int ldw, wbase;
  bool paired;
  if (st < 64)      { W = Wq; ldw = 2048; wbase = (st >> 3) * 256 + (st & 7) * 16; paired = true; }
  else if (st < 72) { W = Wk; ldw = 256;  wbase = (st - 64) * 16; paired = true; }
  else              { W = Wv; ldw = 256;  wbase = (st - 72) * 32; paired = false; }

  __shared__ unsigned short Wt[2][32][LST_];
  __shared__ int offsL[8];
  const int pr = tid >> 3, c0 = (tid & 7) * 4;
  const int wcol = wbase + c0 + ((paired && c0 >= 16) ? 112 : 0);

  if (tid < 8) offsL[tid] = offs[tid];

  f32x4 acc[2][2];
#pragma unroll
  for (int a = 0; a < 2; a++)
#pragma unroll
    for (int b = 0; b < 2; b++) acc[a][b] = (f32x4){0.f, 0.f, 0.f, 0.f};

  f32x4 pa0[2], pa1[2];
  auto LOADW = [&](int IT) {
    int sl = IT & 1;
    size_t kk = (size_t)IT * KSTEP_ + 2 * pr;
    pa0[sl] = *(const f32x4*)(W + kk * ldw + wcol);
    pa1[sl] = *(const f32x4*)(W + (kk + 1) * ldw + wcol);
  };
  auto STOREW = [&](int IT) {
    int sl = IT & 1;
#pragma unroll
    for (int j = 0; j < 4; j++) {
      unsigned v = (unsigned)f2bf(pa0[sl][j]) | ((unsigned)f2bf(pa1[sl][j]) << 16);
      *(unsigned*)&Wt[sl][c0 + j][2 * pr] = v;
    }
  };

  s16x8 aP[2][2][4];
  auto LOADA = [&](int IT) {
    int sl = IT & 1;
    const int kb = IT * KSTEP_;
#pragma unroll
    for (int s = 0; s < 4; s++)
#pragma unroll
      for (int mf = 0; mf < 2; mf++)
        aP[sl][mf][s] = *(const s16x8*)(A + (size_t)(m0 + mf * 16 + lr) * H_ + kb + s * 32 + 8 * kg);
  };

  LOADW(0);
  LOADW(1);
  LOADA(0);
  STOREW(0);
  lds_barrier();

#pragma unroll
  for (int it = 0; it < 8; ++it) {
    if (it + 2 < 8) LOADW(it + 2);
    if (it + 1 < 8) LOADA(it + 1);
#pragma unroll
    for (int s = 0; s < 4; s++) {
      s16x8 bfr[2];
#pragma unroll
      for (int nf = 0; nf < 2; nf++) {
        const unsigned short* wp = &Wt[it & 1][nf * 16 + lr][s * 32 + 2 * lk];
        s16x4 b0 = *(const s16x4*)wp;
        s16x4 b1 = *(const s16x4*)(wp + 4);
#pragma unroll
        for (int j = 0; j < 4; j++) { bfr[nf][j] = b0[j]; bfr[nf][4 + j] = b1[j]; }
      }
#pragma unroll
      for (int mf = 0; mf < 2; mf++)
#pragma unroll
        for (int nf = 0; nf < 2; nf++)
          acc[mf][nf] = __builtin_amdgcn_mfma_f32_16x16x32_bf16(aP[it & 1][mf][s], bfr[nf], acc[mf][nf], 0, 0, 0);
    }
    if (it + 1 < 8) STOREW(it + 1);
    lds_barrier();   // DS-only drain: prefetched global loads stay in flight across the barrier
  }

  const float RK = -9.210340371976184f / 128.0f;
  if (st < 64) {  // Q: rope pair, write q_r
    const int h = st >> 3, x = (st & 7) * 16, dd = x + lr;
    const float inv = expf((float)dd * RK);
#pragma unroll
    for (int mf = 0; mf < 2; mf++)
#pragma unroll
      for (int r = 0; r < 4; r++) {
        int m = m0 + mf * 16 + lk + r;
        if (m >= MROWS_) continue;
        int b = m / HOR_, s = m - b * HOR_;
        float ang = (float)(offsL[b] + s) * inv;
        float cc = cosf(ang), sn = sinf(ang);
        float v1 = acc[mf][0][r], v2 = acc[mf][1][r];
        size_t base = ((size_t)(b * NH_ + h) * 64 + s) * HD_;
        q_r[base + dd] = f2bf(v1 * cc - v2 * sn);
        q_r[base + dd + 128] = f2bf(v2 * cc + v1 * sn);
      }
  } else if (st < 72) {  // K: rope pair, write Kf suffix rows
    const int x = (st - 64) * 16, dd = x + lr;
    const float inv = expf((float)dd * RK);
#pragma unroll
    for (int mf = 0; mf < 2; mf++)
#pragma unroll
      for (int r = 0; r < 4; r++) {
        int m = m0 + mf * 16 + lk + r;
        if (m >= MROWS_) continue;
        int b = m / HOR_, s = m - b * HOR_;
        float ang = (float)(offsL[b] + s) * inv;
        float cc = cosf(ang), sn = sinf(ang);
        float v1 = acc[mf][0][r], v2 = acc[mf][1][r];
        size_t base = ((size_t)b * TPAD_ + PRE_ + s) * HD_;
        Kf[base + dd] = f2bf(v1 * cc - v2 * sn);
        Kf[base + dd + 128] = f2bf(v2 * cc + v1 * sn);
      }
  } else {  // V: write Vt columns
    const int x = (st - 72) * 32;
#pragma unroll
    for (int mf = 0; mf < 2; mf++)
#pragma unroll
      for (int nf = 0; nf < 2; nf++)
#pragma unroll
        for (int r = 0; r < 4; r++) {
          int m = m0 + mf * 16 + lk + r;
          if (m >= MROWS_) continue;
          int b = m / HOR_, s = m - b * HOR_;
          int d = x + nf * 16 + lr;
          Vt[((size_t)(b * HD_ + d)) * TPAD_ + PRE_ + s] = f2bf(acc[mf][nf][r]);
        }
  }
}

// ================================================================ 8-wave flash attention (validated round-12)
// grid (B, 4 rg, NH) [b = bid%8 -> per-batch KV pinned to one XCD's L2]. 512 thr = 8 waves.
__global__ __launch_bounds__(512) void flash8_k(const unsigned short* __restrict__ qr,
                                                const unsigned short* __restrict__ Kf,
                                                const unsigned short* __restrict__ Vt,
                                                unsigned short* __restrict__ attb) {
  const int b = blockIdx.x, rg = blockIdx.y, h = blockIdx.z;
  const int bh = b * NH_ + h;
  const int tid = threadIdx.x, w = tid >> 6, l = tid & 63;
  const int lr = l & 15, kg = l >> 4;
  const int t0 = w * 128;

  __shared__ __align__(16) unsigned short Pl[8][16][136];
  __shared__ float mlS[8][16][2];

  const unsigned short* qbase = qr + ((size_t)bh * 64 + rg * 16 + lr) * HD_;
  s16x8 afr[8];
#pragma unroll
  for (int js = 0; js < 8; js++) afr[js] = *(const s16x8*)(qbase + js * 32 + 8 * kg);
  f32x4 sc[8];
#pragma unroll
  for (int nf = 0; nf < 8; nf++) sc[nf] = (f32x4){0.f, 0.f, 0.f, 0.f};
  const unsigned short* kb = Kf + ((size_t)b * TPAD_ + t0) * HD_;
#pragma unroll
  for (int js = 0; js < 8; js++)
#pragma unroll
    for (int nf = 0; nf < 8; nf++) {
      s16x8 bv = *(const s16x8*)(kb + (size_t)(nf * 16 + lr) * HD_ + js * 32 + 8 * kg);
      sc[nf] = __builtin_amdgcn_mfma_f32_16x16x32_bf16(afr[js], bv, sc[nf], 0, 0, 0);
    }
  float mx[4] = {-3.0e38f, -3.0e38f, -3.0e38f, -3.0e38f};
#pragma unroll
  for (int nf = 0; nf < 8; nf++) {
    int t = t0 + nf * 16 + lr;
#pragma unroll
    for (int r = 0; r < 4; r++) {
      int srw = rg * 16 + 4 * kg + r;
      float v = sc[nf][r] * 0.0625f;
      if (t >= PRE_ && (t - PRE_) > srw) v = -1e9f;
      sc[nf][r] = v;
      mx[r] = fmaxf(mx[r], v);
    }
  }
#pragma unroll
  for (int o = 8; o > 0; o >>= 1)
#pragma unroll
    for (int r = 0; r < 4; r++) mx[r] = fmaxf(mx[r], __shfl_xor(mx[r], o));
  float ls[4] = {0.f, 0.f, 0.f, 0.f};
#pragma unroll
  for (int nf = 0; nf < 8; nf++)
#pragma unroll
    for (int r = 0; r < 4; r++) {
      float p = expf(sc[nf][r] - mx[r]);
      sc[nf][r] = p;
      ls[r] += p;
    }
#pragma unroll
  for (int o = 8; o > 0; o >>= 1)
#pragma unroll
    for (int r = 0; r < 4; r++) ls[r] += __shfl_xor(ls[r], o);
#pragma unroll
  for (int nf = 0; nf < 8; nf++)
#pragma unroll
    for (int r = 0; r < 4; r++) Pl[w][4 * kg + r][nf * 16 + lr] = f2bf(sc[nf][r]);
  if (lr == 0) {
#pragma unroll
    for (int r = 0; r < 4; r++) {
      mlS[w][4 * kg + r][0] = mx[r];
      mlS[w][4 * kg + r][1] = ls[r];
    }
  }
  __syncthreads();
  f32x4 o4[8][2];
#pragma unroll
  for (int a = 0; a < 8; a++)
#pragma unroll
    for (int c = 0; c < 2; c++) o4[a][c] = (f32x4){0.f, 0.f, 0.f, 0.f};
#pragma unroll
  for (int wz = 0; wz < 8; wz++)
#pragma unroll
    for (int ti = 0; ti < 128; ti += 32) {
      s16x8 a = *(const s16x8*)&Pl[wz][lr][ti + 8 * kg];
#pragma unroll
      for (int nf = 0; nf < 2; nf++) {
        s16x8 bv = *(const s16x8*)(Vt + ((size_t)(b * HD_ + w * 32 + nf * 16 + lr)) * TPAD_ +
                                   wz * 128 + ti + 8 * kg);
        o4[wz][nf] = __builtin_amdgcn_mfma_f32_16x16x32_bf16(a, bv, o4[wz][nf], 0, 0, 0);
      }
    }
#pragma unroll
  for (int r = 0; r < 4; r++) {
    int row = 4 * kg + r;
    int s = rg * 16 + row;
    if (s >= HOR_) continue;
    float M = -3.0e38f;
#pragma unroll
    for (int wz = 0; wz < 8; wz++) M = fmaxf(M, mlS[wz][row][0]);
    float w8[8], Lden = 0.f;
#pragma unroll
    for (int wz = 0; wz < 8; wz++) {
      w8[wz] = expf(mlS[wz][row][0] - M);
      Lden += w8[wz] * mlS[wz][row][1];
    }
    float invL = 1.f / Lden;
#pragma unroll
    for (int nf = 0; nf < 2; nf++) {
      float o = 0.f;
#pragma unroll
      for (int wz = 0; wz < 8; wz++) o += w8[wz] * o4[wz][nf][r];
      attb[((size_t)(b * HOR_ + s)) * 2048 + h * HD_ + w * 32 + nf * 16 + lr] = f2bf(o * invL);
    }
  }
}

// ================================================================ split-K MFMA GEMM stage 1 (counted-wait barrier)
// MODE 1=WO, 3=DOWN. KSZT compile-time. XCD-contiguous strip remap (validated r16).
template <int MODE, int NS, int MS, int KSZT>
__global__ __launch_bounds__(512) void gemmS_k(const unsigned short* __restrict__ A,
                                               const float* __restrict__ W0,
                                               float* __restrict__ part) {
  constexpr int NF = 2;
  constexpr int RPW = 64 / MS;
  constexpr int MFC = RPW / 16;
  constexpr int KC = KSZT / NS;
  constexpr int NITER = KC / KSTEP_;
  const int tid = threadIdx.x;
  const int wv = tid >> 6, l = tid & 63;
  const int lr = l & 15, lk = (l >> 4) << 2;
  const int stRaw = blockIdx.x;
  const int n0 = ((stRaw & 7) * 4 + (stRaw >> 3)) * 32;
  const int kz = blockIdx.y;
  const int kbase = kz * KC;
  const int m0 = (int)blockIdx.z * (512 / MS) + wv * RPW;

  __shared__ unsigned short Wt[2][32][LST_];
  const int pr = tid >> 3;
  const int c0 = (tid & 7) * 4;

  f32x4 acc[MFC][NF];
#pragma unroll
  for (int a = 0; a < MFC; a++)
#pragma unroll
    for (int b = 0; b < NF; b++) acc[a][b] = (f32x4){0.f, 0.f, 0.f, 0.f};

  f32x4 pa0[2], pa1[2];
  auto LOADW = [&](int IT) {
    int sl = IT & 1;
    size_t kk = (size_t)(kbase + IT * KSTEP_ + 2 * pr);
    pa0[sl] = *(const f32x4*)(W0 + kk * 1024 + n0 + c0);
    pa1[sl] = *(const f32x4*)(W0 + (kk + 1) * 1024 + n0 + c0);
  };
  auto STOREW = [&](int IT) {
    int sl = IT & 1;
#pragma unroll
    for (int j = 0; j < 4; j++) {
      unsigned v = (unsigned)f2bf(pa0[sl][j]) | ((unsigned)f2bf(pa1[sl][j]) << 16);
      *(unsigned*)&Wt[sl][c0 + j][2 * pr] = v;
    }
  };

  s16x8 aP[2][MFC][4];
  auto LOADA = [&](int IT) {
    int sl = IT & 1;
    const int kb = kbase + IT * KSTEP_;
#pragma unroll
    for (int s = 0; s < 4; s++)
#pragma unroll
      for (int mf = 0; mf < MFC; mf++)
        aP[sl][mf][s] = *(const s16x8*)(A + (size_t)(m0 + mf * 16 + lr) * KSZT + kb + s * 32 + 2 * lk);
  };

  LOADW(0);
  if (NITER > 1) LOADW(1);
  LOADA(0);
  STOREW(0);
  lds_barrier();

#pragma unroll
  for (int it = 0; it < NITER; ++it) {
    if (it + 2 < NITER) LOADW(it + 2);
    if (it + 1 < NITER) LOADA(it + 1);
#pragma unroll
    for (int s = 0; s < 4; s++) {
      s16x8 bfr[NF];
#pragma unroll
      for (int nf = 0; nf < NF; nf++) {
        const unsigned short* wp = &Wt[it & 1][nf * 16 + lr][s * 32 + 2 * lk];
        s16x4 b0 = *(const s16x4*)wp;
        s16x4 b1 = *(const s16x4*)(wp + 4);
#pragma unroll
        for (int j = 0; j < 4; j++) { bfr[nf][j] = b0[j]; bfr[nf][4 + j] = b1[j]; }
      }
#pragma unroll
      for (int mf = 0; mf < MFC; mf++)
#pragma unroll
        for (int nf = 0; nf < NF; nf++)
          acc[mf][nf] = __builtin_amdgcn_mfma_f32_16x16x32_bf16(aP[it & 1][mf][s], bfr[nf], acc[mf][nf], 0, 0, 0);
    }
    if (it + 1 < NITER) STOREW(it + 1);
    lds_barrier();   // DS-only drain: global prefetches survive across the barrier
  }

#pragma unroll
  for (int mf = 0; mf < MFC; mf++)
#pragma unroll
    for (int nf = 0; nf < NF; nf++)
#pragma unroll
      for (int r = 0; r < 4; r++) {
        int row = m0 + mf * 16 + lk + r;
        if (row >= MROWS_) continue;
        int col = n0 + nf * 16 + lr;
        part[((size_t)kz * MPAD_ + row) * 1024 + col] = acc[mf][nf][r];
      }
}

// ---------------------------------------------------------------- split-K reduce + residual-gate + AdaRMSNorm
template <int NS>
__global__ __launch_bounds__(256) void redA_k(const float* __restrict__ part, const float* __restrict__ prev,
                                              const float* __restrict__ gatev, const float* __restrict__ nw,
                                              const float* __restrict__ sc, float* __restrict__ outH,
                                              unsigned short* __restrict__ outN) {
  int r = blockIdx.x, tid = threadIdx.x;
  int c = tid * 4;
  int b = r / HOR_;
  f32x4 v = (f32x4){0.f, 0.f, 0.f, 0.f};
#pragma unroll
  for (int z = 0; z < NS; z++) v += *(const f32x4*)(part + ((size_t)z * MPAD_ + r) * H_ + c);
  f32x4 pv = *(const f32x4*)(prev + (size_t)r * H_ + c);
  f32x4 gv = *(const f32x4*)(gatev + (size_t)b * H_ + c);
  f32x4 h = pv + gv * v;
  *(f32x4*)(outH + (size_t)r * H_ + c) = h;
  float ss = h[0] * h[0] + h[1] * h[1] + h[2] * h[2] + h[3] * h[3];
  __shared__ float r4[4];
  float wsv = wave_sum(ss);
  if ((tid & 63) == 0) r4[tid >> 6] = wsv;
  __syncthreads();
  float rs = rsqrtf((r4[0] + r4[1] + r4[2] + r4[3]) * (1.f / 1024.f) + 1e-6f);
#pragma unroll
  for (int j = 0; j < 4; j++) {
    int n = c + j;
    outN[(size_t)r * H_ + n] = f2bf(h[j] * rs * (1.f + nw[n]) * (1.f + sc[(size_t)b * H_ + n]));
  }
}

// ================================================================ upgate dual GEMM (counted-wait barrier)
// grid (128 strips of 32, 2 m-halves), 512 thr, full-K NITER=8, fully unrolled.
__global__ __launch_bounds__(512) void upg_k(const unsigned short* __restrict__ A, const float* __restrict__ Wg,
                                             const float* __restrict__ Wu, unsigned short* __restrict__ tb) {
  const int stRaw = blockIdx.x;
  const int st = (stRaw & 7) * 16 + (stRaw >> 3);   // XCD-contiguous (validated r16)
  const int mh = blockIdx.y;
  const int n0 = st * 32;
  const int tid = threadIdx.x, wv = tid >> 6, l = tid & 63;
  const int lr = l & 15, kg = l >> 4, lk = kg << 2;
  const int m0 = mh * 256 + wv * 32;

  __shared__ unsigned short Wt[2][64][LST_];
  const int pr = tid >> 3, c0 = (tid & 7) * 4;

  f32x4 acc[2][4];
#pragma unroll
  for (int a = 0; a < 2; a++)
#pragma unroll
    for (int b = 0; b < 4; b++) acc[a][b] = (f32x4){0.f, 0.f, 0.f, 0.f};

  f32x4 pa0, pa1, pb0, pb1;
  auto LOADW = [&](int IT) {
    size_t kk = (size_t)IT * KSTEP_ + 2 * pr;
    pa0 = *(const f32x4*)(Wg + kk * 4096 + n0 + c0);
    pa1 = *(const f32x4*)(Wg + (kk + 1) * 4096 + n0 + c0);
    pb0 = *(const f32x4*)(Wu + kk * 4096 + n0 + c0);
    pb1 = *(const f32x4*)(Wu + (kk + 1) * 4096 + n0 + c0);
  };
  auto STOREW = [&](int BUF) {
#pragma unroll
    for (int j = 0; j < 4; j++) {
      unsigned v = (unsigned)f2bf(pa0[j]) | ((unsigned)f2bf(pa1[j]) << 16);
      *(unsigned*)&Wt[BUF][c0 + j][2 * pr] = v;
      unsigned u = (unsigned)f2bf(pb0[j]) | ((unsigned)f2bf(pb1[j]) << 16);
      *(unsigned*)&Wt[BUF][32 + c0 + j][2 * pr] = u;
    }
  };

  s16x8 aP[2][2][4];
  auto LOADA = [&](int IT) {
    int sl = IT & 1;
    const int kb = IT * KSTEP_;
#pragma unroll
    for (int s = 0; s < 4; s++)
#pragma unroll
      for (int mf = 0; mf < 2; mf++)
        aP[sl][mf][s] = *(const s16x8*)(A + (size_t)(m0 + mf * 16 + lr) * H_ + kb + s * 32 + 8 * kg);
  };

  LOADW(0);
  LOADA(0);
  STOREW(0);
  lds_barrier();

#pragma unroll
  for (int it = 0; it < 8; ++it) {
    if (it + 1 < 8) {
      LOADW(it + 1);
      LOADA(it + 1);
    }
#pragma unroll
    for (int s = 0; s < 4; s++) {
      s16x8 bfr[4];
#pragma unroll
      for (int nf = 0; nf < 4; nf++) {
        const unsigned short* wp = &Wt[it & 1][nf * 16 + lr][s * 32 + 2 * lk];
        s16x4 b0 = *(const s16x4*)wp;
        s16x4 b1 = *(const s16x4*)(wp + 4);
#pragma unroll
        for (int j = 0; j < 4; j++) { bfr[nf][j] = b0[j]; bfr[nf][4 + j] = b1[j]; }
      }
#pragma unroll
      for (int mf = 0; mf < 2; mf++)
#pragma unroll
        for (int nf = 0; nf < 4; nf++)
          acc[mf][nf] = __builtin_amdgcn_mfma_f32_16x16x32_bf16(aP[it & 1][mf][s], bfr[nf], acc[mf][nf], 0, 0, 0);
    }
    if (it + 1 < 8) STOREW((it + 1) & 1);
    lds_barrier();
  }

#pragma unroll
  for (int mf = 0; mf < 2; mf++)
#pragma unroll
    for (int nf = 0; nf < 2; nf++)
#pragma unroll
      for (int r = 0; r < 4; r++) {
        int row = m0 + mf * 16 + lk + r;
        if (row >= MROWS_) continue;
        int col = n0 + nf * 16 + lr;
        float g = acc[mf][nf][r];
        float u = acc[mf][nf + 2][r];
        g = 0.5f * g * (1.f + tanhf(0.7978845608028654f * (g + 0.044715f * g * g * g)));
        tb[(size_t)row * 4096 + col] = f2bf(g * u);
      }
}

// ---------------------------------------------------------------- out = normedF @ action_out_w + b
__global__ __launch_bounds__(256) void fout_k(const unsigned short* __restrict__ nf, const float* __restrict__ Wo,
                                              const float* __restrict__ bo, float* __restrict__ out) {
  int m = blockIdx.x, tid = threadIdx.x;
  int n = tid & 31, kg = tid >> 5;
  float acc = 0.f;
  for (int k = kg * 128; k < kg * 128 + 128; k++)
    acc += bf2f(nf[(size_t)m * H_ + k]) * Wo[(size_t)k * AD_ + n];
  __shared__ float red[8][32];
  red[kg][n] = acc;
  __syncthreads();
  if (kg == 0) {
    float v = 0.f;
#pragma unroll
    for (int g = 0; g < 8; g++) v += red[g][n];
    out[(size_t)m * AD_ + n] = v + bo[n];
  }
}

// ================================================================ host
extern "C" void kernel_launch(void* const* d_in, const int* in_sizes, int n_in,
                              void* d_out, int out_size, void* d_ws, size_t ws_size,
                              hipStream_t stream) {
  const float* prefix_keys   = (const float*)d_in[0];
  const float* prefix_values = (const float*)d_in[1];
  const float* x_t           = (const float*)d_in[2];
  const float* timestep      = (const float*)d_in[3];
  const unsigned char* pad_mask = (const unsigned char*)d_in[4];
  const float* action_in_w   = (const float*)d_in[5];
  const float* action_in_b   = (const float*)d_in[6];
  const float* action_out_w  = (const float*)d_in[7];
  const float* action_out_b  = (const float*)d_in[8];
  const float* tmlp_in_w     = (const float*)d_in[9];
  const float* tmlp_in_b     = (const float*)d_in[10];
  const float* tmlp_out_w    = (const float*)d_in[11];
  const float* tmlp_out_b    = (const float*)d_in[12];
  const float* w_q    = (const float*)d_in[13];
  const float* w_k    = (const float*)d_in[14];
  const float* w_v    = (const float*)d_in[15];
  const float* w_o    = (const float*)d_in[16];
  const float* w_gate = (const float*)d_in[17];
  const float* w_up   = (const float*)d_in[18];
  const float* w_down = (const float*)d_in[19];
  const float* in_norm_w    = (const float*)d_in[20];
  const float* in_scale_w   = (const float*)d_in[21];
  const float* in_gate_w    = (const float*)d_in[22];
  const float* post_norm_w  = (const float*)d_in[23];
  const float* post_scale_w = (const float*)d_in[24];
  const float* post_gate_w  = (const float*)d_in[25];
  const float* fnorm_w       = (const float*)d_in[26];
  const float* fnorm_scale_w = (const float*)d_in[27];

  char* wsp = (char*)d_ws;
  auto alloc = [&](size_t bytes) { void* p = (void*)wsp; wsp += (bytes + 255) & ~(size_t)255; return p; };

  float* emb0   = (float*)alloc((size_t)8 * H_ * 4);
  float* emb1   = (float*)alloc((size_t)8 * H_ * 4);
  float* cond   = (float*)alloc((size_t)8 * H_ * 4);
  float* fscale = (float*)alloc((size_t)8 * H_ * 4);
  float* gates  = (float*)alloc((size_t)4 * L_ * 8 * H_ * 4);
  int*   offs   = (int*)alloc(64);
  float* hbuf   = (float*)alloc((size_t)MPAD_ * H_ * 4);
  float* h1buf  = (float*)alloc((size_t)MPAD_ * H_ * 4);
  unsigned short* normed  = (unsigned short*)alloc((size_t)MPAD_ * H_ * 2);
  unsigned short* normed2 = (unsigned short*)alloc((size_t)MPAD_ * H_ * 2);
  unsigned short* q_r     = (unsigned short*)alloc((size_t)B_ * NH_ * 64 * HD_ * 2);
  unsigned short* Kf_all  = (unsigned short*)alloc((size_t)L_ * B_ * TPAD_ * HD_ * 2);
  unsigned short* Vt_all  = (unsigned short*)alloc((size_t)L_ * B_ * HD_ * TPAD_ * 2);
  unsigned short* attb    = (unsigned short*)alloc((size_t)MPAD_ * 2048 * 2);
  unsigned short* t_buf   = (unsigned short*)alloc((size_t)MPAD_ * FF_ * 2);
  float* wopart = (float*)alloc((size_t)4 * MPAD_ * 1024 * 4);
  float* dpart  = (float*)alloc((size_t)4 * MPAD_ * 1024 * 4);

  // attb pad rows never written by flash8: zero once (stays zero all layers)
  hipMemsetAsync(attb + (size_t)MROWS_ * 2048, 0, (size_t)(MPAD_ - MROWS_) * 2048 * 2, stream);
  // normed2 pad rows never written (redA grid = 400): zero once so upg A-reads stay finite
  hipMemsetAsync(normed2 + (size_t)MROWS_ * H_, 0, (size_t)(MPAD_ - MROWS_) * H_ * 2, stream);
  // t_buf pad rows never written by upg: zero once
  hipMemsetAsync(t_buf + (size_t)MROWS_ * FF_, 0, (size_t)(MPAD_ - MROWS_) * FF_ * 2, stream);

  emb_k<<<8, 256, 0, stream>>>(timestep, emb0);
  gemm8_k<<<16, 256, 0, stream>>>(emb0, tmlp_in_w, tmlp_in_b, emb1, 1);
  gemm8_k<<<16, 256, 0, stream>>>(emb1, tmlp_out_w, tmlp_out_b, cond, 1);
  gemm8_k<<<16, 256, 0, stream>>>(cond, fnorm_scale_w, nullptr, fscale, 0);
  gates_k<<<dim3(16, L_, 4), 256, 0, stream>>>(cond, in_scale_w, in_gate_w, post_scale_w, post_gate_w, gates);
  offs_k<<<1, 256, 0, stream>>>(pad_mask, offs);
  action_in_k<<<(MPAD_ * H_) / 256, 256, 0, stream>>>(x_t, action_in_w, action_in_b, hbuf);
  prefixAll_k<<<dim3(16, B_, L_), 256, 0, stream>>>(prefix_keys, prefix_values, Kf_all, Vt_all);
  ada_k<<<MPAD_, 256, 0, stream>>>(hbuf, in_norm_w, gates, normed);  // layer-0 in_scale = gates z=0,l=0

  for (int i = 0; i < L_; i++) {
    const float* wq_i = w_q + (size_t)i * H_ * 2048;
    const float* wk_i = w_k + (size_t)i * H_ * HD_;
    const float* wv_i = w_v + (size_t)i * H_ * HD_;
    const float* wo_i = w_o + (size_t)i * 2048 * H_;
    const float* wg_i = w_gate + (size_t)i * H_ * FF_;
    const float* wu_i = w_up + (size_t)i * H_ * FF_;
    const float* wd_i = w_down + (size_t)i * FF_ * H_;
    const float* g_in_gate    = gates + ((size_t)(1 * L_ + i) * 8) * H_;
    const float* g_post_scale = gates + ((size_t)(2 * L_ + i) * 8) * H_;
    const float* g_post_gate  = gates + ((size_t)(3 * L_ + i) * 8) * H_;
    unsigned short* Kf_l = Kf_all + (size_t)i * B_ * TPAD_ * HD_;
    unsigned short* Vt_l = Vt_all + (size_t)i * B_ * HD_ * TPAD_;

    qkvF_k<<<dim3(80, 2), 512, 0, stream>>>(normed, wq_i, wk_i, wv_i, offs, q_r, Kf_l, Vt_l);
    flash8_k<<<dim3(B_, 4, NH_), 512, 0, stream>>>(q_r, Kf_l, Vt_l, attb);
    gemmS_k<1, 4, 2, 2048><<<dim3(32, 4, 2), 512, 0, stream>>>(attb, wo_i, wopart);
    redA_k<4><<<MROWS_, 256, 0, stream>>>(wopart, hbuf, g_in_gate, post_norm_w + (size_t)i * H_,
                                          g_post_scale, h1buf, normed2);
    upg_k<<<dim3(128, 2), 512, 0, stream>>>(normed2, wg_i, wu_i, t_buf);
    gemmS_k<3, 4, 2, 4096><<<dim3(32, 4, 2), 512, 0, stream>>>(t_buf, wd_i, dpart);
    const float* nw_next = (i + 1 < L_) ? in_norm_w + (size_t)(i + 1) * H_ : fnorm_w;
    const float* sc_next = (i + 1 < L_) ? gates + ((size_t)(i + 1) * 8) * H_ : fscale;
    redA_k<4><<<MROWS_, 256, 0, stream>>>(dpart, h1buf, g_post_gate, nw_next, sc_next, hbuf, normed);
  }

  fout_k<<<MROWS_, 256, 0, stream>>>(normed, action_out_w, action_out_b, (float*)d_out);
}